// Round 1
// baseline (1518.086 us; speedup 1.0000x reference)
//
#include <hip/hip_runtime.h>
#include <hip/hip_bf16.h>

// ---------------------------------------------------------------------------
// 2-layer GATConv (heads=1), fp32. N=50000, E=800000, Cin=128, Ch=256, Co=128,
// Ed=8. Self loops appended after E real edges; self-loop edge_attr = mean.
// ---------------------------------------------------------------------------

#define NEG_SLOPE 0.2f

__device__ __forceinline__ unsigned enc_f(float f) {
    unsigned u = __float_as_uint(f);
    return (u & 0x80000000u) ? ~u : (u | 0x80000000u);
}
__device__ __forceinline__ float dec_f(unsigned u) {
    return (u & 0x80000000u) ? __uint_as_float(u & 0x7fffffffu)
                             : __uint_as_float(~u);
}

// ---- edge_attr column means (accumulate sums; divide later) ---------------
__global__ void ea_mean_kernel(const float* __restrict__ ea, float* __restrict__ acc, int E) {
    __shared__ float red[8];
    int tid = threadIdx.x;
    int f = tid & 7;
    float s = 0.f;
    size_t total = (size_t)E * 8;
    size_t stride = (size_t)gridDim.x * blockDim.x; // multiple of 8 -> f stays fixed
    for (size_t i = (size_t)blockIdx.x * blockDim.x + tid; i < total; i += stride)
        s += ea[i];
    if (tid < 8) red[tid] = 0.f;
    __syncthreads();
    atomicAdd(&red[f], s);
    __syncthreads();
    if (tid < 8) atomicAdd(&acc[tid], red[tid]);
}

// ---- we_vec{1,2}[j] = sum_k We[j,k]*a_edge[k]; ae_loop = mean_ea . we_vec --
__global__ void prep_kernel(const float* __restrict__ We1, const float* __restrict__ ae1v,
                            const float* __restrict__ We2, const float* __restrict__ ae2v,
                            const float* __restrict__ mean_acc, float Einv,
                            float* __restrict__ we_vec1, float* __restrict__ we_vec2,
                            float* __restrict__ ae_loop, int Ch, int Co) {
    __shared__ float red[256];
    int t = threadIdx.x;
    for (int j = 0; j < 8; ++j) {
        float s = 0.f;
        for (int k = t; k < Ch; k += 256) s += We1[j * Ch + k] * ae1v[k];
        red[t] = s; __syncthreads();
        for (int off = 128; off; off >>= 1) { if (t < off) red[t] += red[t + off]; __syncthreads(); }
        if (t == 0) we_vec1[j] = red[0];
        __syncthreads();
        s = 0.f;
        for (int k = t; k < Co; k += 256) s += We2[j * Co + k] * ae2v[k];
        red[t] = s; __syncthreads();
        for (int off = 128; off; off >>= 1) { if (t < off) red[t] += red[t + off]; __syncthreads(); }
        if (t == 0) we_vec2[j] = red[0];
        __syncthreads();
    }
    if (t == 0) {
        float s1 = 0.f, s2 = 0.f;
        for (int j = 0; j < 8; ++j) {
            float m = mean_acc[j] * Einv;
            s1 += m * we_vec1[j];
            s2 += m * we_vec2[j];
        }
        ae_loop[0] = s1; ae_loop[1] = s2;
    }
}

// ---- per-edge a_e for both layers -----------------------------------------
__global__ void edge_ae_kernel(const float* __restrict__ ea,
                               const float* __restrict__ we_vec1,
                               const float* __restrict__ we_vec2,
                               float* __restrict__ ae1o, float* __restrict__ ae2o, int E) {
    int e = blockIdx.x * blockDim.x + threadIdx.x;
    if (e >= E) return;
    const float4 v0 = *(const float4*)&ea[(size_t)e * 8];
    const float4 v1 = *(const float4*)&ea[(size_t)e * 8 + 4];
    float s1 = v0.x * we_vec1[0] + v0.y * we_vec1[1] + v0.z * we_vec1[2] + v0.w * we_vec1[3]
             + v1.x * we_vec1[4] + v1.y * we_vec1[5] + v1.z * we_vec1[6] + v1.w * we_vec1[7];
    float s2 = v0.x * we_vec2[0] + v0.y * we_vec2[1] + v0.z * we_vec2[2] + v0.w * we_vec2[3]
             + v1.x * we_vec2[4] + v1.y * we_vec2[5] + v1.z * we_vec2[6] + v1.w * we_vec2[7];
    ae1o[e] = s1;
    ae2o[e] = s2;
}

// ---- tiled fp32 GEMM: C[N,M] = A[N,K] @ B[K,M]; optional fused (A+bias,relu)
__global__ __launch_bounds__(256) void gemm_kernel(const float* __restrict__ A,
                                                   const float* __restrict__ B,
                                                   float* __restrict__ C,
                                                   int Nrows, int K, int M,
                                                   const float* __restrict__ abias) {
    __shared__ float As[16][68];
    __shared__ float Bs[16][68];
    int tid = threadIdx.x;
    int tx = tid & 15, ty = tid >> 4;
    int rowBase = blockIdx.y * 64;
    int colBase = blockIdx.x * 64;
    float acc[4][4] = {};
    for (int k0 = 0; k0 < K; k0 += 16) {
        int ka = tid & 15;
#pragma unroll
        for (int it = 0; it < 4; ++it) {
            int r = (tid >> 4) + 16 * it;
            int gr = rowBase + r;
            float v = 0.f;
            if (gr < Nrows) {
                v = A[(size_t)gr * K + k0 + ka];
                if (abias) { v += abias[k0 + ka]; v = v > 0.f ? v : 0.f; }
            }
            As[ka][r] = v;
        }
        int cb = tid & 63;
#pragma unroll
        for (int it = 0; it < 4; ++it) {
            int kr = (tid >> 6) + 4 * it;
            Bs[kr][cb] = B[(size_t)(k0 + kr) * M + colBase + cb];
        }
        __syncthreads();
#pragma unroll
        for (int kk = 0; kk < 16; ++kk) {
            float4 a = *(const float4*)&As[kk][ty * 4];
            float4 b = *(const float4*)&Bs[kk][tx * 4];
            float av[4] = {a.x, a.y, a.z, a.w};
            float bv[4] = {b.x, b.y, b.z, b.w};
#pragma unroll
            for (int i = 0; i < 4; ++i)
#pragma unroll
                for (int j = 0; j < 4; ++j)
                    acc[i][j] += av[i] * bv[j];
        }
        __syncthreads();
    }
#pragma unroll
    for (int i = 0; i < 4; ++i) {
        int gr = rowBase + ty * 4 + i;
        if (gr >= Nrows) continue;
#pragma unroll
        for (int j = 0; j < 4; ++j)
            C[(size_t)gr * M + colBase + tx * 4 + j] = acc[i][j];
    }
}

// ---- a_s[i] = h[i].as, a_d[i] = h[i].ad  (one wave per row, 4 rows/block) --
__global__ void rowdot_kernel(const float* __restrict__ H,
                              const float* __restrict__ av, const float* __restrict__ bv,
                              float* __restrict__ as_out, float* __restrict__ ad_out,
                              int Nrows, int C) {
    int lane = threadIdx.x & 63;
    int wid = threadIdx.x >> 6;
    int row = blockIdx.x * 4 + wid;
    if (row >= Nrows) return;
    float s = 0.f, d = 0.f;
    for (int c = lane; c < C; c += 64) {
        float h = H[(size_t)row * C + c];
        s += h * av[c];
        d += h * bv[c];
    }
#pragma unroll
    for (int off = 32; off; off >>= 1) {
        s += __shfl_down(s, off);
        d += __shfl_down(d, off);
    }
    if (lane == 0) { as_out[row] = s; ad_out[row] = d; }
}

// ---- alpha = leakyrelu(a_s[src]+a_d[dst]+a_e); segment max via atomicMax ---
__global__ void alpha_max_kernel(const int* __restrict__ src, const int* __restrict__ dst,
                                 const float* __restrict__ a_s, const float* __restrict__ a_d,
                                 const float* __restrict__ a_e, const float* __restrict__ ae_loop,
                                 int which, int E, int Etot,
                                 float* __restrict__ alpha, unsigned* __restrict__ amax_u) {
    int e = blockIdx.x * blockDim.x + threadIdx.x;
    if (e >= Etot) return;
    int s, d; float ae;
    if (e < E) { s = src[e]; d = dst[e]; ae = a_e[e]; }
    else       { s = d = e - E; ae = ae_loop[which]; }
    float al = a_s[s] + a_d[d] + ae;
    al = al >= 0.f ? al : NEG_SLOPE * al;
    alpha[e] = al;
    atomicMax(&amax_u[d], enc_f(al));
}

// ---- ex = exp(alpha - amax[dst]); denom[dst] += ex (ex overwrites alpha) ---
__global__ void exp_sum_kernel(const int* __restrict__ dst, int E, int Etot,
                               float* __restrict__ alpha,
                               const unsigned* __restrict__ amax_u,
                               float* __restrict__ denom) {
    int e = blockIdx.x * blockDim.x + threadIdx.x;
    if (e >= Etot) return;
    int d = (e < E) ? dst[e] : e - E;
    float ex = expf(alpha[e] - dec_f(amax_u[d]));
    alpha[e] = ex;
    atomicAdd(&denom[d], ex);
}

// ---- out[dst] += h[src] * (ex/denom[dst]); one block per edge --------------
__global__ void scatter_kernel(const int* __restrict__ src, const int* __restrict__ dst,
                               const float* __restrict__ ex, const float* __restrict__ denom,
                               const float* __restrict__ H, float* __restrict__ out,
                               int E, int C) {
    int e = blockIdx.x;
    int s, d;
    if (e < E) { s = src[e]; d = dst[e]; }
    else       { s = d = e - E; }
    float w = ex[e] / denom[d];
    int c = threadIdx.x;
    atomicAdd(&out[(size_t)d * C + c], H[(size_t)s * C + c] * w);
}

// ---- out[i] = bias (init before scatter) -----------------------------------
__global__ void init_out_kernel(float* __restrict__ out, const float* __restrict__ bias, int C) {
    out[(size_t)blockIdx.x * C + threadIdx.x] = bias[threadIdx.x];
}

extern "C" void kernel_launch(void* const* d_in, const int* in_sizes, int n_in,
                              void* d_out, int out_size, void* d_ws, size_t ws_size,
                              hipStream_t stream) {
    const int Cin = 128, Ch = 256, Co = 128;
    const int N = in_sizes[0] / Cin;        // 50000
    const int E = in_sizes[1] / 2;          // 800000
    const int Etot = E + N;

    const float* x   = (const float*)d_in[0];
    const int*   src = (const int*)d_in[1];
    const int*   dst = src + E;
    const float* ea  = (const float*)d_in[2];
    const float* W1  = (const float*)d_in[3];
    const float* We1 = (const float*)d_in[4];
    const float* as1 = (const float*)d_in[5];
    const float* ad1 = (const float*)d_in[6];
    const float* ae1 = (const float*)d_in[7];
    const float* b1  = (const float*)d_in[8];
    const float* W2  = (const float*)d_in[9];
    const float* We2 = (const float*)d_in[10];
    const float* as2 = (const float*)d_in[11];
    const float* ad2 = (const float*)d_in[12];
    const float* ae2 = (const float*)d_in[13];
    const float* b2  = (const float*)d_in[14];
    float* out = (float*)d_out;

    // workspace layout (floats)
    float* ws = (float*)d_ws;
    size_t off = 0;
    float* h1    = ws + off; off += (size_t)N * Ch;   // reused as h2 (N*Co <= N*Ch)
    float* g1    = ws + off; off += (size_t)N * Ch;   // layer-1 aggregated output (pre-bias/relu)
    float* alpha = ws + off; off += (size_t)Etot;     // alpha, then ex
    float* aE1   = ws + off; off += (size_t)E;
    float* aE2   = ws + off; off += (size_t)E;
    float* asv   = ws + off; off += (size_t)N;
    float* adv   = ws + off; off += (size_t)N;
    unsigned* amax1 = (unsigned*)(ws + off); off += (size_t)N;
    float* den1  = ws + off; off += (size_t)N;
    unsigned* amax2 = (unsigned*)(ws + off); off += (size_t)N;
    float* den2  = ws + off; off += (size_t)N;
    float* misc  = ws + off; off += 32;               // [0:8) mean_acc, [8:16) we_vec1, [16:24) we_vec2, [24:26) ae_loop
    float* mean_acc = misc;
    float* we_vec1  = misc + 8;
    float* we_vec2  = misc + 16;
    float* ae_loop  = misc + 24;

    // zero the accumulated regions (ws is poisoned 0xAA before each call)
    hipMemsetAsync(g1, 0, (size_t)N * Ch * sizeof(float), stream);
    hipMemsetAsync(amax1, 0, (size_t)4 * N * sizeof(float), stream); // amax1,den1,amax2,den2
    hipMemsetAsync(misc, 0, 32 * sizeof(float), stream);

    // ---- precompute -------------------------------------------------------
    ea_mean_kernel<<<1024, 256, 0, stream>>>(ea, mean_acc, E);
    prep_kernel<<<1, 256, 0, stream>>>(We1, ae1, We2, ae2, mean_acc, 1.0f / (float)E,
                                       we_vec1, we_vec2, ae_loop, Ch, Co);
    edge_ae_kernel<<<(E + 255) / 256, 256, 0, stream>>>(ea, we_vec1, we_vec2, aE1, aE2, E);

    // ---- layer 1 ----------------------------------------------------------
    {
        dim3 grid(Ch / 64, (N + 63) / 64);
        gemm_kernel<<<grid, 256, 0, stream>>>(x, W1, h1, N, Cin, Ch, nullptr);
    }
    rowdot_kernel<<<(N + 3) / 4, 256, 0, stream>>>(h1, as1, ad1, asv, adv, N, Ch);
    alpha_max_kernel<<<(Etot + 255) / 256, 256, 0, stream>>>(src, dst, asv, adv, aE1, ae_loop, 0,
                                                             E, Etot, alpha, amax1);
    exp_sum_kernel<<<(Etot + 255) / 256, 256, 0, stream>>>(dst, E, Etot, alpha, amax1, den1);
    scatter_kernel<<<Etot, Ch, 0, stream>>>(src, dst, alpha, den1, h1, g1, E, Ch);

    // ---- layer 2 ----------------------------------------------------------
    float* h2 = h1; // reuse
    {
        dim3 grid(Co / 64, (N + 63) / 64);
        gemm_kernel<<<grid, 256, 0, stream>>>(g1, W2, h2, N, Ch, Co, b1); // fused relu(g1+b1)
    }
    rowdot_kernel<<<(N + 3) / 4, 256, 0, stream>>>(h2, as2, ad2, asv, adv, N, Co);
    init_out_kernel<<<N, Co, 0, stream>>>(out, b2, Co);
    alpha_max_kernel<<<(Etot + 255) / 256, 256, 0, stream>>>(src, dst, asv, adv, aE2, ae_loop, 1,
                                                             E, Etot, alpha, amax2);
    exp_sum_kernel<<<(Etot + 255) / 256, 256, 0, stream>>>(dst, E, Etot, alpha, amax2, den2);
    scatter_kernel<<<Etot, Co, 0, stream>>>(src, dst, alpha, den2, h2, out, E, Co);
}

// Round 2
// 718.170 us; speedup vs baseline: 2.1138x; 2.1138x over previous
//
#include <hip/hip_runtime.h>
#include <hip/hip_bf16.h>

// ---------------------------------------------------------------------------
// 2-layer GATConv (heads=1), fp32. N=50000, E=800000, Cin=128, Ch=256, Co=128,
// Ed=8. Strategy: device-built CSR by dst, then per-node gather softmax +
// aggregation (no global atomics in the hot path).
// ---------------------------------------------------------------------------

#define NEG_SLOPE 0.2f

// ---- edge_attr column means (accumulate sums; divide later) ---------------
__global__ void ea_mean_kernel(const float* __restrict__ ea, float* __restrict__ acc, int E) {
    __shared__ float red[8];
    int tid = threadIdx.x;
    int f = tid & 7;
    float s = 0.f;
    size_t total = (size_t)E * 8;
    size_t stride = (size_t)gridDim.x * blockDim.x; // multiple of 8 -> f stays fixed
    for (size_t i = (size_t)blockIdx.x * blockDim.x + tid; i < total; i += stride)
        s += ea[i];
    if (tid < 8) red[tid] = 0.f;
    __syncthreads();
    atomicAdd(&red[f], s);
    __syncthreads();
    if (tid < 8) atomicAdd(&acc[tid], red[tid]);
}

// ---- we_vec{1,2}[j] = sum_k We[j,k]*a_edge[k]; ae_loop = mean_ea . we_vec --
__global__ void prep_kernel(const float* __restrict__ We1, const float* __restrict__ ae1v,
                            const float* __restrict__ We2, const float* __restrict__ ae2v,
                            const float* __restrict__ mean_acc, float Einv,
                            float* __restrict__ we_vec1, float* __restrict__ we_vec2,
                            float* __restrict__ ae_loop, int Ch, int Co) {
    __shared__ float red[256];
    int t = threadIdx.x;
    for (int j = 0; j < 8; ++j) {
        float s = 0.f;
        for (int k = t; k < Ch; k += 256) s += We1[j * Ch + k] * ae1v[k];
        red[t] = s; __syncthreads();
        for (int off = 128; off; off >>= 1) { if (t < off) red[t] += red[t + off]; __syncthreads(); }
        if (t == 0) we_vec1[j] = red[0];
        __syncthreads();
        s = 0.f;
        for (int k = t; k < Co; k += 256) s += We2[j * Co + k] * ae2v[k];
        red[t] = s; __syncthreads();
        for (int off = 128; off; off >>= 1) { if (t < off) red[t] += red[t + off]; __syncthreads(); }
        if (t == 0) we_vec2[j] = red[0];
        __syncthreads();
    }
    if (t == 0) {
        float s1 = 0.f, s2 = 0.f;
        for (int j = 0; j < 8; ++j) {
            float m = mean_acc[j] * Einv;
            s1 += m * we_vec1[j];
            s2 += m * we_vec2[j];
        }
        ae_loop[0] = s1; ae_loop[1] = s2;
    }
}

// ---- CSR build: histogram ---------------------------------------------------
__global__ void hist_kernel(const int* __restrict__ dst, int* __restrict__ deg, int E) {
    int e = blockIdx.x * blockDim.x + threadIdx.x;
    if (e < E) atomicAdd(&deg[dst[e]], 1);
}

// ---- 3-pass exclusive scan over n = N+1 elements ---------------------------
__global__ void scan1_kernel(const int* __restrict__ deg, int* __restrict__ out,
                             int* __restrict__ bsum, int N, int n) {
    __shared__ int s[256];
    int t = threadIdx.x;
    int i = blockIdx.x * 256 + t;
    int v = (i < N) ? deg[i] : 0;
    s[t] = v; __syncthreads();
    for (int off = 1; off < 256; off <<= 1) {
        int u = (t >= off) ? s[t - off] : 0;
        __syncthreads();
        s[t] += u;
        __syncthreads();
    }
    if (i < n) out[i] = s[t] - v;
    if (t == 255) bsum[blockIdx.x] = s[255];
}

__global__ void scan2_kernel(int* __restrict__ bsum, int nb) {
    __shared__ int s[256];
    int t = threadIdx.x;
    int v = (t < nb) ? bsum[t] : 0;
    s[t] = v; __syncthreads();
    for (int off = 1; off < 256; off <<= 1) {
        int u = (t >= off) ? s[t - off] : 0;
        __syncthreads();
        s[t] += u;
        __syncthreads();
    }
    if (t < nb) bsum[t] = s[t] - v;
}

__global__ void scan3_kernel(int* __restrict__ out, const int* __restrict__ bsum, int n) {
    int i = blockIdx.x * 256 + threadIdx.x;
    if (i < n) out[i] += bsum[blockIdx.x];
}

// ---- CSR fill + fused per-edge a_e (both layers) into CSR order ------------
__global__ void fill_kernel(const int* __restrict__ src, const int* __restrict__ dst,
                            const float* __restrict__ ea,
                            const float* __restrict__ we_vec1, const float* __restrict__ we_vec2,
                            int* __restrict__ cursor, int* __restrict__ csr_src,
                            float* __restrict__ aE1, float* __restrict__ aE2, int E) {
    __shared__ float wv[16];
    if (threadIdx.x < 8) wv[threadIdx.x] = we_vec1[threadIdx.x];
    else if (threadIdx.x < 16) wv[threadIdx.x] = we_vec2[threadIdx.x - 8];
    __syncthreads();
    int e = blockIdx.x * blockDim.x + threadIdx.x;
    if (e >= E) return;
    int d = dst[e];
    int idx = atomicAdd(&cursor[d], 1);
    csr_src[idx] = src[e];
    const float4 v0 = *(const float4*)&ea[(size_t)e * 8];
    const float4 v1 = *(const float4*)&ea[(size_t)e * 8 + 4];
    float s1 = v0.x * wv[0] + v0.y * wv[1] + v0.z * wv[2] + v0.w * wv[3]
             + v1.x * wv[4] + v1.y * wv[5] + v1.z * wv[6] + v1.w * wv[7];
    float s2 = v0.x * wv[8] + v0.y * wv[9] + v0.z * wv[10] + v0.w * wv[11]
             + v1.x * wv[12] + v1.y * wv[13] + v1.z * wv[14] + v1.w * wv[15];
    aE1[idx] = s1;
    aE2[idx] = s2;
}

// ---- tiled fp32 GEMM: C[N,M] = A[N,K] @ B[K,M]; optional fused (A+bias,relu)
__global__ __launch_bounds__(256) void gemm_kernel(const float* __restrict__ A,
                                                   const float* __restrict__ B,
                                                   float* __restrict__ C,
                                                   int Nrows, int K, int M,
                                                   const float* __restrict__ abias) {
    __shared__ float As[16][68];
    __shared__ float Bs[16][68];
    int tid = threadIdx.x;
    int tx = tid & 15, ty = tid >> 4;
    int rowBase = blockIdx.y * 64;
    int colBase = blockIdx.x * 64;
    float acc[4][4] = {};
    for (int k0 = 0; k0 < K; k0 += 16) {
        int ka = tid & 15;
#pragma unroll
        for (int it = 0; it < 4; ++it) {
            int r = (tid >> 4) + 16 * it;
            int gr = rowBase + r;
            float v = 0.f;
            if (gr < Nrows) {
                v = A[(size_t)gr * K + k0 + ka];
                if (abias) { v += abias[k0 + ka]; v = v > 0.f ? v : 0.f; }
            }
            As[ka][r] = v;
        }
        int cb = tid & 63;
#pragma unroll
        for (int it = 0; it < 4; ++it) {
            int kr = (tid >> 6) + 4 * it;
            Bs[kr][cb] = B[(size_t)(k0 + kr) * M + colBase + cb];
        }
        __syncthreads();
#pragma unroll
        for (int kk = 0; kk < 16; ++kk) {
            float4 a = *(const float4*)&As[kk][ty * 4];
            float4 b = *(const float4*)&Bs[kk][tx * 4];
            float av[4] = {a.x, a.y, a.z, a.w};
            float bv[4] = {b.x, b.y, b.z, b.w};
#pragma unroll
            for (int i = 0; i < 4; ++i)
#pragma unroll
                for (int j = 0; j < 4; ++j)
                    acc[i][j] += av[i] * bv[j];
        }
        __syncthreads();
    }
#pragma unroll
    for (int i = 0; i < 4; ++i) {
        int gr = rowBase + ty * 4 + i;
        if (gr >= Nrows) continue;
#pragma unroll
        for (int j = 0; j < 4; ++j)
            C[(size_t)gr * M + colBase + tx * 4 + j] = acc[i][j];
    }
}

// ---- a_s[i] = h[i].as, a_d[i] = h[i].ad  (one wave per row, 4 rows/block) --
__global__ void rowdot_kernel(const float* __restrict__ H,
                              const float* __restrict__ av, const float* __restrict__ bv,
                              float* __restrict__ as_out, float* __restrict__ ad_out,
                              int Nrows, int C) {
    int lane = threadIdx.x & 63;
    int wid = threadIdx.x >> 6;
    int row = blockIdx.x * 4 + wid;
    if (row >= Nrows) return;
    float s = 0.f, d = 0.f;
    for (int c = lane; c < C; c += 64) {
        float h = H[(size_t)row * C + c];
        s += h * av[c];
        d += h * bv[c];
    }
#pragma unroll
    for (int off = 32; off; off >>= 1) {
        s += __shfl_down(s, off);
        d += __shfl_down(d, off);
    }
    if (lane == 0) { as_out[row] = s; ad_out[row] = d; }
}

// ---- per-node segment softmax: one wave per node, CSR order ---------------
__global__ void softmax_kernel(const int* __restrict__ row_start, const int* __restrict__ csr_src,
                               const float* __restrict__ aE,
                               const float* __restrict__ a_s, const float* __restrict__ a_d,
                               const float* __restrict__ ae_loop, int which,
                               float* __restrict__ w, float* __restrict__ wself, int N) {
    int lane = threadIdx.x & 63;
    int wid = threadIdx.x >> 6;
    int node = blockIdx.x * 4 + wid;
    if (node >= N) return;
    int st = row_start[node], en = row_start[node + 1];
    float ad = a_d[node];
    float aloop = a_s[node] + ad + ae_loop[which];
    aloop = aloop >= 0.f ? aloop : NEG_SLOPE * aloop;
    float m = aloop;
    for (int i = st + lane; i < en; i += 64) {
        float al = a_s[csr_src[i]] + ad + aE[i];
        al = al >= 0.f ? al : NEG_SLOPE * al;
        w[i] = al;
        m = fmaxf(m, al);
    }
#pragma unroll
    for (int off = 32; off; off >>= 1) m = fmaxf(m, __shfl_down(m, off));
    m = __shfl(m, 0);
    float es = expf(aloop - m);
    float sum = (lane == 0) ? es : 0.f;
    for (int i = st + lane; i < en; i += 64) {
        float ex = expf(w[i] - m);
        w[i] = ex;
        sum += ex;
    }
#pragma unroll
    for (int off = 32; off; off >>= 1) sum += __shfl_down(sum, off);
    sum = __shfl(sum, 0);
    float inv = 1.f / sum;
    for (int i = st + lane; i < en; i += 64) w[i] *= inv;
    if (lane == 0) wself[node] = es * inv;
}

// ---- per-node gather aggregation: out[n][c] = sum_e w[e]*H[src[e]][c] ------
// NPB nodes per 256-thread block; each thread owns one output column.
// Edge (src,w) pairs are loaded lane-parallel and broadcast in-wave via shfl.
template <int C, int NPB>
__global__ __launch_bounds__(256) void agg_kernel(const int* __restrict__ row_start,
                                                  const int* __restrict__ csr_src,
                                                  const float* __restrict__ w,
                                                  const float* __restrict__ wself,
                                                  const float* __restrict__ H,
                                                  float* __restrict__ out,
                                                  const float* __restrict__ bias, int N) {
    int tid = threadIdx.x;
    int lane = tid & 63;
    int node = blockIdx.x * NPB + tid / C;
    int c = tid % C;
    if (node >= N) return;
    int st = row_start[node], en = row_start[node + 1];
    float acc = wself[node] * H[(size_t)node * C + c];
    for (int base = st; base < en; base += 64) {
        int i = base + lane;
        int sreg = 0; float wreg = 0.f;
        if (i < en) { sreg = csr_src[i]; wreg = w[i]; }
        int cnt = min(64, en - base);
        for (int j = 0; j < cnt; ++j) {
            int s = __shfl(sreg, j);
            float wg = __shfl(wreg, j);
            acc += wg * H[(size_t)s * C + c];
        }
    }
    if (bias) acc += bias[c];
    out[(size_t)node * C + c] = acc;
}

extern "C" void kernel_launch(void* const* d_in, const int* in_sizes, int n_in,
                              void* d_out, int out_size, void* d_ws, size_t ws_size,
                              hipStream_t stream) {
    const int Cin = 128, Ch = 256, Co = 128;
    const int N = in_sizes[0] / Cin;        // 50000
    const int E = in_sizes[1] / 2;          // 800000

    const float* x   = (const float*)d_in[0];
    const int*   src = (const int*)d_in[1];
    const int*   dst = src + E;
    const float* ea  = (const float*)d_in[2];
    const float* W1  = (const float*)d_in[3];
    const float* We1 = (const float*)d_in[4];
    const float* as1 = (const float*)d_in[5];
    const float* ad1 = (const float*)d_in[6];
    const float* ae1 = (const float*)d_in[7];
    const float* b1  = (const float*)d_in[8];
    const float* W2  = (const float*)d_in[9];
    const float* We2 = (const float*)d_in[10];
    const float* as2 = (const float*)d_in[11];
    const float* ad2 = (const float*)d_in[12];
    const float* ae2 = (const float*)d_in[13];
    const float* b2  = (const float*)d_in[14];
    float* out = (float*)d_out;

    // workspace layout (4-byte units)
    float* ws = (float*)d_ws;
    size_t off = 0;
    float* h1    = ws + off; off += (size_t)N * Ch;      // reused as h2
    float* g1    = ws + off; off += (size_t)N * Ch;      // layer-1 aggregated (pre-bias/relu)
    float* aE1   = ws + off; off += (size_t)E;           // per-edge a_e, CSR order
    float* aE2   = ws + off; off += (size_t)E;
    float* wbuf  = ws + off; off += (size_t)E;           // softmax weights, CSR order
    float* wself = ws + off; off += (size_t)N;
    float* asv   = ws + off; off += (size_t)N;
    float* adv   = ws + off; off += (size_t)N;
    int* csr_src   = (int*)(ws + off); off += (size_t)E;
    int* deg       = (int*)(ws + off); off += (size_t)N + 1;
    int* row_start = (int*)(ws + off); off += (size_t)N + 1;
    int* cursor    = (int*)(ws + off); off += (size_t)N;
    int* bsum      = (int*)(ws + off); off += 256;
    float* misc  = ws + off; off += 32;  // [0:8) mean_acc, [8:16) we_vec1, [16:24) we_vec2, [24:26) ae_loop
    float* mean_acc = misc;
    float* we_vec1  = misc + 8;
    float* we_vec2  = misc + 16;
    float* ae_loop  = misc + 24;

    const int n1 = N + 1;
    const int nscan = (n1 + 255) / 256;   // scan blocks (<= 256)

    // zero what must be zero (ws is poisoned 0xAA before each timed call)
    hipMemsetAsync(deg, 0, (size_t)n1 * sizeof(int), stream);
    hipMemsetAsync(misc, 0, 32 * sizeof(float), stream);

    // ---- precompute: edge-attr projections + CSR ---------------------------
    ea_mean_kernel<<<1024, 256, 0, stream>>>(ea, mean_acc, E);
    prep_kernel<<<1, 256, 0, stream>>>(We1, ae1, We2, ae2, mean_acc, 1.0f / (float)E,
                                       we_vec1, we_vec2, ae_loop, Ch, Co);
    hist_kernel<<<(E + 255) / 256, 256, 0, stream>>>(dst, deg, E);
    scan1_kernel<<<nscan, 256, 0, stream>>>(deg, row_start, bsum, N, n1);
    scan2_kernel<<<1, 256, 0, stream>>>(bsum, nscan);
    scan3_kernel<<<nscan, 256, 0, stream>>>(row_start, bsum, n1);
    hipMemcpyAsync(cursor, row_start, (size_t)N * sizeof(int),
                   hipMemcpyDeviceToDevice, stream);
    fill_kernel<<<(E + 255) / 256, 256, 0, stream>>>(src, dst, ea, we_vec1, we_vec2,
                                                     cursor, csr_src, aE1, aE2, E);

    // ---- layer 1 ----------------------------------------------------------
    {
        dim3 grid(Ch / 64, (N + 63) / 64);
        gemm_kernel<<<grid, 256, 0, stream>>>(x, W1, h1, N, Cin, Ch, nullptr);
    }
    rowdot_kernel<<<(N + 3) / 4, 256, 0, stream>>>(h1, as1, ad1, asv, adv, N, Ch);
    softmax_kernel<<<(N + 3) / 4, 256, 0, stream>>>(row_start, csr_src, aE1, asv, adv,
                                                    ae_loop, 0, wbuf, wself, N);
    agg_kernel<256, 1><<<N, 256, 0, stream>>>(row_start, csr_src, wbuf, wself, h1, g1,
                                              nullptr, N);

    // ---- layer 2 ----------------------------------------------------------
    float* h2 = h1; // reuse
    {
        dim3 grid(Co / 64, (N + 63) / 64);
        gemm_kernel<<<grid, 256, 0, stream>>>(g1, W2, h2, N, Ch, Co, b1); // fused relu(g1+b1)
    }
    rowdot_kernel<<<(N + 3) / 4, 256, 0, stream>>>(h2, as2, ad2, asv, adv, N, Co);
    softmax_kernel<<<(N + 3) / 4, 256, 0, stream>>>(row_start, csr_src, aE2, asv, adv,
                                                    ae_loop, 1, wbuf, wself, N);
    agg_kernel<128, 2><<<(N + 1) / 2, 256, 0, stream>>>(row_start, csr_src, wbuf, wself,
                                                        h2, out, b2, N);
}

// Round 3
// 553.005 us; speedup vs baseline: 2.7452x; 1.2987x over previous
//
#include <hip/hip_runtime.h>
#include <hip/hip_bf16.h>

// ---------------------------------------------------------------------------
// 2-layer GATConv (heads=1). N=50000, E=800000, Cin=128, Ch=256, Co=128, Ed=8.
// CSR-by-dst gather softmax/aggregation (no hot-path atomics) +
// split-bf16 MFMA GEMMs (x = hi+lo, 3 MFMA terms => ~fp32 precision).
// ---------------------------------------------------------------------------

#define NEG_SLOPE 0.2f

typedef unsigned short u16;
typedef short short8 __attribute__((ext_vector_type(8)));
typedef float v4f __attribute__((ext_vector_type(4)));
typedef u16 u16x4 __attribute__((ext_vector_type(4)));
typedef u16 u16x8 __attribute__((ext_vector_type(8)));

__device__ __forceinline__ u16 f2bf(float f) {
    unsigned u = __float_as_uint(f);
    return (u16)((u + 0x7fffu + ((u >> 16) & 1u)) >> 16);
}
__device__ __forceinline__ float bf2f(u16 h) {
    return __uint_as_float(((unsigned)h) << 16);
}

// ---- edge_attr column means (accumulate sums; divide later) ---------------
__global__ void ea_mean_kernel(const float* __restrict__ ea, float* __restrict__ acc, int E) {
    __shared__ float red[8];
    int tid = threadIdx.x;
    int f = tid & 7;
    float s = 0.f;
    size_t total = (size_t)E * 8;
    size_t stride = (size_t)gridDim.x * blockDim.x; // multiple of 8 -> f stays fixed
    for (size_t i = (size_t)blockIdx.x * blockDim.x + tid; i < total; i += stride)
        s += ea[i];
    if (tid < 8) red[tid] = 0.f;
    __syncthreads();
    atomicAdd(&red[f], s);
    __syncthreads();
    if (tid < 8) atomicAdd(&acc[tid], red[tid]);
}

// ---- we_vec{1,2}[j] = sum_k We[j,k]*a_edge[k]; ae_loop = mean_ea . we_vec --
__global__ void prep_kernel(const float* __restrict__ We1, const float* __restrict__ ae1v,
                            const float* __restrict__ We2, const float* __restrict__ ae2v,
                            const float* __restrict__ mean_acc, float Einv,
                            float* __restrict__ we_vec1, float* __restrict__ we_vec2,
                            float* __restrict__ ae_loop, int Ch, int Co) {
    __shared__ float red[256];
    int t = threadIdx.x;
    for (int j = 0; j < 8; ++j) {
        float s = 0.f;
        for (int k = t; k < Ch; k += 256) s += We1[j * Ch + k] * ae1v[k];
        red[t] = s; __syncthreads();
        for (int off = 128; off; off >>= 1) { if (t < off) red[t] += red[t + off]; __syncthreads(); }
        if (t == 0) we_vec1[j] = red[0];
        __syncthreads();
        s = 0.f;
        for (int k = t; k < Co; k += 256) s += We2[j * Co + k] * ae2v[k];
        red[t] = s; __syncthreads();
        for (int off = 128; off; off >>= 1) { if (t < off) red[t] += red[t + off]; __syncthreads(); }
        if (t == 0) we_vec2[j] = red[0];
        __syncthreads();
    }
    if (t == 0) {
        float s1 = 0.f, s2 = 0.f;
        for (int j = 0; j < 8; ++j) {
            float m = mean_acc[j] * Einv;
            s1 += m * we_vec1[j];
            s2 += m * we_vec2[j];
        }
        ae_loop[0] = s1; ae_loop[1] = s2;
    }
}

// ---- CSR build: histogram --------------------------------------------------
__global__ void hist_kernel(const int* __restrict__ dst, int* __restrict__ deg, int E) {
    int e = blockIdx.x * blockDim.x + threadIdx.x;
    if (e < E) atomicAdd(&deg[dst[e]], 1);
}

// ---- 3-pass exclusive scan over n = N+1 elements ---------------------------
__global__ void scan1_kernel(const int* __restrict__ deg, int* __restrict__ out,
                             int* __restrict__ bsum, int N, int n) {
    __shared__ int s[256];
    int t = threadIdx.x;
    int i = blockIdx.x * 256 + t;
    int v = (i < N) ? deg[i] : 0;
    s[t] = v; __syncthreads();
    for (int off = 1; off < 256; off <<= 1) {
        int u = (t >= off) ? s[t - off] : 0;
        __syncthreads();
        s[t] += u;
        __syncthreads();
    }
    if (i < n) out[i] = s[t] - v;
    if (t == 255) bsum[blockIdx.x] = s[255];
}

__global__ void scan2_kernel(int* __restrict__ bsum, int nb) {
    __shared__ int s[256];
    int t = threadIdx.x;
    int v = (t < nb) ? bsum[t] : 0;
    s[t] = v; __syncthreads();
    for (int off = 1; off < 256; off <<= 1) {
        int u = (t >= off) ? s[t - off] : 0;
        __syncthreads();
        s[t] += u;
        __syncthreads();
    }
    if (t < nb) bsum[t] = s[t] - v;
}

__global__ void scan3_kernel(int* __restrict__ out, const int* __restrict__ bsum, int n) {
    int i = blockIdx.x * 256 + threadIdx.x;
    if (i < n) out[i] += bsum[blockIdx.x];
}

// ---- CSR fill + fused per-edge a_e (both layers) into CSR order ------------
__global__ void fill_kernel(const int* __restrict__ src, const int* __restrict__ dst,
                            const float* __restrict__ ea,
                            const float* __restrict__ we_vec1, const float* __restrict__ we_vec2,
                            int* __restrict__ cursor, int* __restrict__ csr_src,
                            float* __restrict__ aE1, float* __restrict__ aE2, int E) {
    __shared__ float wv[16];
    if (threadIdx.x < 8) wv[threadIdx.x] = we_vec1[threadIdx.x];
    else if (threadIdx.x < 16) wv[threadIdx.x] = we_vec2[threadIdx.x - 8];
    __syncthreads();
    int e = blockIdx.x * blockDim.x + threadIdx.x;
    if (e >= E) return;
    int d = dst[e];
    int idx = atomicAdd(&cursor[d], 1);
    csr_src[idx] = src[e];
    const float4 v0 = *(const float4*)&ea[(size_t)e * 8];
    const float4 v1 = *(const float4*)&ea[(size_t)e * 8 + 4];
    float s1 = v0.x * wv[0] + v0.y * wv[1] + v0.z * wv[2] + v0.w * wv[3]
             + v1.x * wv[4] + v1.y * wv[5] + v1.z * wv[6] + v1.w * wv[7];
    float s2 = v0.x * wv[8] + v0.y * wv[9] + v0.z * wv[10] + v0.w * wv[11]
             + v1.x * wv[12] + v1.y * wv[13] + v1.z * wv[14] + v1.w * wv[15];
    aE1[idx] = s1;
    aE2[idx] = s2;
}

// ---- split fp32 -> bf16 hi/lo (flat, float4-vectorized) --------------------
__global__ void split_kernel(const float* __restrict__ in, u16* __restrict__ hi,
                             u16* __restrict__ lo, int n4) {
    int i = blockIdx.x * 256 + threadIdx.x;
    if (i >= n4) return;
    float4 v = ((const float4*)in)[i];
    u16x4 h, l;
    h.x = f2bf(v.x); l.x = f2bf(v.x - bf2f(h.x));
    h.y = f2bf(v.y); l.y = f2bf(v.y - bf2f(h.y));
    h.z = f2bf(v.z); l.z = f2bf(v.z - bf2f(h.z));
    h.w = f2bf(v.w); l.w = f2bf(v.w - bf2f(h.w));
    ((u16x4*)hi)[i] = h;
    ((u16x4*)lo)[i] = l;
}

// ---- transpose + split weights: t{hi,lo}[m*K+k] = split(W[k*M+m]) ----------
__global__ void wsplit_kernel(const float* __restrict__ W, u16* __restrict__ thi,
                              u16* __restrict__ tlo, int K, int M) {
    int idx = blockIdx.x * 256 + threadIdx.x;
    if (idx >= K * M) return;
    int k = idx / M, m = idx - k * M;
    float v = W[idx];
    u16 h = f2bf(v);
    u16 l = f2bf(v - bf2f(h));
    thi[(size_t)m * K + k] = h;
    tlo[(size_t)m * K + k] = l;
}

// ---- split-bf16 MFMA GEMM: C[N,M] = A[N,K] @ B[K,M] ------------------------
// A pre-split row-major [N][K] (hi/lo bf16), B pre-split TRANSPOSED [M][K].
// 64x64 tile, 4 waves; wave w computes rows [w*16,w*16+16) x 64 cols.
#define LDA 72   // 64 + 8 pad (ushorts) -> 2-way LDS bank aliasing only (free)
__global__ __launch_bounds__(256) void gemm_mfma_kernel(
        const u16* __restrict__ Ah_g, const u16* __restrict__ Al_g,
        const u16* __restrict__ Bh_g, const u16* __restrict__ Bl_g,
        float* __restrict__ C, int Nrows, int K, int M) {
    __shared__ u16 Ah[64 * LDA], Al[64 * LDA], Bh[64 * LDA], Bl[64 * LDA];
    int tid = threadIdx.x;
    int lane = tid & 63;
    int wv = tid >> 6;
    int l15 = lane & 15;
    int quad = lane >> 4;
    int rb = blockIdx.y * 64;
    int cb = blockIdx.x * 64;

    v4f acc[4];
#pragma unroll
    for (int nt = 0; nt < 4; ++nt) acc[nt] = (v4f){0.f, 0.f, 0.f, 0.f};

    int sr = tid >> 2;            // staging row 0..63
    int sc = (tid & 3) * 16;      // staging col 0..48

    for (int kc = 0; kc < K; kc += 64) {
        // stage A (rows rb..rb+64) and B (cols cb..cb+64), both [64][64] bf16 hi+lo
        {
            int gr = rb + sr;
            u16x8 z = {0, 0, 0, 0, 0, 0, 0, 0};
            u16x8 a0 = z, a1 = z, b0, b1;
            if (gr < Nrows) {
                const u16* pa = Ah_g + (size_t)gr * K + kc + sc;
                const u16* pl = Al_g + (size_t)gr * K + kc + sc;
                a0 = *(const u16x8*)pa;
                a1 = *(const u16x8*)pl;
            }
            const u16* pb = Bh_g + (size_t)(cb + sr) * K + kc + sc;
            const u16* pm = Bl_g + (size_t)(cb + sr) * K + kc + sc;
            b0 = *(const u16x8*)pb;
            b1 = *(const u16x8*)pm;
            *(u16x8*)&Ah[sr * LDA + sc] = a0;
            *(u16x8*)&Al[sr * LDA + sc] = a1;
            *(u16x8*)&Bh[sr * LDA + sc] = b0;
            *(u16x8*)&Bl[sr * LDA + sc] = b1;
            if (gr < Nrows) {
                a0 = *(const u16x8*)(Ah_g + (size_t)gr * K + kc + sc + 8);
                a1 = *(const u16x8*)(Al_g + (size_t)gr * K + kc + sc + 8);
            }
            b0 = *(const u16x8*)(Bh_g + (size_t)(cb + sr) * K + kc + sc + 8);
            b1 = *(const u16x8*)(Bl_g + (size_t)(cb + sr) * K + kc + sc + 8);
            *(u16x8*)&Ah[sr * LDA + sc + 8] = a0;
            *(u16x8*)&Al[sr * LDA + sc + 8] = a1;
            *(u16x8*)&Bh[sr * LDA + sc + 8] = b0;
            *(u16x8*)&Bl[sr * LDA + sc + 8] = b1;
        }
        __syncthreads();
#pragma unroll
        for (int kk = 0; kk < 2; ++kk) {
            int kb = kk * 32 + quad * 8;
            short8 ah = *(const short8*)&Ah[(wv * 16 + l15) * LDA + kb];
            short8 al = *(const short8*)&Al[(wv * 16 + l15) * LDA + kb];
#pragma unroll
            for (int nt = 0; nt < 4; ++nt) {
                short8 bh = *(const short8*)&Bh[(nt * 16 + l15) * LDA + kb];
                short8 bl = *(const short8*)&Bl[(nt * 16 + l15) * LDA + kb];
                acc[nt] = __builtin_amdgcn_mfma_f32_16x16x32_bf16(ah, bh, acc[nt], 0, 0, 0);
                acc[nt] = __builtin_amdgcn_mfma_f32_16x16x32_bf16(ah, bl, acc[nt], 0, 0, 0);
                acc[nt] = __builtin_amdgcn_mfma_f32_16x16x32_bf16(al, bh, acc[nt], 0, 0, 0);
            }
        }
        __syncthreads();
    }
    // C/D layout: col = lane&15, row = quad*4 + reg
#pragma unroll
    for (int nt = 0; nt < 4; ++nt) {
#pragma unroll
        for (int reg = 0; reg < 4; ++reg) {
            int row = rb + wv * 16 + quad * 4 + reg;
            if (row < Nrows)
                C[(size_t)row * M + cb + nt * 16 + l15] = acc[nt][reg];
        }
    }
}

// ---- a_s[i] = h[i].as, a_d[i] = h[i].ad  (one wave per row, 4 rows/block) --
__global__ void rowdot_kernel(const float* __restrict__ H,
                              const float* __restrict__ av, const float* __restrict__ bv,
                              float* __restrict__ as_out, float* __restrict__ ad_out,
                              int Nrows, int C) {
    int lane = threadIdx.x & 63;
    int wid = threadIdx.x >> 6;
    int row = blockIdx.x * 4 + wid;
    if (row >= Nrows) return;
    float s = 0.f, d = 0.f;
    for (int c = lane; c < C; c += 64) {
        float h = H[(size_t)row * C + c];
        s += h * av[c];
        d += h * bv[c];
    }
#pragma unroll
    for (int off = 32; off; off >>= 1) {
        s += __shfl_down(s, off);
        d += __shfl_down(d, off);
    }
    if (lane == 0) { as_out[row] = s; ad_out[row] = d; }
}

// ---- per-node segment softmax: one wave per node, CSR order ---------------
__global__ void softmax_kernel(const int* __restrict__ row_start, const int* __restrict__ csr_src,
                               const float* __restrict__ aE,
                               const float* __restrict__ a_s, const float* __restrict__ a_d,
                               const float* __restrict__ ae_loop, int which,
                               float* __restrict__ w, float* __restrict__ wself, int N) {
    int lane = threadIdx.x & 63;
    int wid = threadIdx.x >> 6;
    int node = blockIdx.x * 4 + wid;
    if (node >= N) return;
    int st = row_start[node], en = row_start[node + 1];
    float ad = a_d[node];
    float aloop = a_s[node] + ad + ae_loop[which];
    aloop = aloop >= 0.f ? aloop : NEG_SLOPE * aloop;
    float m = aloop;
    for (int i = st + lane; i < en; i += 64) {
        float al = a_s[csr_src[i]] + ad + aE[i];
        al = al >= 0.f ? al : NEG_SLOPE * al;
        w[i] = al;
        m = fmaxf(m, al);
    }
#pragma unroll
    for (int off = 32; off; off >>= 1) m = fmaxf(m, __shfl_down(m, off));
    m = __shfl(m, 0);
    float es = expf(aloop - m);
    float sum = (lane == 0) ? es : 0.f;
    for (int i = st + lane; i < en; i += 64) {
        float ex = expf(w[i] - m);
        w[i] = ex;
        sum += ex;
    }
#pragma unroll
    for (int off = 32; off; off >>= 1) sum += __shfl_down(sum, off);
    sum = __shfl(sum, 0);
    float inv = 1.f / sum;
    for (int i = st + lane; i < en; i += 64) w[i] *= inv;
    if (lane == 0) wself[node] = es * inv;
}

// ---- aggregation, wave-per-node, C=256: lane owns 4 cols (float4 gathers) --
// Epilogue: t = relu(acc + b1[c]); split to bf16 hi/lo (layer-2 GEMM input).
__global__ __launch_bounds__(256) void agg1_kernel(const int* __restrict__ row_start,
                                                   const int* __restrict__ csr_src,
                                                   const float* __restrict__ w,
                                                   const float* __restrict__ wself,
                                                   const float* __restrict__ H,
                                                   u16* __restrict__ ohi, u16* __restrict__ olo,
                                                   const float* __restrict__ bias, int N) {
    int lane = threadIdx.x & 63;
    int wv = threadIdx.x >> 6;
    int node = blockIdx.x * 4 + wv;
    if (node >= N) return;
    int st = row_start[node], en = row_start[node + 1];
    float acc0, acc1, acc2, acc3;
    {
        float wsf = wself[node];
        float4 hv = *(const float4*)(H + (size_t)node * 256 + lane * 4);
        acc0 = wsf * hv.x; acc1 = wsf * hv.y; acc2 = wsf * hv.z; acc3 = wsf * hv.w;
    }
    for (int base = st; base < en; base += 64) {
        int i = base + lane;
        int sreg = 0; float wreg = 0.f;
        if (i < en) { sreg = csr_src[i]; wreg = w[i]; }
        int cnt = min(64, en - base);
        int j = 0;
        for (; j + 4 <= cnt; j += 4) {
            int s0 = __shfl(sreg, j),     s1 = __shfl(sreg, j + 1);
            int s2 = __shfl(sreg, j + 2), s3 = __shfl(sreg, j + 3);
            float w0 = __shfl(wreg, j),     w1 = __shfl(wreg, j + 1);
            float w2 = __shfl(wreg, j + 2), w3 = __shfl(wreg, j + 3);
            float4 v0 = *(const float4*)(H + (size_t)s0 * 256 + lane * 4);
            float4 v1 = *(const float4*)(H + (size_t)s1 * 256 + lane * 4);
            float4 v2 = *(const float4*)(H + (size_t)s2 * 256 + lane * 4);
            float4 v3 = *(const float4*)(H + (size_t)s3 * 256 + lane * 4);
            acc0 += w0 * v0.x + w1 * v1.x + w2 * v2.x + w3 * v3.x;
            acc1 += w0 * v0.y + w1 * v1.y + w2 * v2.y + w3 * v3.y;
            acc2 += w0 * v0.z + w1 * v1.z + w2 * v2.z + w3 * v3.z;
            acc3 += w0 * v0.w + w1 * v1.w + w2 * v2.w + w3 * v3.w;
        }
        for (; j < cnt; ++j) {
            int s0 = __shfl(sreg, j);
            float w0 = __shfl(wreg, j);
            float4 v0 = *(const float4*)(H + (size_t)s0 * 256 + lane * 4);
            acc0 += w0 * v0.x; acc1 += w0 * v0.y; acc2 += w0 * v0.z; acc3 += w0 * v0.w;
        }
    }
    const float4 bv = *(const float4*)(bias + lane * 4);
    float t0 = acc0 + bv.x, t1 = acc1 + bv.y, t2 = acc2 + bv.z, t3 = acc3 + bv.w;
    t0 = t0 > 0.f ? t0 : 0.f; t1 = t1 > 0.f ? t1 : 0.f;
    t2 = t2 > 0.f ? t2 : 0.f; t3 = t3 > 0.f ? t3 : 0.f;
    u16x4 h, l;
    h.x = f2bf(t0); l.x = f2bf(t0 - bf2f(h.x));
    h.y = f2bf(t1); l.y = f2bf(t1 - bf2f(h.y));
    h.z = f2bf(t2); l.z = f2bf(t2 - bf2f(h.z));
    h.w = f2bf(t3); l.w = f2bf(t3 - bf2f(h.w));
    size_t o = (size_t)node * 256 + lane * 4;
    *(u16x4*)(ohi + o) = h;
    *(u16x4*)(olo + o) = l;
}

// ---- aggregation, wave-per-node, C=128: lane owns 2 cols (float2 gathers) --
// Epilogue: out = acc + b2[c] (final output).
__global__ __launch_bounds__(256) void agg2_kernel(const int* __restrict__ row_start,
                                                   const int* __restrict__ csr_src,
                                                   const float* __restrict__ w,
                                                   const float* __restrict__ wself,
                                                   const float* __restrict__ H,
                                                   float* __restrict__ out,
                                                   const float* __restrict__ bias, int N) {
    int lane = threadIdx.x & 63;
    int wv = threadIdx.x >> 6;
    int node = blockIdx.x * 4 + wv;
    if (node >= N) return;
    int st = row_start[node], en = row_start[node + 1];
    float acc0, acc1;
    {
        float wsf = wself[node];
        float2 hv = *(const float2*)(H + (size_t)node * 128 + lane * 2);
        acc0 = wsf * hv.x; acc1 = wsf * hv.y;
    }
    for (int base = st; base < en; base += 64) {
        int i = base + lane;
        int sreg = 0; float wreg = 0.f;
        if (i < en) { sreg = csr_src[i]; wreg = w[i]; }
        int cnt = min(64, en - base);
        int j = 0;
        for (; j + 4 <= cnt; j += 4) {
            int s0 = __shfl(sreg, j),     s1 = __shfl(sreg, j + 1);
            int s2 = __shfl(sreg, j + 2), s3 = __shfl(sreg, j + 3);
            float w0 = __shfl(wreg, j),     w1 = __shfl(wreg, j + 1);
            float w2 = __shfl(wreg, j + 2), w3 = __shfl(wreg, j + 3);
            float2 v0 = *(const float2*)(H + (size_t)s0 * 128 + lane * 2);
            float2 v1 = *(const float2*)(H + (size_t)s1 * 128 + lane * 2);
            float2 v2 = *(const float2*)(H + (size_t)s2 * 128 + lane * 2);
            float2 v3 = *(const float2*)(H + (size_t)s3 * 128 + lane * 2);
            acc0 += w0 * v0.x + w1 * v1.x + w2 * v2.x + w3 * v3.x;
            acc1 += w0 * v0.y + w1 * v1.y + w2 * v2.y + w3 * v3.y;
        }
        for (; j < cnt; ++j) {
            int s0 = __shfl(sreg, j);
            float w0 = __shfl(wreg, j);
            float2 v0 = *(const float2*)(H + (size_t)s0 * 128 + lane * 2);
            acc0 += w0 * v0.x; acc1 += w0 * v0.y;
        }
    }
    size_t o = (size_t)node * 128 + lane * 2;
    out[o]     = acc0 + bias[lane * 2];
    out[o + 1] = acc1 + bias[lane * 2 + 1];
}

extern "C" void kernel_launch(void* const* d_in, const int* in_sizes, int n_in,
                              void* d_out, int out_size, void* d_ws, size_t ws_size,
                              hipStream_t stream) {
    const int Cin = 128, Ch = 256, Co = 128;
    const int N = in_sizes[0] / Cin;        // 50000
    const int E = in_sizes[1] / 2;          // 800000

    const float* x   = (const float*)d_in[0];
    const int*   src = (const int*)d_in[1];
    const int*   dst = src + E;
    const float* ea  = (const float*)d_in[2];
    const float* W1  = (const float*)d_in[3];
    const float* We1 = (const float*)d_in[4];
    const float* as1 = (const float*)d_in[5];
    const float* ad1 = (const float*)d_in[6];
    const float* ae1 = (const float*)d_in[7];
    const float* b1  = (const float*)d_in[8];
    const float* W2  = (const float*)d_in[9];
    const float* We2 = (const float*)d_in[10];
    const float* as2 = (const float*)d_in[11];
    const float* ad2 = (const float*)d_in[12];
    const float* ae2 = (const float*)d_in[13];
    const float* b2  = (const float*)d_in[14];
    float* out = (float*)d_out;

    // workspace layout (4-byte units)
    float* ws = (float*)d_ws;
    size_t off = 0;
    float* h1    = ws + off; off += (size_t)N * Ch;      // fp32 h (reused as h2)
    // union region: x splits live here until gemm1 consumes them, then the
    // layer-1 output splits (g1hi/g1lo) overwrite the same space.
    float* ureg  = ws + off; off += (size_t)N * Ch / 2 * 2; // N*Ch ushorts *2 arrays = N*Ch units
    u16* xhi  = (u16*)ureg;                      // N*Cin ushorts
    u16* xlo  = xhi + (size_t)N * Cin;
    u16* g1hi = (u16*)ureg;                      // N*Ch ushorts
    u16* g1lo = g1hi + (size_t)N * Ch;
    float* aE1   = ws + off; off += (size_t)E;           // per-edge a_e, CSR order
    float* aE2   = ws + off; off += (size_t)E;
    float* wbuf  = ws + off; off += (size_t)E;           // softmax weights, CSR order
    float* wself = ws + off; off += (size_t)N;
    float* asv   = ws + off; off += (size_t)N;
    float* adv   = ws + off; off += (size_t)N;
    int* csr_src   = (int*)(ws + off); off += (size_t)E;
    int* deg       = (int*)(ws + off); off += (size_t)N + 1;
    int* row_start = (int*)(ws + off); off += (size_t)N + 1;
    int* cursor    = (int*)(ws + off); off += (size_t)N;
    int* bsum      = (int*)(ws + off); off += 256;
    u16* w1thi = (u16*)(ws + off); off += (size_t)Cin * Ch / 2;
    u16* w1tlo = (u16*)(ws + off); off += (size_t)Cin * Ch / 2;
    u16* w2thi = (u16*)(ws + off); off += (size_t)Ch * Co / 2;
    u16* w2tlo = (u16*)(ws + off); off += (size_t)Ch * Co / 2;
    float* misc  = ws + off; off += 32;  // [0:8) mean_acc, [8:16) we_vec1, [16:24) we_vec2, [24:26) ae_loop
    float* mean_acc = misc;
    float* we_vec1  = misc + 8;
    float* we_vec2  = misc + 16;
    float* ae_loop  = misc + 24;

    const int n1 = N + 1;
    const int nscan = (n1 + 255) / 256;   // scan blocks (<= 256)

    // zero what must be zero (ws is poisoned 0xAA before each timed call)
    hipMemsetAsync(deg, 0, (size_t)n1 * sizeof(int), stream);
    hipMemsetAsync(misc, 0, 32 * sizeof(float), stream);

    // ---- precompute: edge projections, CSR, input splits -------------------
    ea_mean_kernel<<<1024, 256, 0, stream>>>(ea, mean_acc, E);
    prep_kernel<<<1, 256, 0, stream>>>(We1, ae1, We2, ae2, mean_acc, 1.0f / (float)E,
                                       we_vec1, we_vec2, ae_loop, Ch, Co);
    hist_kernel<<<(E + 255) / 256, 256, 0, stream>>>(dst, deg, E);
    scan1_kernel<<<nscan, 256, 0, stream>>>(deg, row_start, bsum, N, n1);
    scan2_kernel<<<1, 256, 0, stream>>>(bsum, nscan);
    scan3_kernel<<<nscan, 256, 0, stream>>>(row_start, bsum, n1);
    hipMemcpyAsync(cursor, row_start, (size_t)N * sizeof(int),
                   hipMemcpyDeviceToDevice, stream);
    fill_kernel<<<(E + 255) / 256, 256, 0, stream>>>(src, dst, ea, we_vec1, we_vec2,
                                                     cursor, csr_src, aE1, aE2, E);
    split_kernel<<<((N * Cin / 4) + 255) / 256, 256, 0, stream>>>(x, xhi, xlo, N * Cin / 4);
    wsplit_kernel<<<(Cin * Ch + 255) / 256, 256, 0, stream>>>(W1, w1thi, w1tlo, Cin, Ch);
    wsplit_kernel<<<(Ch * Co + 255) / 256, 256, 0, stream>>>(W2, w2thi, w2tlo, Ch, Co);

    // ---- layer 1 ----------------------------------------------------------
    {
        dim3 grid(Ch / 64, (N + 63) / 64);
        gemm_mfma_kernel<<<grid, 256, 0, stream>>>(xhi, xlo, w1thi, w1tlo, h1, N, Cin, Ch);
    }
    rowdot_kernel<<<(N + 3) / 4, 256, 0, stream>>>(h1, as1, ad1, asv, adv, N, Ch);
    softmax_kernel<<<(N + 3) / 4, 256, 0, stream>>>(row_start, csr_src, aE1, asv, adv,
                                                    ae_loop, 0, wbuf, wself, N);
    agg1_kernel<<<(N + 3) / 4, 256, 0, stream>>>(row_start, csr_src, wbuf, wself, h1,
                                                 g1hi, g1lo, b1, N);

    // ---- layer 2 ----------------------------------------------------------
    float* h2 = h1; // reuse (agg1 has already consumed h1)
    {
        dim3 grid(Co / 64, (N + 63) / 64);
        gemm_mfma_kernel<<<grid, 256, 0, stream>>>(g1hi, g1lo, w2thi, w2tlo, h2, N, Ch, Co);
    }
    rowdot_kernel<<<(N + 3) / 4, 256, 0, stream>>>(h2, as2, ad2, asv, adv, N, Co);
    softmax_kernel<<<(N + 3) / 4, 256, 0, stream>>>(row_start, csr_src, aE2, asv, adv,
                                                    ae_loop, 1, wbuf, wself, N);
    agg2_kernel<<<(N + 3) / 4, 256, 0, stream>>>(row_start, csr_src, wbuf, wself, h2,
                                                 out, b2, N);
}

// Round 4
// 457.758 us; speedup vs baseline: 3.3163x; 1.2081x over previous
//
#include <hip/hip_runtime.h>
#include <hip/hip_bf16.h>

// ---------------------------------------------------------------------------
// 2-layer GATConv (heads=1). N=50000, E=800000, Cin=128, Ch=256, Co=128, Ed=8.
// CSR-by-dst gather softmax/aggregation (no hot-path atomics),
// split-bf16 MFMA GEMMs (3-term => ~fp32), h stored bf16 to halve gather BW.
// ---------------------------------------------------------------------------

#define NEG_SLOPE 0.2f

typedef unsigned short u16;
typedef short short8 __attribute__((ext_vector_type(8)));
typedef float v4f __attribute__((ext_vector_type(4)));
typedef u16 u16x2 __attribute__((ext_vector_type(2)));
typedef u16 u16x4 __attribute__((ext_vector_type(4)));
typedef u16 u16x8 __attribute__((ext_vector_type(8)));

__device__ __forceinline__ u16 f2bf(float f) {
    unsigned u = __float_as_uint(f);
    return (u16)((u + 0x7fffu + ((u >> 16) & 1u)) >> 16);
}
__device__ __forceinline__ float bf2f(u16 h) {
    return __uint_as_float(((unsigned)h) << 16);
}

// ---- fused: edge_attr column sums + dst-degree histogram -------------------
__global__ void ea_hist_kernel(const float* __restrict__ ea, const int* __restrict__ dst,
                               float* __restrict__ acc, int* __restrict__ deg, int E) {
    __shared__ float red[8];
    int tid = threadIdx.x;
    if (tid < 8) red[tid] = 0.f;
    __syncthreads();
    float s[8] = {0.f};
    int stride = gridDim.x * blockDim.x;
    for (int e = blockIdx.x * blockDim.x + tid; e < E; e += stride) {
        atomicAdd(&deg[dst[e]], 1);
        const float4 v0 = *(const float4*)&ea[(size_t)e * 8];
        const float4 v1 = *(const float4*)&ea[(size_t)e * 8 + 4];
        s[0] += v0.x; s[1] += v0.y; s[2] += v0.z; s[3] += v0.w;
        s[4] += v1.x; s[5] += v1.y; s[6] += v1.z; s[7] += v1.w;
    }
#pragma unroll
    for (int j = 0; j < 8; ++j) atomicAdd(&red[j], s[j]);
    __syncthreads();
    if (tid < 8) atomicAdd(&acc[tid], red[tid]);
}

// ---- we_vec{1,2}[j] = sum_k We[j,k]*a_edge[k]; ae_loop = mean_ea . we_vec --
__global__ void prep_kernel(const float* __restrict__ We1, const float* __restrict__ ae1v,
                            const float* __restrict__ We2, const float* __restrict__ ae2v,
                            const float* __restrict__ mean_acc, float Einv,
                            float* __restrict__ we_vec1, float* __restrict__ we_vec2,
                            float* __restrict__ ae_loop, int Ch, int Co) {
    __shared__ float red[256];
    int t = threadIdx.x;
    for (int j = 0; j < 8; ++j) {
        float s = 0.f;
        for (int k = t; k < Ch; k += 256) s += We1[j * Ch + k] * ae1v[k];
        red[t] = s; __syncthreads();
        for (int off = 128; off; off >>= 1) { if (t < off) red[t] += red[t + off]; __syncthreads(); }
        if (t == 0) we_vec1[j] = red[0];
        __syncthreads();
        s = 0.f;
        for (int k = t; k < Co; k += 256) s += We2[j * Co + k] * ae2v[k];
        red[t] = s; __syncthreads();
        for (int off = 128; off; off >>= 1) { if (t < off) red[t] += red[t + off]; __syncthreads(); }
        if (t == 0) we_vec2[j] = red[0];
        __syncthreads();
    }
    if (t == 0) {
        float s1 = 0.f, s2 = 0.f;
        for (int j = 0; j < 8; ++j) {
            float m = mean_acc[j] * Einv;
            s1 += m * we_vec1[j];
            s2 += m * we_vec2[j];
        }
        ae_loop[0] = s1; ae_loop[1] = s2;
    }
}

// ---- 3-pass exclusive scan over n = N+1 elements ---------------------------
__global__ void scan1_kernel(const int* __restrict__ deg, int* __restrict__ out,
                             int* __restrict__ bsum, int N, int n) {
    __shared__ int s[256];
    int t = threadIdx.x;
    int i = blockIdx.x * 256 + t;
    int v = (i < N) ? deg[i] : 0;
    s[t] = v; __syncthreads();
    for (int off = 1; off < 256; off <<= 1) {
        int u = (t >= off) ? s[t - off] : 0;
        __syncthreads();
        s[t] += u;
        __syncthreads();
    }
    if (i < n) out[i] = s[t] - v;
    if (t == 255) bsum[blockIdx.x] = s[255];
}

__global__ void scan2_kernel(int* __restrict__ bsum, int nb) {
    __shared__ int s[256];
    int t = threadIdx.x;
    int v = (t < nb) ? bsum[t] : 0;
    s[t] = v; __syncthreads();
    for (int off = 1; off < 256; off <<= 1) {
        int u = (t >= off) ? s[t - off] : 0;
        __syncthreads();
        s[t] += u;
        __syncthreads();
    }
    if (t < nb) bsum[t] = s[t] - v;
}

// scan3 also initializes the fill cursor (saves a d2d copy)
__global__ void scan3_kernel(int* __restrict__ out, int* __restrict__ cursor,
                             const int* __restrict__ bsum, int n, int N) {
    int i = blockIdx.x * 256 + threadIdx.x;
    if (i < n) {
        int v = out[i] + bsum[blockIdx.x];
        out[i] = v;
        if (i < N) cursor[i] = v;
    }
}

// ---- CSR fill + fused per-edge a_e (both layers) into CSR order ------------
__global__ void fill_kernel(const int* __restrict__ src, const int* __restrict__ dst,
                            const float* __restrict__ ea,
                            const float* __restrict__ we_vec1, const float* __restrict__ we_vec2,
                            int* __restrict__ cursor, int* __restrict__ csr_src,
                            float* __restrict__ aE1, float* __restrict__ aE2, int E) {
    __shared__ float wv[16];
    if (threadIdx.x < 8) wv[threadIdx.x] = we_vec1[threadIdx.x];
    else if (threadIdx.x < 16) wv[threadIdx.x] = we_vec2[threadIdx.x - 8];
    __syncthreads();
    int e = blockIdx.x * blockDim.x + threadIdx.x;
    if (e >= E) return;
    int d = dst[e];
    int idx = atomicAdd(&cursor[d], 1);
    csr_src[idx] = src[e];
    const float4 v0 = *(const float4*)&ea[(size_t)e * 8];
    const float4 v1 = *(const float4*)&ea[(size_t)e * 8 + 4];
    float s1 = v0.x * wv[0] + v0.y * wv[1] + v0.z * wv[2] + v0.w * wv[3]
             + v1.x * wv[4] + v1.y * wv[5] + v1.z * wv[6] + v1.w * wv[7];
    float s2 = v0.x * wv[8] + v0.y * wv[9] + v0.z * wv[10] + v0.w * wv[11]
             + v1.x * wv[12] + v1.y * wv[13] + v1.z * wv[14] + v1.w * wv[15];
    aE1[idx] = s1;
    aE2[idx] = s2;
}

// ---- split fp32 -> bf16 hi/lo (flat, float4-vectorized) --------------------
__global__ void split_kernel(const float* __restrict__ in, u16* __restrict__ hi,
                             u16* __restrict__ lo, int n4) {
    int i = blockIdx.x * 256 + threadIdx.x;
    if (i >= n4) return;
    float4 v = ((const float4*)in)[i];
    u16x4 h, l;
    h.x = f2bf(v.x); l.x = f2bf(v.x - bf2f(h.x));
    h.y = f2bf(v.y); l.y = f2bf(v.y - bf2f(h.y));
    h.z = f2bf(v.z); l.z = f2bf(v.z - bf2f(h.z));
    h.w = f2bf(v.w); l.w = f2bf(v.w - bf2f(h.w));
    ((u16x4*)hi)[i] = h;
    ((u16x4*)lo)[i] = l;
}

// ---- transpose + split weights: t{hi,lo}[m*K+k] = split(W[k*M+m]) ----------
__global__ void wsplit_kernel(const float* __restrict__ W, u16* __restrict__ thi,
                              u16* __restrict__ tlo, int K, int M) {
    int idx = blockIdx.x * 256 + threadIdx.x;
    if (idx >= K * M) return;
    int k = idx / M, m = idx - k * M;
    float v = W[idx];
    u16 h = f2bf(v);
    u16 l = f2bf(v - bf2f(h));
    thi[(size_t)m * K + k] = h;
    tlo[(size_t)m * K + k] = l;
}

// ---- split-bf16 MFMA GEMM: Cb[N,M] = bf16(A[N,K] @ B[K,M]) -----------------
// A pre-split row-major [N][K] (hi/lo bf16), B pre-split TRANSPOSED [M][K].
// 64x64 tile, 4 waves; wave w computes rows [w*16,w*16+16) x 64 cols.
// Output stored as bf16 (consumers gather it; halves their traffic).
#define LDA 72
__global__ __launch_bounds__(256) void gemm_mfma_kernel(
        const u16* __restrict__ Ah_g, const u16* __restrict__ Al_g,
        const u16* __restrict__ Bh_g, const u16* __restrict__ Bl_g,
        u16* __restrict__ Cb, int Nrows, int K, int M) {
    __shared__ u16 Ah[64 * LDA], Al[64 * LDA], Bh[64 * LDA], Bl[64 * LDA];
    int tid = threadIdx.x;
    int lane = tid & 63;
    int wv = tid >> 6;
    int l15 = lane & 15;
    int quad = lane >> 4;
    int rb = blockIdx.y * 64;
    int cb = blockIdx.x * 64;

    v4f acc[4];
#pragma unroll
    for (int nt = 0; nt < 4; ++nt) acc[nt] = (v4f){0.f, 0.f, 0.f, 0.f};

    int sr = tid >> 2;            // staging row 0..63
    int sc = (tid & 3) * 16;      // staging col 0..48

    for (int kc = 0; kc < K; kc += 64) {
        {
            int gr = rb + sr;
            u16x8 z = {0, 0, 0, 0, 0, 0, 0, 0};
            u16x8 a0 = z, a1 = z, b0, b1;
            if (gr < Nrows) {
                a0 = *(const u16x8*)(Ah_g + (size_t)gr * K + kc + sc);
                a1 = *(const u16x8*)(Al_g + (size_t)gr * K + kc + sc);
            }
            b0 = *(const u16x8*)(Bh_g + (size_t)(cb + sr) * K + kc + sc);
            b1 = *(const u16x8*)(Bl_g + (size_t)(cb + sr) * K + kc + sc);
            *(u16x8*)&Ah[sr * LDA + sc] = a0;
            *(u16x8*)&Al[sr * LDA + sc] = a1;
            *(u16x8*)&Bh[sr * LDA + sc] = b0;
            *(u16x8*)&Bl[sr * LDA + sc] = b1;
            if (gr < Nrows) {
                a0 = *(const u16x8*)(Ah_g + (size_t)gr * K + kc + sc + 8);
                a1 = *(const u16x8*)(Al_g + (size_t)gr * K + kc + sc + 8);
            }
            b0 = *(const u16x8*)(Bh_g + (size_t)(cb + sr) * K + kc + sc + 8);
            b1 = *(const u16x8*)(Bl_g + (size_t)(cb + sr) * K + kc + sc + 8);
            *(u16x8*)&Ah[sr * LDA + sc + 8] = a0;
            *(u16x8*)&Al[sr * LDA + sc + 8] = a1;
            *(u16x8*)&Bh[sr * LDA + sc + 8] = b0;
            *(u16x8*)&Bl[sr * LDA + sc + 8] = b1;
        }
        __syncthreads();
#pragma unroll
        for (int kk = 0; kk < 2; ++kk) {
            int kb = kk * 32 + quad * 8;
            short8 ah = *(const short8*)&Ah[(wv * 16 + l15) * LDA + kb];
            short8 al = *(const short8*)&Al[(wv * 16 + l15) * LDA + kb];
#pragma unroll
            for (int nt = 0; nt < 4; ++nt) {
                short8 bh = *(const short8*)&Bh[(nt * 16 + l15) * LDA + kb];
                short8 bl = *(const short8*)&Bl[(nt * 16 + l15) * LDA + kb];
                acc[nt] = __builtin_amdgcn_mfma_f32_16x16x32_bf16(ah, bh, acc[nt], 0, 0, 0);
                acc[nt] = __builtin_amdgcn_mfma_f32_16x16x32_bf16(ah, bl, acc[nt], 0, 0, 0);
                acc[nt] = __builtin_amdgcn_mfma_f32_16x16x32_bf16(al, bh, acc[nt], 0, 0, 0);
            }
        }
        __syncthreads();
    }
    // C/D layout: col = lane&15, row = quad*4 + reg
#pragma unroll
    for (int nt = 0; nt < 4; ++nt) {
#pragma unroll
        for (int reg = 0; reg < 4; ++reg) {
            int row = rb + wv * 16 + quad * 4 + reg;
            if (row < Nrows)
                Cb[(size_t)row * M + cb + nt * 16 + l15] = f2bf(acc[nt][reg]);
        }
    }
}

// ---- a_s[i] = h[i].as, a_d[i] = h[i].ad; h is bf16, lane owns C/64 cols ----
template <int C>
__global__ void rowdot_kernel(const u16* __restrict__ Hb,
                              const float* __restrict__ av, const float* __restrict__ bv,
                              float* __restrict__ as_out, float* __restrict__ ad_out,
                              int Nrows) {
    constexpr int V = C / 64;
    int lane = threadIdx.x & 63;
    int wid = threadIdx.x >> 6;
    int row = blockIdx.x * 4 + wid;
    if (row >= Nrows) return;
    float s = 0.f, d = 0.f;
    const u16* p = Hb + (size_t)row * C + lane * V;
#pragma unroll
    for (int v = 0; v < V; ++v) {
        float h = bf2f(p[v]);
        s += h * av[lane * V + v];
        d += h * bv[lane * V + v];
    }
#pragma unroll
    for (int off = 32; off; off >>= 1) {
        s += __shfl_down(s, off);
        d += __shfl_down(d, off);
    }
    if (lane == 0) { as_out[row] = s; ad_out[row] = d; }
}

// ---- per-node segment softmax: one wave per node, CSR order ---------------
__global__ void softmax_kernel(const int* __restrict__ row_start, const int* __restrict__ csr_src,
                               const float* __restrict__ aE,
                               const float* __restrict__ a_s, const float* __restrict__ a_d,
                               const float* __restrict__ ae_loop, int which,
                               float* __restrict__ w, float* __restrict__ wself, int N) {
    int lane = threadIdx.x & 63;
    int wid = threadIdx.x >> 6;
    int node = blockIdx.x * 4 + wid;
    if (node >= N) return;
    int st = row_start[node], en = row_start[node + 1];
    float ad = a_d[node];
    float aloop = a_s[node] + ad + ae_loop[which];
    aloop = aloop >= 0.f ? aloop : NEG_SLOPE * aloop;
    float m = aloop;
    for (int i = st + lane; i < en; i += 64) {
        float al = a_s[csr_src[i]] + ad + aE[i];
        al = al >= 0.f ? al : NEG_SLOPE * al;
        w[i] = al;
        m = fmaxf(m, al);
    }
#pragma unroll
    for (int off = 32; off; off >>= 1) m = fmaxf(m, __shfl_down(m, off));
    m = __shfl(m, 0);
    float es = expf(aloop - m);
    float sum = (lane == 0) ? es : 0.f;
    for (int i = st + lane; i < en; i += 64) {
        float ex = expf(w[i] - m);
        w[i] = ex;
        sum += ex;
    }
#pragma unroll
    for (int off = 32; off; off >>= 1) sum += __shfl_down(sum, off);
    sum = __shfl(sum, 0);
    float inv = 1.f / sum;
    for (int i = st + lane; i < en; i += 64) w[i] *= inv;
    if (lane == 0) wself[node] = es * inv;
}

// ---- aggregation L1, wave-per-node, C=256: lane owns 4 cols (bf16 gathers) -
// Epilogue: t = relu(acc + b1[c]); split to bf16 hi/lo (layer-2 GEMM input).
__global__ __launch_bounds__(256) void agg1_kernel(const int* __restrict__ row_start,
                                                   const int* __restrict__ csr_src,
                                                   const float* __restrict__ w,
                                                   const float* __restrict__ wself,
                                                   const u16* __restrict__ Hb,
                                                   u16* __restrict__ ohi, u16* __restrict__ olo,
                                                   const float* __restrict__ bias, int N) {
    int lane = threadIdx.x & 63;
    int wv = threadIdx.x >> 6;
    int node = blockIdx.x * 4 + wv;
    if (node >= N) return;
    int st = row_start[node], en = row_start[node + 1];
    float acc0, acc1, acc2, acc3;
    {
        float wsf = wself[node];
        u16x4 hv = *(const u16x4*)(Hb + (size_t)node * 256 + lane * 4);
        acc0 = wsf * bf2f(hv.x); acc1 = wsf * bf2f(hv.y);
        acc2 = wsf * bf2f(hv.z); acc3 = wsf * bf2f(hv.w);
    }
    for (int base = st; base < en; base += 64) {
        int i = base + lane;
        int sreg = 0; float wreg = 0.f;
        if (i < en) { sreg = csr_src[i]; wreg = w[i]; }
        int cnt = min(64, en - base);
        int j = 0;
        for (; j + 8 <= cnt; j += 8) {
            int s[8]; float wt[8];
#pragma unroll
            for (int q = 0; q < 8; ++q) { s[q] = __shfl(sreg, j + q); wt[q] = __shfl(wreg, j + q); }
            u16x4 v[8];
#pragma unroll
            for (int q = 0; q < 8; ++q) v[q] = *(const u16x4*)(Hb + (size_t)s[q] * 256 + lane * 4);
#pragma unroll
            for (int q = 0; q < 8; ++q) {
                acc0 += wt[q] * bf2f(v[q].x); acc1 += wt[q] * bf2f(v[q].y);
                acc2 += wt[q] * bf2f(v[q].z); acc3 += wt[q] * bf2f(v[q].w);
            }
        }
        for (; j < cnt; ++j) {
            int s0 = __shfl(sreg, j);
            float w0 = __shfl(wreg, j);
            u16x4 v0 = *(const u16x4*)(Hb + (size_t)s0 * 256 + lane * 4);
            acc0 += w0 * bf2f(v0.x); acc1 += w0 * bf2f(v0.y);
            acc2 += w0 * bf2f(v0.z); acc3 += w0 * bf2f(v0.w);
        }
    }
    const float4 bv = *(const float4*)(bias + lane * 4);
    float t0 = acc0 + bv.x, t1 = acc1 + bv.y, t2 = acc2 + bv.z, t3 = acc3 + bv.w;
    t0 = t0 > 0.f ? t0 : 0.f; t1 = t1 > 0.f ? t1 : 0.f;
    t2 = t2 > 0.f ? t2 : 0.f; t3 = t3 > 0.f ? t3 : 0.f;
    u16x4 h, l;
    h.x = f2bf(t0); l.x = f2bf(t0 - bf2f(h.x));
    h.y = f2bf(t1); l.y = f2bf(t1 - bf2f(h.y));
    h.z = f2bf(t2); l.z = f2bf(t2 - bf2f(h.z));
    h.w = f2bf(t3); l.w = f2bf(t3 - bf2f(h.w));
    size_t o = (size_t)node * 256 + lane * 4;
    *(u16x4*)(ohi + o) = h;
    *(u16x4*)(olo + o) = l;
}

// ---- aggregation L2, wave-per-node, C=128: lane owns 2 cols (bf16 gathers) -
// Epilogue: out = acc + b2[c] (final fp32 output).
__global__ __launch_bounds__(256) void agg2_kernel(const int* __restrict__ row_start,
                                                   const int* __restrict__ csr_src,
                                                   const float* __restrict__ w,
                                                   const float* __restrict__ wself,
                                                   const u16* __restrict__ Hb,
                                                   float* __restrict__ out,
                                                   const float* __restrict__ bias, int N) {
    int lane = threadIdx.x & 63;
    int wv = threadIdx.x >> 6;
    int node = blockIdx.x * 4 + wv;
    if (node >= N) return;
    int st = row_start[node], en = row_start[node + 1];
    float acc0, acc1;
    {
        float wsf = wself[node];
        u16x2 hv = *(const u16x2*)(Hb + (size_t)node * 128 + lane * 2);
        acc0 = wsf * bf2f(hv.x); acc1 = wsf * bf2f(hv.y);
    }
    for (int base = st; base < en; base += 64) {
        int i = base + lane;
        int sreg = 0; float wreg = 0.f;
        if (i < en) { sreg = csr_src[i]; wreg = w[i]; }
        int cnt = min(64, en - base);
        int j = 0;
        for (; j + 8 <= cnt; j += 8) {
            int s[8]; float wt[8];
#pragma unroll
            for (int q = 0; q < 8; ++q) { s[q] = __shfl(sreg, j + q); wt[q] = __shfl(wreg, j + q); }
            u16x2 v[8];
#pragma unroll
            for (int q = 0; q < 8; ++q) v[q] = *(const u16x2*)(Hb + (size_t)s[q] * 128 + lane * 2);
#pragma unroll
            for (int q = 0; q < 8; ++q) {
                acc0 += wt[q] * bf2f(v[q].x); acc1 += wt[q] * bf2f(v[q].y);
            }
        }
        for (; j < cnt; ++j) {
            int s0 = __shfl(sreg, j);
            float w0 = __shfl(wreg, j);
            u16x2 v0 = *(const u16x2*)(Hb + (size_t)s0 * 128 + lane * 2);
            acc0 += w0 * bf2f(v0.x); acc1 += w0 * bf2f(v0.y);
        }
    }
    size_t o = (size_t)node * 128 + lane * 2;
    out[o]     = acc0 + bias[lane * 2];
    out[o + 1] = acc1 + bias[lane * 2 + 1];
}

extern "C" void kernel_launch(void* const* d_in, const int* in_sizes, int n_in,
                              void* d_out, int out_size, void* d_ws, size_t ws_size,
                              hipStream_t stream) {
    const int Cin = 128, Ch = 256, Co = 128;
    const int N = in_sizes[0] / Cin;        // 50000
    const int E = in_sizes[1] / 2;          // 800000

    const float* x   = (const float*)d_in[0];
    const int*   src = (const int*)d_in[1];
    const int*   dst = src + E;
    const float* ea  = (const float*)d_in[2];
    const float* W1  = (const float*)d_in[3];
    const float* We1 = (const float*)d_in[4];
    const float* as1 = (const float*)d_in[5];
    const float* ad1 = (const float*)d_in[6];
    const float* ae1 = (const float*)d_in[7];
    const float* b1  = (const float*)d_in[8];
    const float* W2  = (const float*)d_in[9];
    const float* We2 = (const float*)d_in[10];
    const float* as2 = (const float*)d_in[11];
    const float* ad2 = (const float*)d_in[12];
    const float* ae2 = (const float*)d_in[13];
    const float* b2  = (const float*)d_in[14];
    float* out = (float*)d_out;

    // workspace layout (4-byte units)
    float* ws = (float*)d_ws;
    size_t off = 0;
    u16* h1b = (u16*)(ws + off); off += (size_t)N * Ch / 2;   // bf16 h (reused as h2b)
    // union region: x splits live here until gemm1 consumes them, then the
    // layer-1 output splits (g1hi/g1lo) overwrite the same space.
    float* ureg  = ws + off; off += (size_t)N * Ch;           // N*Ch ushorts * 2 arrays
    u16* xhi  = (u16*)ureg;                                   // N*Cin ushorts
    u16* xlo  = xhi + (size_t)N * Cin;
    u16* g1hi = (u16*)ureg;                                   // N*Ch ushorts
    u16* g1lo = g1hi + (size_t)N * Ch;
    float* aE1   = ws + off; off += (size_t)E;                // per-edge a_e, CSR order
    float* aE2   = ws + off; off += (size_t)E;
    float* wbuf  = ws + off; off += (size_t)E;                // softmax weights, CSR order
    float* wself = ws + off; off += (size_t)N;
    float* asv   = ws + off; off += (size_t)N;
    float* adv   = ws + off; off += (size_t)N;
    int* csr_src   = (int*)(ws + off); off += (size_t)E;
    int* deg       = (int*)(ws + off); off += (size_t)N + 1;
    int* row_start = (int*)(ws + off); off += (size_t)N + 1;
    int* cursor    = (int*)(ws + off); off += (size_t)N;
    int* bsum      = (int*)(ws + off); off += 256;
    u16* w1thi = (u16*)(ws + off); off += (size_t)Cin * Ch / 2;
    u16* w1tlo = (u16*)(ws + off); off += (size_t)Cin * Ch / 2;
    u16* w2thi = (u16*)(ws + off); off += (size_t)Ch * Co / 2;
    u16* w2tlo = (u16*)(ws + off); off += (size_t)Ch * Co / 2;
    float* misc  = ws + off; off += 32;  // [0:8) mean_acc, [8:16) we_vec1, [16:24) we_vec2, [24:26) ae_loop
    float* mean_acc = misc;
    float* we_vec1  = misc + 8;
    float* we_vec2  = misc + 16;
    float* ae_loop  = misc + 24;

    const int n1 = N + 1;
    const int nscan = (n1 + 255) / 256;   // scan blocks (<= 256)

    // zero what must be zero (ws is poisoned 0xAA before each timed call)
    hipMemsetAsync(deg, 0, (size_t)n1 * sizeof(int), stream);
    hipMemsetAsync(misc, 0, 32 * sizeof(float), stream);

    // ---- precompute: edge projections, CSR, input splits -------------------
    ea_hist_kernel<<<1024, 256, 0, stream>>>(ea, dst, mean_acc, deg, E);
    prep_kernel<<<1, 256, 0, stream>>>(We1, ae1, We2, ae2, mean_acc, 1.0f / (float)E,
                                       we_vec1, we_vec2, ae_loop, Ch, Co);
    scan1_kernel<<<nscan, 256, 0, stream>>>(deg, row_start, bsum, N, n1);
    scan2_kernel<<<1, 256, 0, stream>>>(bsum, nscan);
    scan3_kernel<<<nscan, 256, 0, stream>>>(row_start, cursor, bsum, n1, N);
    fill_kernel<<<(E + 255) / 256, 256, 0, stream>>>(src, dst, ea, we_vec1, we_vec2,
                                                     cursor, csr_src, aE1, aE2, E);
    split_kernel<<<((N * Cin / 4) + 255) / 256, 256, 0, stream>>>(x, xhi, xlo, N * Cin / 4);
    wsplit_kernel<<<(Cin * Ch + 255) / 256, 256, 0, stream>>>(W1, w1thi, w1tlo, Cin, Ch);
    wsplit_kernel<<<(Ch * Co + 255) / 256, 256, 0, stream>>>(W2, w2thi, w2tlo, Ch, Co);

    // ---- layer 1 ----------------------------------------------------------
    {
        dim3 grid(Ch / 64, (N + 63) / 64);
        gemm_mfma_kernel<<<grid, 256, 0, stream>>>(xhi, xlo, w1thi, w1tlo, h1b, N, Cin, Ch);
    }
    rowdot_kernel<256><<<(N + 3) / 4, 256, 0, stream>>>(h1b, as1, ad1, asv, adv, N);
    softmax_kernel<<<(N + 3) / 4, 256, 0, stream>>>(row_start, csr_src, aE1, asv, adv,
                                                    ae_loop, 0, wbuf, wself, N);
    agg1_kernel<<<(N + 3) / 4, 256, 0, stream>>>(row_start, csr_src, wbuf, wself, h1b,
                                                 g1hi, g1lo, b1, N);

    // ---- layer 2 ----------------------------------------------------------
    u16* h2b = h1b; // reuse (agg1 has already consumed h1b)
    {
        dim3 grid(Co / 64, (N + 63) / 64);
        gemm_mfma_kernel<<<grid, 256, 0, stream>>>(g1hi, g1lo, w2thi, w2tlo, h2b, N, Ch, Co);
    }
    rowdot_kernel<128><<<(N + 3) / 4, 256, 0, stream>>>(h2b, as2, ad2, asv, adv, N);
    softmax_kernel<<<(N + 3) / 4, 256, 0, stream>>>(row_start, csr_src, aE2, asv, adv,
                                                    ae_loop, 1, wbuf, wself, N);
    agg2_kernel<<<(N + 3) / 4, 256, 0, stream>>>(row_start, csr_src, wbuf, wself, h2b,
                                                 out, b2, N);
}

// Round 5
// 434.913 us; speedup vs baseline: 3.4905x; 1.0525x over previous
//
#include <hip/hip_runtime.h>
#include <hip/hip_bf16.h>

// ---------------------------------------------------------------------------
// 2-layer GATConv (heads=1). N=50000, E=800000, Cin=128, Ch=256, Co=128, Ed=8.
// CSR-by-dst gather with ONLINE-SOFTMAX fused into aggregation (no hot-path
// atomics, no wbuf), packed 16B edge structs {src, ae1, ae2}, split-bf16 MFMA
// GEMMs (3-term => ~fp32) with fused attention row-dots in the epilogue.
// ---------------------------------------------------------------------------

#define NEG_SLOPE 0.2f

typedef unsigned short u16;
typedef short short8 __attribute__((ext_vector_type(8)));
typedef float v4f __attribute__((ext_vector_type(4)));
typedef u16 u16x2 __attribute__((ext_vector_type(2)));
typedef u16 u16x4 __attribute__((ext_vector_type(4)));
typedef u16 u16x8 __attribute__((ext_vector_type(8)));

__device__ __forceinline__ u16 f2bf(float f) {
    unsigned u = __float_as_uint(f);
    return (u16)((u + 0x7fffu + ((u >> 16) & 1u)) >> 16);
}
__device__ __forceinline__ float bf2f(u16 h) {
    return __uint_as_float(((unsigned)h) << 16);
}
__device__ __forceinline__ float lrelu(float x) {
    return x >= 0.f ? x : NEG_SLOPE * x;
}

// ---- we_vec{1,2}[j] = sum_k We[j,k]*a_edge[k]  (params only, runs first) ---
__global__ void prep_kernel(const float* __restrict__ We1, const float* __restrict__ ae1v,
                            const float* __restrict__ We2, const float* __restrict__ ae2v,
                            float* __restrict__ we_vec1, float* __restrict__ we_vec2,
                            int Ch, int Co) {
    __shared__ float red[256];
    int t = threadIdx.x;
    for (int j = 0; j < 8; ++j) {
        float s = 0.f;
        for (int k = t; k < Ch; k += 256) s += We1[j * Ch + k] * ae1v[k];
        red[t] = s; __syncthreads();
        for (int off = 128; off; off >>= 1) { if (t < off) red[t] += red[t + off]; __syncthreads(); }
        if (t == 0) we_vec1[j] = red[0];
        __syncthreads();
        s = 0.f;
        for (int k = t; k < Co; k += 256) s += We2[j * Co + k] * ae2v[k];
        red[t] = s; __syncthreads();
        for (int off = 128; off; off >>= 1) { if (t < off) red[t] += red[t + off]; __syncthreads(); }
        if (t == 0) we_vec2[j] = red[0];
        __syncthreads();
    }
}

// ---- fused: edge_attr col sums + dst histogram + per-edge a_e (edge order) -
__global__ void ea_hist_kernel(const float* __restrict__ ea, const int* __restrict__ dst,
                               const float* __restrict__ we_vec1, const float* __restrict__ we_vec2,
                               float* __restrict__ acc, int* __restrict__ deg,
                               float2* __restrict__ aEe, int E) {
    __shared__ float red[8];
    __shared__ float wv[16];
    int tid = threadIdx.x;
    if (tid < 8) { red[tid] = 0.f; wv[tid] = we_vec1[tid]; }
    else if (tid < 16) wv[tid] = we_vec2[tid - 8];
    __syncthreads();
    float s[8] = {0.f};
    int stride = gridDim.x * blockDim.x;
    for (int e = blockIdx.x * blockDim.x + tid; e < E; e += stride) {
        atomicAdd(&deg[dst[e]], 1);
        const float4 v0 = *(const float4*)&ea[(size_t)e * 8];
        const float4 v1 = *(const float4*)&ea[(size_t)e * 8 + 4];
        s[0] += v0.x; s[1] += v0.y; s[2] += v0.z; s[3] += v0.w;
        s[4] += v1.x; s[5] += v1.y; s[6] += v1.z; s[7] += v1.w;
        float s1 = v0.x * wv[0] + v0.y * wv[1] + v0.z * wv[2] + v0.w * wv[3]
                 + v1.x * wv[4] + v1.y * wv[5] + v1.z * wv[6] + v1.w * wv[7];
        float s2 = v0.x * wv[8] + v0.y * wv[9] + v0.z * wv[10] + v0.w * wv[11]
                 + v1.x * wv[12] + v1.y * wv[13] + v1.z * wv[14] + v1.w * wv[15];
        aEe[e] = make_float2(s1, s2);
    }
#pragma unroll
    for (int j = 0; j < 8; ++j) atomicAdd(&red[j], s[j]);
    __syncthreads();
    if (tid < 8) atomicAdd(&acc[tid], red[tid]);
}

// ---- 3-pass exclusive scan over n = N+1 elements ---------------------------
__global__ void scan1_kernel(const int* __restrict__ deg, int* __restrict__ out,
                             int* __restrict__ bsum, int N, int n) {
    __shared__ int s[256];
    int t = threadIdx.x;
    int i = blockIdx.x * 256 + t;
    int v = (i < N) ? deg[i] : 0;
    s[t] = v; __syncthreads();
    for (int off = 1; off < 256; off <<= 1) {
        int u = (t >= off) ? s[t - off] : 0;
        __syncthreads();
        s[t] += u;
        __syncthreads();
    }
    if (i < n) out[i] = s[t] - v;
    if (t == 255) bsum[blockIdx.x] = s[255];
}

// scan2 also computes ae_loop (self-loop attention term) from the ea means
__global__ void scan2_kernel(int* __restrict__ bsum, int nb,
                             const float* __restrict__ mean_acc, float Einv,
                             const float* __restrict__ we_vec1, const float* __restrict__ we_vec2,
                             float* __restrict__ ae_loop) {
    __shared__ int s[256];
    int t = threadIdx.x;
    if (t == 0) {
        float s1 = 0.f, s2 = 0.f;
        for (int j = 0; j < 8; ++j) {
            float m = mean_acc[j] * Einv;
            s1 += m * we_vec1[j];
            s2 += m * we_vec2[j];
        }
        ae_loop[0] = s1; ae_loop[1] = s2;
    }
    int v = (t < nb) ? bsum[t] : 0;
    s[t] = v; __syncthreads();
    for (int off = 1; off < 256; off <<= 1) {
        int u = (t >= off) ? s[t - off] : 0;
        __syncthreads();
        s[t] += u;
        __syncthreads();
    }
    if (t < nb) bsum[t] = s[t] - v;
}

// scan3 also initializes the fill cursor
__global__ void scan3_kernel(int* __restrict__ out, int* __restrict__ cursor,
                             const int* __restrict__ bsum, int n, int N) {
    int i = blockIdx.x * 256 + threadIdx.x;
    if (i < n) {
        int v = out[i] + bsum[blockIdx.x];
        out[i] = v;
        if (i < N) cursor[i] = v;
    }
}

// ---- CSR fill: ONE packed 16B store per edge {src_bits, ae1, ae2, pad} -----
__global__ void fill_kernel(const int* __restrict__ src, const int* __restrict__ dst,
                            const float2* __restrict__ aEe,
                            int* __restrict__ cursor, float4* __restrict__ epack, int E) {
    int e = blockIdx.x * blockDim.x + threadIdx.x;
    if (e >= E) return;
    int d = dst[e];
    int idx = atomicAdd(&cursor[d], 1);
    float2 a = aEe[e];
    epack[idx] = make_float4(__int_as_float(src[e]), a.x, a.y, 0.f);
}

// ---- split fp32 -> bf16 hi/lo (flat, float4-vectorized) --------------------
__global__ void split_kernel(const float* __restrict__ in, u16* __restrict__ hi,
                             u16* __restrict__ lo, int n4) {
    int i = blockIdx.x * 256 + threadIdx.x;
    if (i >= n4) return;
    float4 v = ((const float4*)in)[i];
    u16x4 h, l;
    h.x = f2bf(v.x); l.x = f2bf(v.x - bf2f(h.x));
    h.y = f2bf(v.y); l.y = f2bf(v.y - bf2f(h.y));
    h.z = f2bf(v.z); l.z = f2bf(v.z - bf2f(h.z));
    h.w = f2bf(v.w); l.w = f2bf(v.w - bf2f(h.w));
    ((u16x4*)hi)[i] = h;
    ((u16x4*)lo)[i] = l;
}

// ---- transpose + split weights: t{hi,lo}[m*K+k] = split(W[k*M+m]) ----------
__global__ void wsplit_kernel(const float* __restrict__ W, u16* __restrict__ thi,
                              u16* __restrict__ tlo, int K, int M) {
    int idx = blockIdx.x * 256 + threadIdx.x;
    if (idx >= K * M) return;
    int k = idx / M, m = idx - k * M;
    float v = W[idx];
    u16 h = f2bf(v);
    u16 l = f2bf(v - bf2f(h));
    thi[(size_t)m * K + k] = h;
    tlo[(size_t)m * K + k] = l;
}

// ---- split-bf16 MFMA GEMM + fused attention row-dots -----------------------
// Cb[N,M] = bf16(A@B); as_out[r] += sum_c (A@B)[r,c]*av[c] (atomic), same bv.
// A row-major [N][K] hi/lo, B TRANSPOSED [M][K] hi/lo. 64x64 tile, 4 waves.
#define LDA 72
__global__ __launch_bounds__(256) void gemm_mfma_kernel(
        const u16* __restrict__ Ah_g, const u16* __restrict__ Al_g,
        const u16* __restrict__ Bh_g, const u16* __restrict__ Bl_g,
        u16* __restrict__ Cb, int Nrows, int K, int M,
        const float* __restrict__ av, const float* __restrict__ bv,
        float* __restrict__ as_out, float* __restrict__ ad_out) {
    __shared__ u16 Ah[64 * LDA], Al[64 * LDA], Bh[64 * LDA], Bl[64 * LDA];
    int tid = threadIdx.x;
    int lane = tid & 63;
    int wv = tid >> 6;
    int l15 = lane & 15;
    int quad = lane >> 4;
    int rb = blockIdx.y * 64;
    int cb = blockIdx.x * 64;

    v4f acc[4];
#pragma unroll
    for (int nt = 0; nt < 4; ++nt) acc[nt] = (v4f){0.f, 0.f, 0.f, 0.f};

    int sr = tid >> 2;            // staging row 0..63
    int sc = (tid & 3) * 16;      // staging col 0..48

    for (int kc = 0; kc < K; kc += 64) {
        {
            int gr = rb + sr;
            u16x8 z = {0, 0, 0, 0, 0, 0, 0, 0};
            u16x8 a0 = z, a1 = z, b0, b1;
            if (gr < Nrows) {
                a0 = *(const u16x8*)(Ah_g + (size_t)gr * K + kc + sc);
                a1 = *(const u16x8*)(Al_g + (size_t)gr * K + kc + sc);
            }
            b0 = *(const u16x8*)(Bh_g + (size_t)(cb + sr) * K + kc + sc);
            b1 = *(const u16x8*)(Bl_g + (size_t)(cb + sr) * K + kc + sc);
            *(u16x8*)&Ah[sr * LDA + sc] = a0;
            *(u16x8*)&Al[sr * LDA + sc] = a1;
            *(u16x8*)&Bh[sr * LDA + sc] = b0;
            *(u16x8*)&Bl[sr * LDA + sc] = b1;
            if (gr < Nrows) {
                a0 = *(const u16x8*)(Ah_g + (size_t)gr * K + kc + sc + 8);
                a1 = *(const u16x8*)(Al_g + (size_t)gr * K + kc + sc + 8);
            }
            b0 = *(const u16x8*)(Bh_g + (size_t)(cb + sr) * K + kc + sc + 8);
            b1 = *(const u16x8*)(Bl_g + (size_t)(cb + sr) * K + kc + sc + 8);
            *(u16x8*)&Ah[sr * LDA + sc + 8] = a0;
            *(u16x8*)&Al[sr * LDA + sc + 8] = a1;
            *(u16x8*)&Bh[sr * LDA + sc + 8] = b0;
            *(u16x8*)&Bl[sr * LDA + sc + 8] = b1;
        }
        __syncthreads();
#pragma unroll
        for (int kk = 0; kk < 2; ++kk) {
            int kb = kk * 32 + quad * 8;
            short8 ah = *(const short8*)&Ah[(wv * 16 + l15) * LDA + kb];
            short8 al = *(const short8*)&Al[(wv * 16 + l15) * LDA + kb];
#pragma unroll
            for (int nt = 0; nt < 4; ++nt) {
                short8 bh = *(const short8*)&Bh[(nt * 16 + l15) * LDA + kb];
                short8 bl = *(const short8*)&Bl[(nt * 16 + l15) * LDA + kb];
                acc[nt] = __builtin_amdgcn_mfma_f32_16x16x32_bf16(ah, bh, acc[nt], 0, 0, 0);
                acc[nt] = __builtin_amdgcn_mfma_f32_16x16x32_bf16(ah, bl, acc[nt], 0, 0, 0);
                acc[nt] = __builtin_amdgcn_mfma_f32_16x16x32_bf16(al, bh, acc[nt], 0, 0, 0);
            }
        }
        __syncthreads();
    }
    // C/D layout: col = lane&15, row = quad*4 + reg
#pragma unroll
    for (int nt = 0; nt < 4; ++nt) {
#pragma unroll
        for (int reg = 0; reg < 4; ++reg) {
            int row = rb + wv * 16 + quad * 4 + reg;
            if (row < Nrows)
                Cb[(size_t)row * M + cb + nt * 16 + l15] = f2bf(acc[nt][reg]);
        }
    }
    // fused row-dots: partial a_s/a_d for this block's 64 cols
    float sd[4] = {0.f, 0.f, 0.f, 0.f};
    float dd[4] = {0.f, 0.f, 0.f, 0.f};
#pragma unroll
    for (int nt = 0; nt < 4; ++nt) {
        float a = av[cb + nt * 16 + l15];
        float b = bv[cb + nt * 16 + l15];
#pragma unroll
        for (int reg = 0; reg < 4; ++reg) {
            sd[reg] += acc[nt][reg] * a;
            dd[reg] += acc[nt][reg] * b;
        }
    }
#pragma unroll
    for (int off = 1; off < 16; off <<= 1) {
#pragma unroll
        for (int reg = 0; reg < 4; ++reg) {
            sd[reg] += __shfl_xor(sd[reg], off);
            dd[reg] += __shfl_xor(dd[reg], off);
        }
    }
    if (l15 == 0) {
        int row0 = rb + wv * 16 + quad * 4;
#pragma unroll
        for (int reg = 0; reg < 4; ++reg) {
            if (row0 + reg < Nrows) {
                atomicAdd(as_out + row0 + reg, sd[reg]);
                atomicAdd(ad_out + row0 + reg, dd[reg]);
            }
        }
    }
}

// ---- fused online-softmax + aggregation, L1 (C=256), wave per node ---------
// Epilogue: t = relu(acc + b1); split bf16 hi/lo for layer-2 GEMM.
__global__ __launch_bounds__(256) void agg1_kernel(const int* __restrict__ row_start,
                                                   const float4* __restrict__ epack,
                                                   const float* __restrict__ asv,
                                                   const float* __restrict__ adv,
                                                   const float* __restrict__ ae_loop,
                                                   const u16* __restrict__ Hb,
                                                   u16* __restrict__ ohi, u16* __restrict__ olo,
                                                   const float* __restrict__ bias, int N) {
    int lane = threadIdx.x & 63;
    int wvi = threadIdx.x >> 6;
    int node = blockIdx.x * 4 + wvi;
    if (node >= N) return;
    int st = row_start[node], en = row_start[node + 1];
    float ad = adv[node];
    float aloop = lrelu(asv[node] + ad + ae_loop[0]);
    // online softmax over edges + self loop
    float m = aloop;
    float sum = (lane == 0) ? 1.f : 0.f;   // self-loop term at scale m=aloop
    for (int i = st + lane; i < en; i += 64) {
        float4 ep = epack[i];
        float al = lrelu(asv[__float_as_int(ep.x)] + ad + ep.y);
        float mn = fmaxf(m, al);
        sum = sum * __expf(m - mn) + __expf(al - mn);
        m = mn;
    }
#pragma unroll
    for (int off = 1; off < 64; off <<= 1) {
        float mo = __shfl_xor(m, off);
        float so = __shfl_xor(sum, off);
        float M = fmaxf(m, mo);
        sum = sum * __expf(m - M) + so * __expf(mo - M);
        m = M;
    }
    float inv = 1.f / sum;
    // gather-accumulate
    float acc0, acc1, acc2, acc3;
    {
        float wsf = __expf(aloop - m) * inv;
        u16x4 hv = *(const u16x4*)(Hb + (size_t)node * 256 + lane * 4);
        acc0 = wsf * bf2f(hv.x); acc1 = wsf * bf2f(hv.y);
        acc2 = wsf * bf2f(hv.z); acc3 = wsf * bf2f(hv.w);
    }
    for (int base = st; base < en; base += 64) {
        int i = base + lane;
        int sreg = 0; float wreg = 0.f;
        if (i < en) {
            float4 ep = epack[i];
            sreg = __float_as_int(ep.x);
            wreg = __expf(lrelu(asv[sreg] + ad + ep.y) - m) * inv;
        }
        int cnt = min(64, en - base);
        int j = 0;
        for (; j + 8 <= cnt; j += 8) {
            int s[8]; float wt[8];
#pragma unroll
            for (int q = 0; q < 8; ++q) { s[q] = __shfl(sreg, j + q); wt[q] = __shfl(wreg, j + q); }
            u16x4 v[8];
#pragma unroll
            for (int q = 0; q < 8; ++q) v[q] = *(const u16x4*)(Hb + (size_t)s[q] * 256 + lane * 4);
#pragma unroll
            for (int q = 0; q < 8; ++q) {
                acc0 += wt[q] * bf2f(v[q].x); acc1 += wt[q] * bf2f(v[q].y);
                acc2 += wt[q] * bf2f(v[q].z); acc3 += wt[q] * bf2f(v[q].w);
            }
        }
        for (; j < cnt; ++j) {
            int s0 = __shfl(sreg, j);
            float w0 = __shfl(wreg, j);
            u16x4 v0 = *(const u16x4*)(Hb + (size_t)s0 * 256 + lane * 4);
            acc0 += w0 * bf2f(v0.x); acc1 += w0 * bf2f(v0.y);
            acc2 += w0 * bf2f(v0.z); acc3 += w0 * bf2f(v0.w);
        }
    }
    const float4 bvv = *(const float4*)(bias + lane * 4);
    float t0 = acc0 + bvv.x, t1 = acc1 + bvv.y, t2 = acc2 + bvv.z, t3 = acc3 + bvv.w;
    t0 = t0 > 0.f ? t0 : 0.f; t1 = t1 > 0.f ? t1 : 0.f;
    t2 = t2 > 0.f ? t2 : 0.f; t3 = t3 > 0.f ? t3 : 0.f;
    u16x4 h, l;
    h.x = f2bf(t0); l.x = f2bf(t0 - bf2f(h.x));
    h.y = f2bf(t1); l.y = f2bf(t1 - bf2f(h.y));
    h.z = f2bf(t2); l.z = f2bf(t2 - bf2f(h.z));
    h.w = f2bf(t3); l.w = f2bf(t3 - bf2f(h.w));
    size_t o = (size_t)node * 256 + lane * 4;
    *(u16x4*)(ohi + o) = h;
    *(u16x4*)(olo + o) = l;
}

// ---- fused online-softmax + aggregation, L2 (C=128) ------------------------
__global__ __launch_bounds__(256) void agg2_kernel(const int* __restrict__ row_start,
                                                   const float4* __restrict__ epack,
                                                   const float* __restrict__ asv,
                                                   const float* __restrict__ adv,
                                                   const float* __restrict__ ae_loop,
                                                   const u16* __restrict__ Hb,
                                                   float* __restrict__ out,
                                                   const float* __restrict__ bias, int N) {
    int lane = threadIdx.x & 63;
    int wvi = threadIdx.x >> 6;
    int node = blockIdx.x * 4 + wvi;
    if (node >= N) return;
    int st = row_start[node], en = row_start[node + 1];
    float ad = adv[node];
    float aloop = lrelu(asv[node] + ad + ae_loop[1]);
    float m = aloop;
    float sum = (lane == 0) ? 1.f : 0.f;
    for (int i = st + lane; i < en; i += 64) {
        float4 ep = epack[i];
        float al = lrelu(asv[__float_as_int(ep.x)] + ad + ep.z);
        float mn = fmaxf(m, al);
        sum = sum * __expf(m - mn) + __expf(al - mn);
        m = mn;
    }
#pragma unroll
    for (int off = 1; off < 64; off <<= 1) {
        float mo = __shfl_xor(m, off);
        float so = __shfl_xor(sum, off);
        float M = fmaxf(m, mo);
        sum = sum * __expf(m - M) + so * __expf(mo - M);
        m = M;
    }
    float inv = 1.f / sum;
    float acc0, acc1;
    {
        float wsf = __expf(aloop - m) * inv;
        u16x2 hv = *(const u16x2*)(Hb + (size_t)node * 128 + lane * 2);
        acc0 = wsf * bf2f(hv.x); acc1 = wsf * bf2f(hv.y);
    }
    for (int base = st; base < en; base += 64) {
        int i = base + lane;
        int sreg = 0; float wreg = 0.f;
        if (i < en) {
            float4 ep = epack[i];
            sreg = __float_as_int(ep.x);
            wreg = __expf(lrelu(asv[sreg] + ad + ep.z) - m) * inv;
        }
        int cnt = min(64, en - base);
        int j = 0;
        for (; j + 8 <= cnt; j += 8) {
            int s[8]; float wt[8];
#pragma unroll
            for (int q = 0; q < 8; ++q) { s[q] = __shfl(sreg, j + q); wt[q] = __shfl(wreg, j + q); }
            u16x2 v[8];
#pragma unroll
            for (int q = 0; q < 8; ++q) v[q] = *(const u16x2*)(Hb + (size_t)s[q] * 128 + lane * 2);
#pragma unroll
            for (int q = 0; q < 8; ++q) {
                acc0 += wt[q] * bf2f(v[q].x); acc1 += wt[q] * bf2f(v[q].y);
            }
        }
        for (; j < cnt; ++j) {
            int s0 = __shfl(sreg, j);
            float w0 = __shfl(wreg, j);
            u16x2 v0 = *(const u16x2*)(Hb + (size_t)s0 * 128 + lane * 2);
            acc0 += w0 * bf2f(v0.x); acc1 += w0 * bf2f(v0.y);
        }
    }
    size_t o = (size_t)node * 128 + lane * 2;
    out[o]     = acc0 + bias[lane * 2];
    out[o + 1] = acc1 + bias[lane * 2 + 1];
}

extern "C" void kernel_launch(void* const* d_in, const int* in_sizes, int n_in,
                              void* d_out, int out_size, void* d_ws, size_t ws_size,
                              hipStream_t stream) {
    const int Cin = 128, Ch = 256, Co = 128;
    const int N = in_sizes[0] / Cin;        // 50000
    const int E = in_sizes[1] / 2;          // 800000

    const float* x   = (const float*)d_in[0];
    const int*   src = (const int*)d_in[1];
    const int*   dst = src + E;
    const float* ea  = (const float*)d_in[2];
    const float* W1  = (const float*)d_in[3];
    const float* We1 = (const float*)d_in[4];
    const float* as1 = (const float*)d_in[5];
    const float* ad1 = (const float*)d_in[6];
    const float* ae1 = (const float*)d_in[7];
    const float* b1  = (const float*)d_in[8];
    const float* W2  = (const float*)d_in[9];
    const float* We2 = (const float*)d_in[10];
    const float* as2 = (const float*)d_in[11];
    const float* ad2 = (const float*)d_in[12];
    const float* ae2 = (const float*)d_in[13];
    const float* b2  = (const float*)d_in[14];
    float* out = (float*)d_out;

    // workspace layout (4-byte units)
    float* ws = (float*)d_ws;
    size_t off = 0;
    u16* h1b = (u16*)(ws + off); off += (size_t)N * Ch / 2;   // bf16 h (reused as h2b)
    float* ureg  = ws + off; off += (size_t)N * Ch;           // x splits, then g1 splits
    u16* xhi  = (u16*)ureg;
    u16* xlo  = xhi + (size_t)N * Cin;
    u16* g1hi = (u16*)ureg;
    u16* g1lo = g1hi + (size_t)N * Ch;
    float4* epack = (float4*)(ws + off); off += (size_t)E * 4;  // packed CSR edges
    float2* aEe   = (float2*)(ws + off); off += (size_t)E * 2;  // edge-order a_e
    float* asv   = ws + off; off += (size_t)N;                // a_src (zeroed per layer)
    float* adv   = ws + off; off += (size_t)N;                // a_dst
    int* deg       = (int*)(ws + off); off += (size_t)N + 1;
    int* row_start = (int*)(ws + off); off += (size_t)N + 1;
    int* cursor    = (int*)(ws + off); off += (size_t)N;
    int* bsum      = (int*)(ws + off); off += 256;
    u16* w1thi = (u16*)(ws + off); off += (size_t)Cin * Ch / 2;
    u16* w1tlo = (u16*)(ws + off); off += (size_t)Cin * Ch / 2;
    u16* w2thi = (u16*)(ws + off); off += (size_t)Ch * Co / 2;
    u16* w2tlo = (u16*)(ws + off); off += (size_t)Ch * Co / 2;
    float* misc  = ws + off; off += 32;  // [0:8) mean_acc, [8:16) we_vec1, [16:24) we_vec2, [24:26) ae_loop
    float* mean_acc = misc;
    float* we_vec1  = misc + 8;
    float* we_vec2  = misc + 16;
    float* ae_loop  = misc + 24;

    const int n1 = N + 1;
    const int nscan = (n1 + 255) / 256;   // <= 256

    // zero what must be zero (ws is poisoned 0xAA before each timed call)
    hipMemsetAsync(deg, 0, (size_t)n1 * sizeof(int), stream);
    hipMemsetAsync(asv, 0, (size_t)2 * N * sizeof(float), stream);
    hipMemsetAsync(misc, 0, 32 * sizeof(float), stream);

    // ---- precompute: we_vec (params only) -> edge pass -> CSR -> splits ----
    prep_kernel<<<1, 256, 0, stream>>>(We1, ae1, We2, ae2, we_vec1, we_vec2, Ch, Co);
    ea_hist_kernel<<<1024, 256, 0, stream>>>(ea, dst, we_vec1, we_vec2,
                                             mean_acc, deg, aEe, E);
    scan1_kernel<<<nscan, 256, 0, stream>>>(deg, row_start, bsum, N, n1);
    scan2_kernel<<<1, 256, 0, stream>>>(bsum, nscan, mean_acc, 1.0f / (float)E,
                                        we_vec1, we_vec2, ae_loop);
    scan3_kernel<<<nscan, 256, 0, stream>>>(row_start, cursor, bsum, n1, N);
    fill_kernel<<<(E + 255) / 256, 256, 0, stream>>>(src, dst, aEe, cursor, epack, E);
    split_kernel<<<((N * Cin / 4) + 255) / 256, 256, 0, stream>>>(x, xhi, xlo, N * Cin / 4);
    wsplit_kernel<<<(Cin * Ch + 255) / 256, 256, 0, stream>>>(W1, w1thi, w1tlo, Cin, Ch);
    wsplit_kernel<<<(Ch * Co + 255) / 256, 256, 0, stream>>>(W2, w2thi, w2tlo, Ch, Co);

    // ---- layer 1 ----------------------------------------------------------
    {
        dim3 grid(Ch / 64, (N + 63) / 64);
        gemm_mfma_kernel<<<grid, 256, 0, stream>>>(xhi, xlo, w1thi, w1tlo, h1b, N, Cin, Ch,
                                                   as1, ad1, asv, adv);
    }
    agg1_kernel<<<(N + 3) / 4, 256, 0, stream>>>(row_start, epack, asv, adv, ae_loop,
                                                 h1b, g1hi, g1lo, b1, N);

    // ---- layer 2 ----------------------------------------------------------
    hipMemsetAsync(asv, 0, (size_t)2 * N * sizeof(float), stream);  // re-zero for gemm2 dots
    u16* h2b = h1b; // reuse
    {
        dim3 grid(Co / 64, (N + 63) / 64);
        gemm_mfma_kernel<<<grid, 256, 0, stream>>>(g1hi, g1lo, w2thi, w2tlo, h2b, N, Ch, Co,
                                                   as2, ad2, asv, adv);
    }
    agg2_kernel<<<(N + 3) / 4, 256, 0, stream>>>(row_start, epack, asv, adv, ae_loop,
                                                 h2b, out, b2, N);
}

// Round 6
// 417.444 us; speedup vs baseline: 3.6366x; 1.0418x over previous
//
#include <hip/hip_runtime.h>
#include <hip/hip_bf16.h>

// ---------------------------------------------------------------------------
// 2-layer GATConv (heads=1). N=50000, E=800000, Cin=128, Ch=256, Co=128, Ed=8.
// CSR-by-dst + single-pass FLASH softmax-aggregation (no hot-path atomics),
// packed 16B edge structs, split-bf16 MFMA GEMMs (3-term => ~fp32) with
// 128x128 tiles and fused attention row-dots in the epilogue.
// ---------------------------------------------------------------------------

#define NEG_SLOPE 0.2f

typedef unsigned short u16;
typedef short short8 __attribute__((ext_vector_type(8)));
typedef float v4f __attribute__((ext_vector_type(4)));
typedef u16 u16x4 __attribute__((ext_vector_type(4)));
typedef u16 u16x8 __attribute__((ext_vector_type(8)));

__device__ __forceinline__ u16 f2bf(float f) {
    unsigned u = __float_as_uint(f);
    return (u16)((u + 0x7fffu + ((u >> 16) & 1u)) >> 16);
}
__device__ __forceinline__ float bf2f(u16 h) {
    return __uint_as_float(((unsigned)h) << 16);
}
__device__ __forceinline__ float bf_lo(int v) { return __uint_as_float(((unsigned)v) << 16); }
__device__ __forceinline__ float bf_hi(int v) { return __uint_as_float(((unsigned)v) & 0xffff0000u); }
__device__ __forceinline__ float lrelu(float x) {
    return x >= 0.f ? x : NEG_SLOPE * x;
}

// ---- we_vec{1,2}[j] = sum_k We[j,k]*a_edge[k]  (params only, runs first) ---
__global__ void prep_kernel(const float* __restrict__ We1, const float* __restrict__ ae1v,
                            const float* __restrict__ We2, const float* __restrict__ ae2v,
                            float* __restrict__ we_vec1, float* __restrict__ we_vec2,
                            int Ch, int Co) {
    __shared__ float red[256];
    int t = threadIdx.x;
    for (int j = 0; j < 8; ++j) {
        float s = 0.f;
        for (int k = t; k < Ch; k += 256) s += We1[j * Ch + k] * ae1v[k];
        red[t] = s; __syncthreads();
        for (int off = 128; off; off >>= 1) { if (t < off) red[t] += red[t + off]; __syncthreads(); }
        if (t == 0) we_vec1[j] = red[0];
        __syncthreads();
        s = 0.f;
        for (int k = t; k < Co; k += 256) s += We2[j * Co + k] * ae2v[k];
        red[t] = s; __syncthreads();
        for (int off = 128; off; off >>= 1) { if (t < off) red[t] += red[t + off]; __syncthreads(); }
        if (t == 0) we_vec2[j] = red[0];
        __syncthreads();
    }
}

// ---- fused: edge_attr col sums + dst histogram + per-edge a_e (edge order) -
__global__ void ea_hist_kernel(const float* __restrict__ ea, const int* __restrict__ dst,
                               const float* __restrict__ we_vec1, const float* __restrict__ we_vec2,
                               float* __restrict__ acc, int* __restrict__ deg,
                               float2* __restrict__ aEe, int E) {
    __shared__ float red[8];
    __shared__ float wv[16];
    int tid = threadIdx.x;
    if (tid < 8) { red[tid] = 0.f; wv[tid] = we_vec1[tid]; }
    else if (tid < 16) wv[tid] = we_vec2[tid - 8];
    __syncthreads();
    float s[8] = {0.f};
    int stride = gridDim.x * blockDim.x;
    for (int e = blockIdx.x * blockDim.x + tid; e < E; e += stride) {
        atomicAdd(&deg[dst[e]], 1);
        const float4 v0 = *(const float4*)&ea[(size_t)e * 8];
        const float4 v1 = *(const float4*)&ea[(size_t)e * 8 + 4];
        s[0] += v0.x; s[1] += v0.y; s[2] += v0.z; s[3] += v0.w;
        s[4] += v1.x; s[5] += v1.y; s[6] += v1.z; s[7] += v1.w;
        float s1 = v0.x * wv[0] + v0.y * wv[1] + v0.z * wv[2] + v0.w * wv[3]
                 + v1.x * wv[4] + v1.y * wv[5] + v1.z * wv[6] + v1.w * wv[7];
        float s2 = v0.x * wv[8] + v0.y * wv[9] + v0.z * wv[10] + v0.w * wv[11]
                 + v1.x * wv[12] + v1.y * wv[13] + v1.z * wv[14] + v1.w * wv[15];
        aEe[e] = make_float2(s1, s2);
    }
#pragma unroll
    for (int j = 0; j < 8; ++j) atomicAdd(&red[j], s[j]);
    __syncthreads();
    if (tid < 8) atomicAdd(&acc[tid], red[tid]);
}

// ---- 3-pass exclusive scan over n = N+1 elements ---------------------------
__global__ void scan1_kernel(const int* __restrict__ deg, int* __restrict__ out,
                             int* __restrict__ bsum, int N, int n) {
    __shared__ int s[256];
    int t = threadIdx.x;
    int i = blockIdx.x * 256 + t;
    int v = (i < N) ? deg[i] : 0;
    s[t] = v; __syncthreads();
    for (int off = 1; off < 256; off <<= 1) {
        int u = (t >= off) ? s[t - off] : 0;
        __syncthreads();
        s[t] += u;
        __syncthreads();
    }
    if (i < n) out[i] = s[t] - v;
    if (t == 255) bsum[blockIdx.x] = s[255];
}

// scan2 also computes ae_loop (self-loop attention term) from the ea means
__global__ void scan2_kernel(int* __restrict__ bsum, int nb,
                             const float* __restrict__ mean_acc, float Einv,
                             const float* __restrict__ we_vec1, const float* __restrict__ we_vec2,
                             float* __restrict__ ae_loop) {
    __shared__ int s[256];
    int t = threadIdx.x;
    if (t == 0) {
        float s1 = 0.f, s2 = 0.f;
        for (int j = 0; j < 8; ++j) {
            float m = mean_acc[j] * Einv;
            s1 += m * we_vec1[j];
            s2 += m * we_vec2[j];
        }
        ae_loop[0] = s1; ae_loop[1] = s2;
    }
    int v = (t < nb) ? bsum[t] : 0;
    s[t] = v; __syncthreads();
    for (int off = 1; off < 256; off <<= 1) {
        int u = (t >= off) ? s[t - off] : 0;
        __syncthreads();
        s[t] += u;
        __syncthreads();
    }
    if (t < nb) bsum[t] = s[t] - v;
}

// scan3 also initializes the fill cursor
__global__ void scan3_kernel(int* __restrict__ out, int* __restrict__ cursor,
                             const int* __restrict__ bsum, int n, int N) {
    int i = blockIdx.x * 256 + threadIdx.x;
    if (i < n) {
        int v = out[i] + bsum[blockIdx.x];
        out[i] = v;
        if (i < N) cursor[i] = v;
    }
}

// ---- CSR fill: ONE packed 16B store per edge {src_bits, ae1, ae2, pad} -----
__global__ void fill_kernel(const int* __restrict__ src, const int* __restrict__ dst,
                            const float2* __restrict__ aEe,
                            int* __restrict__ cursor, float4* __restrict__ epack, int E) {
    int e = blockIdx.x * blockDim.x + threadIdx.x;
    if (e >= E) return;
    int d = dst[e];
    int idx = atomicAdd(&cursor[d], 1);
    float2 a = aEe[e];
    epack[idx] = make_float4(__int_as_float(src[e]), a.x, a.y, 0.f);
}

// ---- merged split: x (float4 path) + W1^T + W2^T splits --------------------
__global__ void splitall_kernel(const float* __restrict__ x, u16* __restrict__ xhi,
                                u16* __restrict__ xlo, int n4x,
                                const float* __restrict__ W1, u16* __restrict__ w1thi,
                                u16* __restrict__ w1tlo, int K1, int M1,
                                const float* __restrict__ W2, u16* __restrict__ w2thi,
                                u16* __restrict__ w2tlo, int K2, int M2) {
    int idx = blockIdx.x * 256 + threadIdx.x;
    if (idx < n4x) {
        float4 v = ((const float4*)x)[idx];
        u16x4 h, l;
        h.x = f2bf(v.x); l.x = f2bf(v.x - bf2f(h.x));
        h.y = f2bf(v.y); l.y = f2bf(v.y - bf2f(h.y));
        h.z = f2bf(v.z); l.z = f2bf(v.z - bf2f(h.z));
        h.w = f2bf(v.w); l.w = f2bf(v.w - bf2f(h.w));
        ((u16x4*)xhi)[idx] = h;
        ((u16x4*)xlo)[idx] = l;
        return;
    }
    int t = idx - n4x;
    if (t < K1 * M1) {
        int k = t / M1, m = t - k * M1;
        float v = W1[t];
        u16 h = f2bf(v);
        w1thi[(size_t)m * K1 + k] = h;
        w1tlo[(size_t)m * K1 + k] = f2bf(v - bf2f(h));
        return;
    }
    t -= K1 * M1;
    if (t < K2 * M2) {
        int k = t / M2, m = t - k * M2;
        float v = W2[t];
        u16 h = f2bf(v);
        w2thi[(size_t)m * K2 + k] = h;
        w2tlo[(size_t)m * K2 + k] = f2bf(v - bf2f(h));
    }
}

// ---- split-bf16 MFMA GEMM, 128x128 tile + fused attention row-dots ---------
// Cb[N,M] = bf16(A@B); as_out[r] += sum_c C[r,c]*av[c] (atomic), ad same w/ bv.
// A row-major [N][K] hi/lo, B TRANSPOSED [M][K] hi/lo. BK=32, 4 waves, each a
// 64x64 quadrant (4x4 of 16x16x32 MFMA, 3 split terms).
#define BK 32
#define LDA 40   // 32 + 8 pad (u16): 80B row stride -> ~2-way LDS aliasing
__global__ __launch_bounds__(256) void gemm_mfma_kernel(
        const u16* __restrict__ Ah_g, const u16* __restrict__ Al_g,
        const u16* __restrict__ Bh_g, const u16* __restrict__ Bl_g,
        u16* __restrict__ Cb, int Nrows, int K, int M,
        const float* __restrict__ av, const float* __restrict__ bv,
        float* __restrict__ as_out, float* __restrict__ ad_out) {
    __shared__ u16 Ah[128 * LDA], Al[128 * LDA], Bh[128 * LDA], Bl[128 * LDA];
    int tid = threadIdx.x;
    int lane = tid & 63;
    int wv = tid >> 6;
    int wm = wv >> 1, wn = wv & 1;
    int l15 = lane & 15, quad = lane >> 4;
    int rb = blockIdx.y * 128;
    int cb = blockIdx.x * 128;

    v4f acc[4][4];
#pragma unroll
    for (int mi = 0; mi < 4; ++mi)
#pragma unroll
        for (int ni = 0; ni < 4; ++ni) acc[mi][ni] = (v4f){0.f, 0.f, 0.f, 0.f};

    int sr = tid >> 1;            // staging row 0..127
    int sc = (tid & 1) * 16;      // staging col 0 or 16

    for (int kc = 0; kc < K; kc += BK) {
        int gr = rb + sr;
        u16x8 z = {0, 0, 0, 0, 0, 0, 0, 0};
        u16x8 a0 = z, a1 = z, a2 = z, a3 = z;
        if (gr < Nrows) {
            size_t ba = (size_t)gr * K + kc + sc;
            a0 = *(const u16x8*)(Ah_g + ba);
            a1 = *(const u16x8*)(Ah_g + ba + 8);
            a2 = *(const u16x8*)(Al_g + ba);
            a3 = *(const u16x8*)(Al_g + ba + 8);
        }
        size_t bb = (size_t)(cb + sr) * K + kc + sc;
        u16x8 b0 = *(const u16x8*)(Bh_g + bb);
        u16x8 b1 = *(const u16x8*)(Bh_g + bb + 8);
        u16x8 b2 = *(const u16x8*)(Bl_g + bb);
        u16x8 b3 = *(const u16x8*)(Bl_g + bb + 8);
        *(u16x8*)&Ah[sr * LDA + sc] = a0;
        *(u16x8*)&Ah[sr * LDA + sc + 8] = a1;
        *(u16x8*)&Al[sr * LDA + sc] = a2;
        *(u16x8*)&Al[sr * LDA + sc + 8] = a3;
        *(u16x8*)&Bh[sr * LDA + sc] = b0;
        *(u16x8*)&Bh[sr * LDA + sc + 8] = b1;
        *(u16x8*)&Bl[sr * LDA + sc] = b2;
        *(u16x8*)&Bl[sr * LDA + sc + 8] = b3;
        __syncthreads();
        short8 ah[4], al[4], bh[4], bl[4];
#pragma unroll
        for (int mi = 0; mi < 4; ++mi) {
            int r = (wm * 64 + mi * 16 + l15) * LDA + quad * 8;
            ah[mi] = *(const short8*)&Ah[r];
            al[mi] = *(const short8*)&Al[r];
        }
#pragma unroll
        for (int ni = 0; ni < 4; ++ni) {
            int r = (wn * 64 + ni * 16 + l15) * LDA + quad * 8;
            bh[ni] = *(const short8*)&Bh[r];
            bl[ni] = *(const short8*)&Bl[r];
        }
#pragma unroll
        for (int mi = 0; mi < 4; ++mi)
#pragma unroll
            for (int ni = 0; ni < 4; ++ni) {
                acc[mi][ni] = __builtin_amdgcn_mfma_f32_16x16x32_bf16(ah[mi], bh[ni], acc[mi][ni], 0, 0, 0);
                acc[mi][ni] = __builtin_amdgcn_mfma_f32_16x16x32_bf16(ah[mi], bl[ni], acc[mi][ni], 0, 0, 0);
                acc[mi][ni] = __builtin_amdgcn_mfma_f32_16x16x32_bf16(al[mi], bh[ni], acc[mi][ni], 0, 0, 0);
            }
        __syncthreads();
    }
    // C/D layout: col = lane&15, row = quad*4 + reg
#pragma unroll
    for (int mi = 0; mi < 4; ++mi)
#pragma unroll
        for (int ni = 0; ni < 4; ++ni) {
#pragma unroll
            for (int reg = 0; reg < 4; ++reg) {
                int row = rb + wm * 64 + mi * 16 + quad * 4 + reg;
                if (row < Nrows)
                    Cb[(size_t)row * M + cb + wn * 64 + ni * 16 + l15] = f2bf(acc[mi][ni][reg]);
            }
        }
    // fused row-dots over this wave's 64 cols
    float sd[4][4] = {}, dd[4][4] = {};
#pragma unroll
    for (int ni = 0; ni < 4; ++ni) {
        int col = cb + wn * 64 + ni * 16 + l15;
        float a = av[col], b = bv[col];
#pragma unroll
        for (int mi = 0; mi < 4; ++mi)
#pragma unroll
            for (int reg = 0; reg < 4; ++reg) {
                sd[mi][reg] += acc[mi][ni][reg] * a;
                dd[mi][reg] += acc[mi][ni][reg] * b;
            }
    }
#pragma unroll
    for (int off = 1; off < 16; off <<= 1)
#pragma unroll
        for (int mi = 0; mi < 4; ++mi)
#pragma unroll
            for (int reg = 0; reg < 4; ++reg) {
                sd[mi][reg] += __shfl_xor(sd[mi][reg], off);
                dd[mi][reg] += __shfl_xor(dd[mi][reg], off);
            }
    if (l15 == 0) {
#pragma unroll
        for (int mi = 0; mi < 4; ++mi) {
            int row0 = rb + wm * 64 + mi * 16 + quad * 4;
#pragma unroll
            for (int reg = 0; reg < 4; ++reg) {
                if (row0 + reg < Nrows) {
                    atomicAdd(as_out + row0 + reg, sd[mi][reg]);
                    atomicAdd(ad_out + row0 + reg, dd[mi][reg]);
                }
            }
        }
    }
}

// ---- single-pass FLASH softmax-aggregation, L1 (C=256), wave per node ------
// Epilogue: t = relu(acc/sum + b1); split bf16 hi/lo for layer-2 GEMM.
__global__ __launch_bounds__(256) void agg1_kernel(const int* __restrict__ row_start,
                                                   const float4* __restrict__ epack,
                                                   const float* __restrict__ asv,
                                                   const float* __restrict__ adv,
                                                   const float* __restrict__ ae_loop,
                                                   const u16* __restrict__ Hb,
                                                   u16* __restrict__ ohi, u16* __restrict__ olo,
                                                   const float* __restrict__ bias, int N) {
    __shared__ float2 xch[4][64];
    int lane = threadIdx.x & 63;
    int wvi = threadIdx.x >> 6;
    int node = blockIdx.x * 4 + wvi;
    if (node >= N) return;
    int st = row_start[node], en = row_start[node + 1];
    float ad = adv[node];
    float aloop = lrelu(asv[node] + ad + ae_loop[0]);
    float m = aloop, sum = 1.f;        // self-loop: weight exp(aloop-m)=1
    float acc0, acc1, acc2, acc3;
    {
        int2 hv = *(const int2*)(Hb + (size_t)node * 256 + lane * 4);
        acc0 = bf_lo(hv.x); acc1 = bf_hi(hv.x);
        acc2 = bf_lo(hv.y); acc3 = bf_hi(hv.y);
    }
    for (int base = st; base < en; base += 64) {
        int i = base + lane;
        float al = -3.0e38f; int sreg = 0;
        if (i < en) {
            float4 ep = epack[i];
            sreg = __float_as_int(ep.x);
            al = lrelu(asv[sreg] + ad + ep.y);
        }
        float cm = al;
#pragma unroll
        for (int o = 1; o < 64; o <<= 1) cm = fmaxf(cm, __shfl_xor(cm, o));
        if (cm > m) {
            float sc = __expf(m - cm);
            acc0 *= sc; acc1 *= sc; acc2 *= sc; acc3 *= sc;
            sum *= sc; m = cm;
        }
        float w = (i < en) ? __expf(al - m) : 0.f;
        float wsum = w;
#pragma unroll
        for (int o = 1; o < 64; o <<= 1) wsum += __shfl_xor(wsum, o);
        sum += wsum;
        xch[wvi][lane] = make_float2(w, __int_as_float(sreg));
        int cnt = min(64, en - base);
        int j = 0;
        for (; j + 4 <= cnt; j += 4) {
            float2 e0 = xch[wvi][j], e1 = xch[wvi][j + 1];
            float2 e2 = xch[wvi][j + 2], e3 = xch[wvi][j + 3];
            int2 h0 = *(const int2*)(Hb + (size_t)__float_as_int(e0.y) * 256 + lane * 4);
            int2 h1 = *(const int2*)(Hb + (size_t)__float_as_int(e1.y) * 256 + lane * 4);
            int2 h2 = *(const int2*)(Hb + (size_t)__float_as_int(e2.y) * 256 + lane * 4);
            int2 h3 = *(const int2*)(Hb + (size_t)__float_as_int(e3.y) * 256 + lane * 4);
            acc0 += e0.x * bf_lo(h0.x) + e1.x * bf_lo(h1.x) + e2.x * bf_lo(h2.x) + e3.x * bf_lo(h3.x);
            acc1 += e0.x * bf_hi(h0.x) + e1.x * bf_hi(h1.x) + e2.x * bf_hi(h2.x) + e3.x * bf_hi(h3.x);
            acc2 += e0.x * bf_lo(h0.y) + e1.x * bf_lo(h1.y) + e2.x * bf_lo(h2.y) + e3.x * bf_lo(h3.y);
            acc3 += e0.x * bf_hi(h0.y) + e1.x * bf_hi(h1.y) + e2.x * bf_hi(h2.y) + e3.x * bf_hi(h3.y);
        }
        for (; j < cnt; ++j) {
            float2 e0 = xch[wvi][j];
            int2 h0 = *(const int2*)(Hb + (size_t)__float_as_int(e0.y) * 256 + lane * 4);
            acc0 += e0.x * bf_lo(h0.x); acc1 += e0.x * bf_hi(h0.x);
            acc2 += e0.x * bf_lo(h0.y); acc3 += e0.x * bf_hi(h0.y);
        }
    }
    float inv = 1.f / sum;
    const float4 bvv = *(const float4*)(bias + lane * 4);
    float t0 = acc0 * inv + bvv.x, t1 = acc1 * inv + bvv.y;
    float t2 = acc2 * inv + bvv.z, t3 = acc3 * inv + bvv.w;
    t0 = t0 > 0.f ? t0 : 0.f; t1 = t1 > 0.f ? t1 : 0.f;
    t2 = t2 > 0.f ? t2 : 0.f; t3 = t3 > 0.f ? t3 : 0.f;
    u16x4 h, l;
    h.x = f2bf(t0); l.x = f2bf(t0 - bf2f(h.x));
    h.y = f2bf(t1); l.y = f2bf(t1 - bf2f(h.y));
    h.z = f2bf(t2); l.z = f2bf(t2 - bf2f(h.z));
    h.w = f2bf(t3); l.w = f2bf(t3 - bf2f(h.w));
    size_t o = (size_t)node * 256 + lane * 4;
    *(u16x4*)(ohi + o) = h;
    *(u16x4*)(olo + o) = l;
}

// ---- single-pass FLASH softmax-aggregation, L2 (C=128) ---------------------
__global__ __launch_bounds__(256) void agg2_kernel(const int* __restrict__ row_start,
                                                   const float4* __restrict__ epack,
                                                   const float* __restrict__ asv,
                                                   const float* __restrict__ adv,
                                                   const float* __restrict__ ae_loop,
                                                   const u16* __restrict__ Hb,
                                                   float* __restrict__ out,
                                                   const float* __restrict__ bias, int N) {
    __shared__ float2 xch[4][64];
    int lane = threadIdx.x & 63;
    int wvi = threadIdx.x >> 6;
    int node = blockIdx.x * 4 + wvi;
    if (node >= N) return;
    int st = row_start[node], en = row_start[node + 1];
    float ad = adv[node];
    float aloop = lrelu(asv[node] + ad + ae_loop[1]);
    float m = aloop, sum = 1.f;
    float acc0, acc1;
    {
        int hv = *(const int*)(Hb + (size_t)node * 128 + lane * 2);
        acc0 = bf_lo(hv); acc1 = bf_hi(hv);
    }
    for (int base = st; base < en; base += 64) {
        int i = base + lane;
        float al = -3.0e38f; int sreg = 0;
        if (i < en) {
            float4 ep = epack[i];
            sreg = __float_as_int(ep.x);
            al = lrelu(asv[sreg] + ad + ep.z);
        }
        float cm = al;
#pragma unroll
        for (int o = 1; o < 64; o <<= 1) cm = fmaxf(cm, __shfl_xor(cm, o));
        if (cm > m) {
            float sc = __expf(m - cm);
            acc0 *= sc; acc1 *= sc;
            sum *= sc; m = cm;
        }
        float w = (i < en) ? __expf(al - m) : 0.f;
        float wsum = w;
#pragma unroll
        for (int o = 1; o < 64; o <<= 1) wsum += __shfl_xor(wsum, o);
        sum += wsum;
        xch[wvi][lane] = make_float2(w, __int_as_float(sreg));
        int cnt = min(64, en - base);
        int j = 0;
        for (; j + 4 <= cnt; j += 4) {
            float2 e0 = xch[wvi][j], e1 = xch[wvi][j + 1];
            float2 e2 = xch[wvi][j + 2], e3 = xch[wvi][j + 3];
            int h0 = *(const int*)(Hb + (size_t)__float_as_int(e0.y) * 128 + lane * 2);
            int h1 = *(const int*)(Hb + (size_t)__float_as_int(e1.y) * 128 + lane * 2);
            int h2 = *(const int*)(Hb + (size_t)__float_as_int(e2.y) * 128 + lane * 2);
            int h3 = *(const int*)(Hb + (size_t)__float_as_int(e3.y) * 128 + lane * 2);
            acc0 += e0.x * bf_lo(h0) + e1.x * bf_lo(h1) + e2.x * bf_lo(h2) + e3.x * bf_lo(h3);
            acc1 += e0.x * bf_hi(h0) + e1.x * bf_hi(h1) + e2.x * bf_hi(h2) + e3.x * bf_hi(h3);
        }
        for (; j < cnt; ++j) {
            float2 e0 = xch[wvi][j];
            int h0 = *(const int*)(Hb + (size_t)__float_as_int(e0.y) * 128 + lane * 2);
            acc0 += e0.x * bf_lo(h0); acc1 += e0.x * bf_hi(h0);
        }
    }
    float inv = 1.f / sum;
    size_t o = (size_t)node * 128 + lane * 2;
    out[o]     = acc0 * inv + bias[lane * 2];
    out[o + 1] = acc1 * inv + bias[lane * 2 + 1];
}

extern "C" void kernel_launch(void* const* d_in, const int* in_sizes, int n_in,
                              void* d_out, int out_size, void* d_ws, size_t ws_size,
                              hipStream_t stream) {
    const int Cin = 128, Ch = 256, Co = 128;
    const int N = in_sizes[0] / Cin;        // 50000
    const int E = in_sizes[1] / 2;          // 800000

    const float* x   = (const float*)d_in[0];
    const int*   src = (const int*)d_in[1];
    const int*   dst = src + E;
    const float* ea  = (const float*)d_in[2];
    const float* W1  = (const float*)d_in[3];
    const float* We1 = (const float*)d_in[4];
    const float* as1 = (const float*)d_in[5];
    const float* ad1 = (const float*)d_in[6];
    const float* ae1 = (const float*)d_in[7];
    const float* b1  = (const float*)d_in[8];
    const float* W2  = (const float*)d_in[9];
    const float* We2 = (const float*)d_in[10];
    const float* as2 = (const float*)d_in[11];
    const float* ad2 = (const float*)d_in[12];
    const float* ae2 = (const float*)d_in[13];
    const float* b2  = (const float*)d_in[14];
    float* out = (float*)d_out;

    // workspace layout (4-byte units)
    float* ws = (float*)d_ws;
    size_t off = 0;
    u16* h1b = (u16*)(ws + off); off += (size_t)N * Ch / 2;   // bf16 h (reused as h2b)
    float* ureg  = ws + off; off += (size_t)N * Ch;           // x splits, then g1 splits
    u16* xhi  = (u16*)ureg;
    u16* xlo  = xhi + (size_t)N * Cin;
    u16* g1hi = (u16*)ureg;
    u16* g1lo = g1hi + (size_t)N * Ch;
    float4* epack = (float4*)(ws + off); off += (size_t)E * 4;  // packed CSR edges
    float2* aEe   = (float2*)(ws + off); off += (size_t)E * 2;  // edge-order a_e
    int* row_start = (int*)(ws + off); off += (size_t)N + 1;
    int* cursor    = (int*)(ws + off); off += (size_t)N;
    int* bsum      = (int*)(ws + off); off += 256;
    u16* w1thi = (u16*)(ws + off); off += (size_t)Cin * Ch / 2;
    u16* w1tlo = (u16*)(ws + off); off += (size_t)Cin * Ch / 2;
    u16* w2thi = (u16*)(ws + off); off += (size_t)Ch * Co / 2;
    u16* w2tlo = (u16*)(ws + off); off += (size_t)Ch * Co / 2;
    // contiguous zero-region: deg | asv | adv | misc
    int*   deg  = (int*)(ws + off); off += (size_t)N + 1;
    float* asv  = ws + off; off += (size_t)N;
    float* adv  = ws + off; off += (size_t)N;
    float* misc = ws + off; off += 32;  // [0:8) mean_acc, [8:16) we_vec1, [16:24) we_vec2, [24:26) ae_loop
    float* mean_acc = misc;
    float* we_vec1  = misc + 8;
    float* we_vec2  = misc + 16;
    float* ae_loop  = misc + 24;

    const int n1 = N + 1;
    const int nscan = (n1 + 255) / 256;   // <= 256

    // one memset covers deg+asv+adv+misc (ws is poisoned 0xAA per call)
    hipMemsetAsync(deg, 0, ((size_t)3 * N + 33) * sizeof(float), stream);

    // ---- precompute: we_vec -> edge pass -> CSR -> splits ------------------
    prep_kernel<<<1, 256, 0, stream>>>(We1, ae1, We2, ae2, we_vec1, we_vec2, Ch, Co);
    ea_hist_kernel<<<1024, 256, 0, stream>>>(ea, dst, we_vec1, we_vec2,
                                             mean_acc, deg, aEe, E);
    scan1_kernel<<<nscan, 256, 0, stream>>>(deg, row_start, bsum, N, n1);
    scan2_kernel<<<1, 256, 0, stream>>>(bsum, nscan, mean_acc, 1.0f / (float)E,
                                        we_vec1, we_vec2, ae_loop);
    scan3_kernel<<<nscan, 256, 0, stream>>>(row_start, cursor, bsum, n1, N);
    fill_kernel<<<(E + 255) / 256, 256, 0, stream>>>(src, dst, aEe, cursor, epack, E);
    {
        int n4x = N * Cin / 4;
        int tot = n4x + Cin * Ch + Ch * Co;
        splitall_kernel<<<(tot + 255) / 256, 256, 0, stream>>>(
            x, xhi, xlo, n4x, W1, w1thi, w1tlo, Cin, Ch, W2, w2thi, w2tlo, Ch, Co);
    }

    // ---- layer 1 ----------------------------------------------------------
    {
        dim3 grid(Ch / 128, (N + 127) / 128);
        gemm_mfma_kernel<<<grid, 256, 0, stream>>>(xhi, xlo, w1thi, w1tlo, h1b, N, Cin, Ch,
                                                   as1, ad1, asv, adv);
    }
    agg1_kernel<<<(N + 3) / 4, 256, 0, stream>>>(row_start, epack, asv, adv, ae_loop,
                                                 h1b, g1hi, g1lo, b1, N);

    // ---- layer 2 ----------------------------------------------------------
    hipMemsetAsync(asv, 0, (size_t)2 * N * sizeof(float), stream);  // re-zero for gemm2 dots
    u16* h2b = h1b; // reuse
    {
        dim3 grid(Co / 128, (N + 127) / 128);
        gemm_mfma_kernel<<<grid, 256, 0, stream>>>(g1hi, g1lo, w2thi, w2tlo, h2b, N, Ch, Co,
                                                   as2, ad2, asv, adv);
    }
    agg2_kernel<<<(N + 3) / 4, 256, 0, stream>>>(row_start, epack, asv, adv, ae_loop,
                                                 h2b, out, b2, N);
}

// Round 7
// 401.130 us; speedup vs baseline: 3.7845x; 1.0407x over previous
//
#include <hip/hip_runtime.h>
#include <hip/hip_bf16.h>

// ---------------------------------------------------------------------------
// 2-layer GATConv (heads=1). N=50000, E=800000, Cin=128, Ch=256, Co=128, Ed=8.
// CSR-by-dst + single-pass FLASH softmax-aggregation (no hot-path atomics),
// packed 16B edge structs, 2-term bf16 MFMA GEMMs (A bf16, W hi+lo => ~2^-9
// relative, below the bf16 h-storage rounding), 128x128 tiles, fused
// attention row-dots in the GEMM epilogue.
// ---------------------------------------------------------------------------

#define NEG_SLOPE 0.2f

typedef unsigned short u16;
typedef short short8 __attribute__((ext_vector_type(8)));
typedef float v4f __attribute__((ext_vector_type(4)));
typedef u16 u16x4 __attribute__((ext_vector_type(4)));
typedef u16 u16x8 __attribute__((ext_vector_type(8)));

__device__ __forceinline__ u16 f2bf(float f) {
    unsigned u = __float_as_uint(f);
    return (u16)((u + 0x7fffu + ((u >> 16) & 1u)) >> 16);
}
__device__ __forceinline__ float bf2f(u16 h) {
    return __uint_as_float(((unsigned)h) << 16);
}
__device__ __forceinline__ float bf_lo(int v) { return __uint_as_float(((unsigned)v) << 16); }
__device__ __forceinline__ float bf_hi(int v) { return __uint_as_float(((unsigned)v) & 0xffff0000u); }
__device__ __forceinline__ float lrelu(float x) {
    return x >= 0.f ? x : NEG_SLOPE * x;
}

// ---- we_vec{1,2}[j] = sum_k We[j,k]*a_edge[k]  (params only, runs first) ---
__global__ void prep_kernel(const float* __restrict__ We1, const float* __restrict__ ae1v,
                            const float* __restrict__ We2, const float* __restrict__ ae2v,
                            float* __restrict__ we_vec1, float* __restrict__ we_vec2,
                            int Ch, int Co) {
    __shared__ float red[256];
    int t = threadIdx.x;
    for (int j = 0; j < 8; ++j) {
        float s = 0.f;
        for (int k = t; k < Ch; k += 256) s += We1[j * Ch + k] * ae1v[k];
        red[t] = s; __syncthreads();
        for (int off = 128; off; off >>= 1) { if (t < off) red[t] += red[t + off]; __syncthreads(); }
        if (t == 0) we_vec1[j] = red[0];
        __syncthreads();
        s = 0.f;
        for (int k = t; k < Co; k += 256) s += We2[j * Co + k] * ae2v[k];
        red[t] = s; __syncthreads();
        for (int off = 128; off; off >>= 1) { if (t < off) red[t] += red[t + off]; __syncthreads(); }
        if (t == 0) we_vec2[j] = red[0];
        __syncthreads();
    }
}

// ---- fused: edge_attr col sums + dst histogram + per-edge a_e (edge order) -
__global__ void ea_hist_kernel(const float* __restrict__ ea, const int* __restrict__ dst,
                               const float* __restrict__ we_vec1, const float* __restrict__ we_vec2,
                               float* __restrict__ acc, int* __restrict__ deg,
                               float2* __restrict__ aEe, int E) {
    __shared__ float red[8];
    __shared__ float wv[16];
    int tid = threadIdx.x;
    if (tid < 8) { red[tid] = 0.f; wv[tid] = we_vec1[tid]; }
    else if (tid < 16) wv[tid] = we_vec2[tid - 8];
    __syncthreads();
    float s[8] = {0.f};
    int stride = gridDim.x * blockDim.x;
    for (int e = blockIdx.x * blockDim.x + tid; e < E; e += stride) {
        atomicAdd(&deg[dst[e]], 1);
        const float4 v0 = *(const float4*)&ea[(size_t)e * 8];
        const float4 v1 = *(const float4*)&ea[(size_t)e * 8 + 4];
        s[0] += v0.x; s[1] += v0.y; s[2] += v0.z; s[3] += v0.w;
        s[4] += v1.x; s[5] += v1.y; s[6] += v1.z; s[7] += v1.w;
        float s1 = v0.x * wv[0] + v0.y * wv[1] + v0.z * wv[2] + v0.w * wv[3]
                 + v1.x * wv[4] + v1.y * wv[5] + v1.z * wv[6] + v1.w * wv[7];
        float s2 = v0.x * wv[8] + v0.y * wv[9] + v0.z * wv[10] + v0.w * wv[11]
                 + v1.x * wv[12] + v1.y * wv[13] + v1.z * wv[14] + v1.w * wv[15];
        aEe[e] = make_float2(s1, s2);
    }
#pragma unroll
    for (int j = 0; j < 8; ++j) atomicAdd(&red[j], s[j]);
    __syncthreads();
    if (tid < 8) atomicAdd(&acc[tid], red[tid]);
}

// ---- 3-pass exclusive scan over n = N+1 elements ---------------------------
__global__ void scan1_kernel(const int* __restrict__ deg, int* __restrict__ out,
                             int* __restrict__ bsum, int N, int n) {
    __shared__ int s[256];
    int t = threadIdx.x;
    int i = blockIdx.x * 256 + t;
    int v = (i < N) ? deg[i] : 0;
    s[t] = v; __syncthreads();
    for (int off = 1; off < 256; off <<= 1) {
        int u = (t >= off) ? s[t - off] : 0;
        __syncthreads();
        s[t] += u;
        __syncthreads();
    }
    if (i < n) out[i] = s[t] - v;
    if (t == 255) bsum[blockIdx.x] = s[255];
}

// scan2 also computes ae_loop (self-loop attention term) from the ea means
__global__ void scan2_kernel(int* __restrict__ bsum, int nb,
                             const float* __restrict__ mean_acc, float Einv,
                             const float* __restrict__ we_vec1, const float* __restrict__ we_vec2,
                             float* __restrict__ ae_loop) {
    __shared__ int s[256];
    int t = threadIdx.x;
    if (t == 0) {
        float s1 = 0.f, s2 = 0.f;
        for (int j = 0; j < 8; ++j) {
            float m = mean_acc[j] * Einv;
            s1 += m * we_vec1[j];
            s2 += m * we_vec2[j];
        }
        ae_loop[0] = s1; ae_loop[1] = s2;
    }
    int v = (t < nb) ? bsum[t] : 0;
    s[t] = v; __syncthreads();
    for (int off = 1; off < 256; off <<= 1) {
        int u = (t >= off) ? s[t - off] : 0;
        __syncthreads();
        s[t] += u;
        __syncthreads();
    }
    if (t < nb) bsum[t] = s[t] - v;
}

// scan3 also initializes the fill cursor
__global__ void scan3_kernel(int* __restrict__ out, int* __restrict__ cursor,
                             const int* __restrict__ bsum, int n, int N) {
    int i = blockIdx.x * 256 + threadIdx.x;
    if (i < n) {
        int v = out[i] + bsum[blockIdx.x];
        out[i] = v;
        if (i < N) cursor[i] = v;
    }
}

// ---- CSR fill: ONE packed 16B store per edge {src_bits, ae1, ae2, pad} -----
__global__ void fill_kernel(const int* __restrict__ src, const int* __restrict__ dst,
                            const float2* __restrict__ aEe,
                            int* __restrict__ cursor, float4* __restrict__ epack, int E) {
    int e = blockIdx.x * blockDim.x + threadIdx.x;
    if (e >= E) return;
    int d = dst[e];
    int idx = atomicAdd(&cursor[d], 1);
    float2 a = aEe[e];
    epack[idx] = make_float4(__int_as_float(src[e]), a.x, a.y, 0.f);
}

// ---- merged convert/split: x -> bf16; W1^T, W2^T -> bf16 hi/lo -------------
__global__ void splitall_kernel(const float* __restrict__ x, u16* __restrict__ xb, int n4x,
                                const float* __restrict__ W1, u16* __restrict__ w1thi,
                                u16* __restrict__ w1tlo, int K1, int M1,
                                const float* __restrict__ W2, u16* __restrict__ w2thi,
                                u16* __restrict__ w2tlo, int K2, int M2) {
    int idx = blockIdx.x * 256 + threadIdx.x;
    if (idx < n4x) {
        float4 v = ((const float4*)x)[idx];
        u16x4 h;
        h.x = f2bf(v.x); h.y = f2bf(v.y); h.z = f2bf(v.z); h.w = f2bf(v.w);
        ((u16x4*)xb)[idx] = h;
        return;
    }
    int t = idx - n4x;
    if (t < K1 * M1) {
        int k = t / M1, m = t - k * M1;
        float v = W1[t];
        u16 h = f2bf(v);
        w1thi[(size_t)m * K1 + k] = h;
        w1tlo[(size_t)m * K1 + k] = f2bf(v - bf2f(h));
        return;
    }
    t -= K1 * M1;
    if (t < K2 * M2) {
        int k = t / M2, m = t - k * M2;
        float v = W2[t];
        u16 h = f2bf(v);
        w2thi[(size_t)m * K2 + k] = h;
        w2tlo[(size_t)m * K2 + k] = f2bf(v - bf2f(h));
    }
}

// ---- 2-term bf16 MFMA GEMM, 128x128 tile + fused attention row-dots --------
// Cb[N,M] = bf16(A@B); as_out[r] += sum_c C[r,c]*av[c] (atomic), ad same w/ bv.
// A row-major [N][K] bf16; B TRANSPOSED [M][K] hi/lo bf16. BK=32, 4 waves,
// each a 64x64 quadrant (4x4 of 16x16x32 MFMA, 2 split terms).
#define BK 32
#define LDA 40   // 32 + 8 pad (u16)
__global__ __launch_bounds__(256) void gemm_mfma_kernel(
        const u16* __restrict__ A_g,
        const u16* __restrict__ Bh_g, const u16* __restrict__ Bl_g,
        u16* __restrict__ Cb, int Nrows, int K, int M,
        const float* __restrict__ av, const float* __restrict__ bv,
        float* __restrict__ as_out, float* __restrict__ ad_out) {
    __shared__ u16 Ah[128 * LDA], Bh[128 * LDA], Bl[128 * LDA];
    int tid = threadIdx.x;
    int lane = tid & 63;
    int wv = tid >> 6;
    int wm = wv >> 1, wn = wv & 1;
    int l15 = lane & 15, quad = lane >> 4;
    int rb = blockIdx.y * 128;
    int cb = blockIdx.x * 128;

    v4f acc[4][4];
#pragma unroll
    for (int mi = 0; mi < 4; ++mi)
#pragma unroll
        for (int ni = 0; ni < 4; ++ni) acc[mi][ni] = (v4f){0.f, 0.f, 0.f, 0.f};

    int sr = tid >> 1;            // staging row 0..127
    int sc = (tid & 1) * 16;      // staging col 0 or 16

    for (int kc = 0; kc < K; kc += BK) {
        int gr = rb + sr;
        u16x8 z = {0, 0, 0, 0, 0, 0, 0, 0};
        u16x8 a0 = z, a1 = z;
        if (gr < Nrows) {
            size_t ba = (size_t)gr * K + kc + sc;
            a0 = *(const u16x8*)(A_g + ba);
            a1 = *(const u16x8*)(A_g + ba + 8);
        }
        size_t bb = (size_t)(cb + sr) * K + kc + sc;
        u16x8 b0 = *(const u16x8*)(Bh_g + bb);
        u16x8 b1 = *(const u16x8*)(Bh_g + bb + 8);
        u16x8 b2 = *(const u16x8*)(Bl_g + bb);
        u16x8 b3 = *(const u16x8*)(Bl_g + bb + 8);
        *(u16x8*)&Ah[sr * LDA + sc] = a0;
        *(u16x8*)&Ah[sr * LDA + sc + 8] = a1;
        *(u16x8*)&Bh[sr * LDA + sc] = b0;
        *(u16x8*)&Bh[sr * LDA + sc + 8] = b1;
        *(u16x8*)&Bl[sr * LDA + sc] = b2;
        *(u16x8*)&Bl[sr * LDA + sc + 8] = b3;
        __syncthreads();
        short8 ah[4], bh[4], bl[4];
#pragma unroll
        for (int mi = 0; mi < 4; ++mi) {
            int r = (wm * 64 + mi * 16 + l15) * LDA + quad * 8;
            ah[mi] = *(const short8*)&Ah[r];
        }
#pragma unroll
        for (int ni = 0; ni < 4; ++ni) {
            int r = (wn * 64 + ni * 16 + l15) * LDA + quad * 8;
            bh[ni] = *(const short8*)&Bh[r];
            bl[ni] = *(const short8*)&Bl[r];
        }
#pragma unroll
        for (int mi = 0; mi < 4; ++mi)
#pragma unroll
            for (int ni = 0; ni < 4; ++ni) {
                acc[mi][ni] = __builtin_amdgcn_mfma_f32_16x16x32_bf16(ah[mi], bh[ni], acc[mi][ni], 0, 0, 0);
                acc[mi][ni] = __builtin_amdgcn_mfma_f32_16x16x32_bf16(ah[mi], bl[ni], acc[mi][ni], 0, 0, 0);
            }
        __syncthreads();
    }
    // C/D layout: col = lane&15, row = quad*4 + reg
#pragma unroll
    for (int mi = 0; mi < 4; ++mi)
#pragma unroll
        for (int ni = 0; ni < 4; ++ni) {
#pragma unroll
            for (int reg = 0; reg < 4; ++reg) {
                int row = rb + wm * 64 + mi * 16 + quad * 4 + reg;
                if (row < Nrows)
                    Cb[(size_t)row * M + cb + wn * 64 + ni * 16 + l15] = f2bf(acc[mi][ni][reg]);
            }
        }
    // fused row-dots over this wave's 64 cols
    float sd[4][4] = {}, dd[4][4] = {};
#pragma unroll
    for (int ni = 0; ni < 4; ++ni) {
        int col = cb + wn * 64 + ni * 16 + l15;
        float a = av[col], b = bv[col];
#pragma unroll
        for (int mi = 0; mi < 4; ++mi)
#pragma unroll
            for (int reg = 0; reg < 4; ++reg) {
                sd[mi][reg] += acc[mi][ni][reg] * a;
                dd[mi][reg] += acc[mi][ni][reg] * b;
            }
    }
#pragma unroll
    for (int off = 1; off < 16; off <<= 1)
#pragma unroll
        for (int mi = 0; mi < 4; ++mi)
#pragma unroll
            for (int reg = 0; reg < 4; ++reg) {
                sd[mi][reg] += __shfl_xor(sd[mi][reg], off);
                dd[mi][reg] += __shfl_xor(dd[mi][reg], off);
            }
    if (l15 == 0) {
#pragma unroll
        for (int mi = 0; mi < 4; ++mi) {
            int row0 = rb + wm * 64 + mi * 16 + quad * 4;
#pragma unroll
            for (int reg = 0; reg < 4; ++reg) {
                if (row0 + reg < Nrows) {
                    atomicAdd(as_out + row0 + reg, sd[mi][reg]);
                    atomicAdd(ad_out + row0 + reg, dd[mi][reg]);
                }
            }
        }
    }
}

// ---- single-pass FLASH softmax-aggregation, L1 (C=256), wave per node ------
// Epilogue: t = relu(acc/sum + b1); store bf16 (layer-2 GEMM A input).
__global__ __launch_bounds__(256) void agg1_kernel(const int* __restrict__ row_start,
                                                   const float4* __restrict__ epack,
                                                   const float* __restrict__ asv,
                                                   const float* __restrict__ adv,
                                                   const float* __restrict__ ae_loop,
                                                   const u16* __restrict__ Hb,
                                                   u16* __restrict__ ohi,
                                                   const float* __restrict__ bias, int N) {
    __shared__ float2 xch[4][64];
    int lane = threadIdx.x & 63;
    int wvi = threadIdx.x >> 6;
    int node = blockIdx.x * 4 + wvi;
    if (node >= N) return;
    int st = row_start[node], en = row_start[node + 1];
    float ad = adv[node];
    float aloop = lrelu(asv[node] + ad + ae_loop[0]);
    float m = aloop, sum = 1.f;        // self-loop: weight exp(aloop-m)=1
    float acc0, acc1, acc2, acc3;
    {
        int2 hv = *(const int2*)(Hb + (size_t)node * 256 + lane * 4);
        acc0 = bf_lo(hv.x); acc1 = bf_hi(hv.x);
        acc2 = bf_lo(hv.y); acc3 = bf_hi(hv.y);
    }
    for (int base = st; base < en; base += 64) {
        int i = base + lane;
        float al = -3.0e38f; int sreg = 0;
        if (i < en) {
            float4 ep = epack[i];
            sreg = __float_as_int(ep.x);
            al = lrelu(asv[sreg] + ad + ep.y);
        }
        float cm = al;
#pragma unroll
        for (int o = 1; o < 64; o <<= 1) cm = fmaxf(cm, __shfl_xor(cm, o));
        if (cm > m) {
            float sc = __expf(m - cm);
            acc0 *= sc; acc1 *= sc; acc2 *= sc; acc3 *= sc;
            sum *= sc; m = cm;
        }
        float w = (i < en) ? __expf(al - m) : 0.f;
        float wsum = w;
#pragma unroll
        for (int o = 1; o < 64; o <<= 1) wsum += __shfl_xor(wsum, o);
        sum += wsum;
        xch[wvi][lane] = make_float2(w, __int_as_float(sreg));
        int cnt = min(64, en - base);
        int j = 0;
        for (; j + 4 <= cnt; j += 4) {
            float2 e0 = xch[wvi][j], e1 = xch[wvi][j + 1];
            float2 e2 = xch[wvi][j + 2], e3 = xch[wvi][j + 3];
            int2 h0 = *(const int2*)(Hb + (size_t)__float_as_int(e0.y) * 256 + lane * 4);
            int2 h1 = *(const int2*)(Hb + (size_t)__float_as_int(e1.y) * 256 + lane * 4);
            int2 h2 = *(const int2*)(Hb + (size_t)__float_as_int(e2.y) * 256 + lane * 4);
            int2 h3 = *(const int2*)(Hb + (size_t)__float_as_int(e3.y) * 256 + lane * 4);
            acc0 += e0.x * bf_lo(h0.x) + e1.x * bf_lo(h1.x) + e2.x * bf_lo(h2.x) + e3.x * bf_lo(h3.x);
            acc1 += e0.x * bf_hi(h0.x) + e1.x * bf_hi(h1.x) + e2.x * bf_hi(h2.x) + e3.x * bf_hi(h3.x);
            acc2 += e0.x * bf_lo(h0.y) + e1.x * bf_lo(h1.y) + e2.x * bf_lo(h2.y) + e3.x * bf_lo(h3.y);
            acc3 += e0.x * bf_hi(h0.y) + e1.x * bf_hi(h1.y) + e2.x * bf_hi(h2.y) + e3.x * bf_hi(h3.y);
        }
        for (; j < cnt; ++j) {
            float2 e0 = xch[wvi][j];
            int2 h0 = *(const int2*)(Hb + (size_t)__float_as_int(e0.y) * 256 + lane * 4);
            acc0 += e0.x * bf_lo(h0.x); acc1 += e0.x * bf_hi(h0.x);
            acc2 += e0.x * bf_lo(h0.y); acc3 += e0.x * bf_hi(h0.y);
        }
    }
    float inv = 1.f / sum;
    const float4 bvv = *(const float4*)(bias + lane * 4);
    float t0 = acc0 * inv + bvv.x, t1 = acc1 * inv + bvv.y;
    float t2 = acc2 * inv + bvv.z, t3 = acc3 * inv + bvv.w;
    t0 = t0 > 0.f ? t0 : 0.f; t1 = t1 > 0.f ? t1 : 0.f;
    t2 = t2 > 0.f ? t2 : 0.f; t3 = t3 > 0.f ? t3 : 0.f;
    u16x4 h;
    h.x = f2bf(t0); h.y = f2bf(t1); h.z = f2bf(t2); h.w = f2bf(t3);
    *(u16x4*)(ohi + (size_t)node * 256 + lane * 4) = h;
}

// ---- single-pass FLASH softmax-aggregation, L2 (C=128) ---------------------
__global__ __launch_bounds__(256) void agg2_kernel(const int* __restrict__ row_start,
                                                   const float4* __restrict__ epack,
                                                   const float* __restrict__ asv,
                                                   const float* __restrict__ adv,
                                                   const float* __restrict__ ae_loop,
                                                   const u16* __restrict__ Hb,
                                                   float* __restrict__ out,
                                                   const float* __restrict__ bias, int N) {
    __shared__ float2 xch[4][64];
    int lane = threadIdx.x & 63;
    int wvi = threadIdx.x >> 6;
    int node = blockIdx.x * 4 + wvi;
    if (node >= N) return;
    int st = row_start[node], en = row_start[node + 1];
    float ad = adv[node];
    float aloop = lrelu(asv[node] + ad + ae_loop[1]);
    float m = aloop, sum = 1.f;
    float acc0, acc1;
    {
        int hv = *(const int*)(Hb + (size_t)node * 128 + lane * 2);
        acc0 = bf_lo(hv); acc1 = bf_hi(hv);
    }
    for (int base = st; base < en; base += 64) {
        int i = base + lane;
        float al = -3.0e38f; int sreg = 0;
        if (i < en) {
            float4 ep = epack[i];
            sreg = __float_as_int(ep.x);
            al = lrelu(asv[sreg] + ad + ep.z);
        }
        float cm = al;
#pragma unroll
        for (int o = 1; o < 64; o <<= 1) cm = fmaxf(cm, __shfl_xor(cm, o));
        if (cm > m) {
            float sc = __expf(m - cm);
            acc0 *= sc; acc1 *= sc;
            sum *= sc; m = cm;
        }
        float w = (i < en) ? __expf(al - m) : 0.f;
        float wsum = w;
#pragma unroll
        for (int o = 1; o < 64; o <<= 1) wsum += __shfl_xor(wsum, o);
        sum += wsum;
        xch[wvi][lane] = make_float2(w, __int_as_float(sreg));
        int cnt = min(64, en - base);
        int j = 0;
        for (; j + 4 <= cnt; j += 4) {
            float2 e0 = xch[wvi][j], e1 = xch[wvi][j + 1];
            float2 e2 = xch[wvi][j + 2], e3 = xch[wvi][j + 3];
            int h0 = *(const int*)(Hb + (size_t)__float_as_int(e0.y) * 128 + lane * 2);
            int h1 = *(const int*)(Hb + (size_t)__float_as_int(e1.y) * 128 + lane * 2);
            int h2 = *(const int*)(Hb + (size_t)__float_as_int(e2.y) * 128 + lane * 2);
            int h3 = *(const int*)(Hb + (size_t)__float_as_int(e3.y) * 128 + lane * 2);
            acc0 += e0.x * bf_lo(h0) + e1.x * bf_lo(h1) + e2.x * bf_lo(h2) + e3.x * bf_lo(h3);
            acc1 += e0.x * bf_hi(h0) + e1.x * bf_hi(h1) + e2.x * bf_hi(h2) + e3.x * bf_hi(h3);
        }
        for (; j < cnt; ++j) {
            float2 e0 = xch[wvi][j];
            int h0 = *(const int*)(Hb + (size_t)__float_as_int(e0.y) * 128 + lane * 2);
            acc0 += e0.x * bf_lo(h0); acc1 += e0.x * bf_hi(h0);
        }
    }
    float inv = 1.f / sum;
    size_t o = (size_t)node * 128 + lane * 2;
    out[o]     = acc0 * inv + bias[lane * 2];
    out[o + 1] = acc1 * inv + bias[lane * 2 + 1];
}

extern "C" void kernel_launch(void* const* d_in, const int* in_sizes, int n_in,
                              void* d_out, int out_size, void* d_ws, size_t ws_size,
                              hipStream_t stream) {
    const int Cin = 128, Ch = 256, Co = 128;
    const int N = in_sizes[0] / Cin;        // 50000
    const int E = in_sizes[1] / 2;          // 800000

    const float* x   = (const float*)d_in[0];
    const int*   src = (const int*)d_in[1];
    const int*   dst = src + E;
    const float* ea  = (const float*)d_in[2];
    const float* W1  = (const float*)d_in[3];
    const float* We1 = (const float*)d_in[4];
    const float* as1 = (const float*)d_in[5];
    const float* ad1 = (const float*)d_in[6];
    const float* ae1 = (const float*)d_in[7];
    const float* b1  = (const float*)d_in[8];
    const float* W2  = (const float*)d_in[9];
    const float* We2 = (const float*)d_in[10];
    const float* as2 = (const float*)d_in[11];
    const float* ad2 = (const float*)d_in[12];
    const float* ae2 = (const float*)d_in[13];
    const float* b2  = (const float*)d_in[14];
    float* out = (float*)d_out;

    // workspace layout (4-byte units)
    float* ws = (float*)d_ws;
    size_t off = 0;
    u16* h1b = (u16*)(ws + off); off += (size_t)N * Ch / 2;   // bf16 h (reused as h2b)
    // union region: x bf16 until gemm1 consumes it, then g1 bf16 (agg1 output)
    float* ureg  = ws + off; off += (size_t)N * Ch / 2;
    u16* xb   = (u16*)ureg;                                   // N*Cin u16
    u16* g1b  = (u16*)ureg;                                   // N*Ch u16
    float4* epack = (float4*)(ws + off); off += (size_t)E * 4;  // packed CSR edges
    float2* aEe   = (float2*)(ws + off); off += (size_t)E * 2;  // edge-order a_e
    int* row_start = (int*)(ws + off); off += (size_t)N + 1;
    int* cursor    = (int*)(ws + off); off += (size_t)N;
    int* bsum      = (int*)(ws + off); off += 256;
    u16* w1thi = (u16*)(ws + off); off += (size_t)Cin * Ch / 2;
    u16* w1tlo = (u16*)(ws + off); off += (size_t)Cin * Ch / 2;
    u16* w2thi = (u16*)(ws + off); off += (size_t)Ch * Co / 2;
    u16* w2tlo = (u16*)(ws + off); off += (size_t)Ch * Co / 2;
    // contiguous zero-region: deg | asv1 adv1 asv2 adv2 | misc
    int*   deg  = (int*)(ws + off); off += (size_t)N + 1;
    float* asv1 = ws + off; off += (size_t)N;
    float* adv1 = ws + off; off += (size_t)N;
    float* asv2 = ws + off; off += (size_t)N;
    float* adv2 = ws + off; off += (size_t)N;
    float* misc = ws + off; off += 32;  // [0:8) mean_acc, [8:16) we_vec1, [16:24) we_vec2, [24:26) ae_loop
    float* mean_acc = misc;
    float* we_vec1  = misc + 8;
    float* we_vec2  = misc + 16;
    float* ae_loop  = misc + 24;

    const int n1 = N + 1;
    const int nscan = (n1 + 255) / 256;   // <= 256

    // one memset covers deg + 4 dot-buffers + misc (ws is poisoned per call)
    hipMemsetAsync(deg, 0, ((size_t)5 * N + 33) * sizeof(float), stream);

    // ---- precompute: we_vec -> edge pass -> CSR -> converts ----------------
    prep_kernel<<<1, 256, 0, stream>>>(We1, ae1, We2, ae2, we_vec1, we_vec2, Ch, Co);
    ea_hist_kernel<<<1024, 256, 0, stream>>>(ea, dst, we_vec1, we_vec2,
                                             mean_acc, deg, aEe, E);
    scan1_kernel<<<nscan, 256, 0, stream>>>(deg, row_start, bsum, N, n1);
    scan2_kernel<<<1, 256, 0, stream>>>(bsum, nscan, mean_acc, 1.0f / (float)E,
                                        we_vec1, we_vec2, ae_loop);
    scan3_kernel<<<nscan, 256, 0, stream>>>(row_start, cursor, bsum, n1, N);
    fill_kernel<<<(E + 255) / 256, 256, 0, stream>>>(src, dst, aEe, cursor, epack, E);
    {
        int n4x = N * Cin / 4;
        int tot = n4x + Cin * Ch + Ch * Co;
        splitall_kernel<<<(tot + 255) / 256, 256, 0, stream>>>(
            x, xb, n4x, W1, w1thi, w1tlo, Cin, Ch, W2, w2thi, w2tlo, Ch, Co);
    }

    // ---- layer 1 ----------------------------------------------------------
    {
        dim3 grid(Ch / 128, (N + 127) / 128);
        gemm_mfma_kernel<<<grid, 256, 0, stream>>>(xb, w1thi, w1tlo, h1b, N, Cin, Ch,
                                                   as1, ad1, asv1, adv1);
    }
    agg1_kernel<<<(N + 3) / 4, 256, 0, stream>>>(row_start, epack, asv1, adv1, ae_loop,
                                                 h1b, g1b, b1, N);

    // ---- layer 2 ----------------------------------------------------------
    u16* h2b = h1b; // reuse (agg1 consumed h1b)
    {
        dim3 grid(Co / 128, (N + 127) / 128);
        gemm_mfma_kernel<<<grid, 256, 0, stream>>>(g1b, w2thi, w2tlo, h2b, N, Ch, Co,
                                                   as2, ad2, asv2, adv2);
    }
    agg2_kernel<<<(N + 3) / 4, 256, 0, stream>>>(row_start, epack, asv2, adv2, ae_loop,
                                                 h2b, out, b2, N);
}

// Round 8
// 397.944 us; speedup vs baseline: 3.8148x; 1.0080x over previous
//
#include <hip/hip_runtime.h>
#include <hip/hip_bf16.h>

// ---------------------------------------------------------------------------
// 2-layer GATConv (heads=1). N=50000, E=800000, Cin=128, Ch=256, Co=128, Ed=8.
// 7-dispatch pipeline:
//   memset | [ea_hist ∥ W-split] | fused-scan | [gemm1 ∥ CSR-fill] | agg1 |
//   gemm2 | agg2
// CSR-by-dst + single-pass flash softmax-aggregation, 2-term bf16 MFMA GEMMs
// (A bf16, W hi+lo), fused attention row-dots in GEMM epilogue.
// ---------------------------------------------------------------------------

#define NEG_SLOPE 0.2f
#define EHB 1024           // ea_hist blocks inside pre_fat

typedef unsigned short u16;
typedef short short8 __attribute__((ext_vector_type(8)));
typedef float v4f __attribute__((ext_vector_type(4)));
typedef u16 u16x4 __attribute__((ext_vector_type(4)));
typedef u16 u16x8 __attribute__((ext_vector_type(8)));

__device__ __forceinline__ u16 f2bf(float f) {
    unsigned u = __float_as_uint(f);
    return (u16)((u + 0x7fffu + ((u >> 16) & 1u)) >> 16);
}
__device__ __forceinline__ float bf2f(u16 h) {
    return __uint_as_float(((unsigned)h) << 16);
}
__device__ __forceinline__ float bf_lo(int v) { return __uint_as_float(((unsigned)v) << 16); }
__device__ __forceinline__ float bf_hi(int v) { return __uint_as_float(((unsigned)v) & 0xffff0000u); }
__device__ __forceinline__ float lrelu(float x) {
    return x >= 0.f ? x : NEG_SLOPE * x;
}
__device__ __forceinline__ int ld_acq(int* p) {
    return __hip_atomic_load(p, __ATOMIC_ACQUIRE, __HIP_MEMORY_SCOPE_AGENT);
}
__device__ __forceinline__ void st_rel(int* p, int v) {
    __hip_atomic_store(p, v, __ATOMIC_RELEASE, __HIP_MEMORY_SCOPE_AGENT);
}

// ---- FAT A: [blocks 0..EHB): edge_attr sums + dst hist + per-edge a_e ------
//             [blocks EHB..): W1^T / W2^T bf16 hi/lo splits
// we_vec computed per-block in LDS (replaces prep_kernel); block 0 publishes.
__global__ __launch_bounds__(256) void pre_fat_kernel(
        const float* __restrict__ ea, const int* __restrict__ dst,
        const float* __restrict__ We1, const float* __restrict__ ae1v,
        const float* __restrict__ We2, const float* __restrict__ ae2v,
        float* __restrict__ mean_acc, int* __restrict__ deg,
        float2* __restrict__ aEe, int E,
        const float* __restrict__ W1, u16* __restrict__ w1thi, u16* __restrict__ w1tlo,
        const float* __restrict__ W2, u16* __restrict__ w2thi, u16* __restrict__ w2tlo,
        float* __restrict__ we_vec1g, float* __restrict__ we_vec2g) {
    int tid = threadIdx.x;
    if (blockIdx.x >= EHB) {
        // ---- W splits: 65536 elements over 256 blocks ----
        int t = (blockIdx.x - EHB) * 256 + tid;
        if (t < 128 * 256) {               // W1 [Cin=128][Ch=256]
            int k = t >> 8, m = t & 255;
            float v = W1[t];
            u16 h = f2bf(v);
            w1thi[(size_t)m * 128 + k] = h;
            w1tlo[(size_t)m * 128 + k] = f2bf(v - bf2f(h));
        } else {                           // W2 [Ch=256][Co=128]
            t -= 128 * 256;
            int k = t >> 7, m = t & 127;
            float v = W2[t];
            u16 h = f2bf(v);
            w2thi[(size_t)m * 256 + k] = h;
            w2tlo[(size_t)m * 256 + k] = f2bf(v - bf2f(h));
        }
        return;
    }
    // ---- ea_hist ----
    __shared__ float red[8];
    __shared__ float wv[16];
    if (tid < 16) { wv[tid] = 0.f; if (tid < 8) red[tid] = 0.f; }
    __syncthreads();
    {   // per-block we_vec: wv[j] = sum_k We1[j][k]*ae1v[k]; wv[8+j] for We2
        float a1 = ae1v[tid];              // Ch == 256 == blockDim
        int lane = tid & 63;
#pragma unroll
        for (int j = 0; j < 8; ++j) {
            float v = We1[j * 256 + tid] * a1;
#pragma unroll
            for (int o = 32; o; o >>= 1) v += __shfl_down(v, o);
            if (lane == 0) atomicAdd(&wv[j], v);
        }
        if (tid < 128) {
            float a2 = ae2v[tid];          // Co == 128
#pragma unroll
            for (int j = 0; j < 8; ++j) {
                float v = We2[j * 128 + tid] * a2;
#pragma unroll
                for (int o = 32; o; o >>= 1) v += __shfl_down(v, o);
                if (lane == 0) atomicAdd(&wv[8 + j], v);
            }
        }
    }
    __syncthreads();
    if (blockIdx.x == 0 && tid < 16) {
        if (tid < 8) we_vec1g[tid] = wv[tid];
        else         we_vec2g[tid - 8] = wv[tid];
    }
    float s[8] = {0.f};
    int stride = EHB * 256;
    for (int e = blockIdx.x * 256 + tid; e < E; e += stride) {
        atomicAdd(&deg[dst[e]], 1);
        const float4 v0 = *(const float4*)&ea[(size_t)e * 8];
        const float4 v1 = *(const float4*)&ea[(size_t)e * 8 + 4];
        s[0] += v0.x; s[1] += v0.y; s[2] += v0.z; s[3] += v0.w;
        s[4] += v1.x; s[5] += v1.y; s[6] += v1.z; s[7] += v1.w;
        float s1 = v0.x * wv[0] + v0.y * wv[1] + v0.z * wv[2] + v0.w * wv[3]
                 + v1.x * wv[4] + v1.y * wv[5] + v1.z * wv[6] + v1.w * wv[7];
        float s2 = v0.x * wv[8] + v0.y * wv[9] + v0.z * wv[10] + v0.w * wv[11]
                 + v1.x * wv[12] + v1.y * wv[13] + v1.z * wv[14] + v1.w * wv[15];
        aEe[e] = make_float2(s1, s2);
    }
#pragma unroll
    for (int j = 0; j < 8; ++j) atomicAdd(&red[j], s[j]);
    __syncthreads();
    if (tid < 8) atomicAdd(&mean_acc[tid], red[tid]);
}

// ---- fused single-kernel exclusive scan (196 blocks, all co-resident) ------
// Also writes cursor and computes ae_loop. Barrier: deposit partial -> last
// arriver scans partials -> flag -> everyone resumes.
__global__ __launch_bounds__(256) void scan_fused_kernel(
        const int* __restrict__ deg, int* __restrict__ row_start,
        int* __restrict__ cursor, int* __restrict__ partials, int* __restrict__ pprefix,
        int* __restrict__ gcount, int* __restrict__ gflag, int N, int n,
        const float* __restrict__ mean_acc, float Einv,
        const float* __restrict__ we_vec1, const float* __restrict__ we_vec2,
        float* __restrict__ ae_loop) {
    __shared__ int s[256];
    __shared__ int amLast, bprefix;
    int t = threadIdx.x, bid = blockIdx.x;
    int i = bid * 256 + t;
    int v = (i < N) ? deg[i] : 0;
    s[t] = v; __syncthreads();
    for (int off = 1; off < 256; off <<= 1) {
        int u = (t >= off) ? s[t - off] : 0;
        __syncthreads();
        s[t] += u;
        __syncthreads();
    }
    int incl = s[t];
    int total = s[255];
    if (t == 0) {
        partials[bid] = total;
        __threadfence();
        int c = __hip_atomic_fetch_add(gcount, 1, __ATOMIC_ACQ_REL, __HIP_MEMORY_SCOPE_AGENT);
        amLast = (c == (int)gridDim.x - 1);
    }
    __syncthreads();
    if (amLast) {
        int G = gridDim.x;
        int pv = (t < G) ? ld_acq(&partials[t]) : 0;
        __syncthreads();           // s[] reuse
        s[t] = pv; __syncthreads();
        for (int off = 1; off < 256; off <<= 1) {
            int u = (t >= off) ? s[t - off] : 0;
            __syncthreads();
            s[t] += u;
            __syncthreads();
        }
        if (t < G) pprefix[t] = s[t] - pv;
        if (t == 0) {
            float s1 = 0.f, s2 = 0.f;
#pragma unroll
            for (int j = 0; j < 8; ++j) {
                float m = mean_acc[j] * Einv;
                s1 += m * we_vec1[j];
                s2 += m * we_vec2[j];
            }
            ae_loop[0] = s1; ae_loop[1] = s2;
        }
        __threadfence();
        __syncthreads();
        if (t == 0) st_rel(gflag, 1);
    }
    if (t == 0) {
        while (ld_acq(gflag) == 0) __builtin_amdgcn_s_sleep(2);
        bprefix = ld_acq(&pprefix[bid]);
    }
    __syncthreads();
    int ex = bprefix + incl - v;
    if (i < n) row_start[i] = ex;
    if (i < N) cursor[i] = ex;
}

// ---- FAT B: [blocks 0..Gg): gemm1 (A = fp32 x, converted while staging)
//             [blocks Gg..): CSR fill (one packed 16B store per edge)
// gemm: Cb = bf16(A@B), fused row-dots into as/ad (atomic). 128x128, BK=32.
#define BK 32
#define LDA 40   // 32 + 8 pad (u16)
__global__ __launch_bounds__(256) void gemm1_fill_fat_kernel(
        const float* __restrict__ A32,
        const u16* __restrict__ Bh_g, const u16* __restrict__ Bl_g,
        u16* __restrict__ Cb, int Nrows, int K, int M,
        const float* __restrict__ av, const float* __restrict__ bv,
        float* __restrict__ as_out, float* __restrict__ ad_out, int Gg, int gx,
        const int* __restrict__ src, const int* __restrict__ dst,
        const float2* __restrict__ aEe, int* __restrict__ cursor,
        float4* __restrict__ epack, int E) {
    __shared__ u16 Ah[128 * LDA], Bh[128 * LDA], Bl[128 * LDA];
    int tid = threadIdx.x;
    if ((int)blockIdx.x >= Gg) {
        int e = ((int)blockIdx.x - Gg) * 256 + tid;
        if (e < E) {
            int d = dst[e];
            int idx = atomicAdd(&cursor[d], 1);
            float2 a = aEe[e];
            epack[idx] = make_float4(__int_as_float(src[e]), a.x, a.y, 0.f);
        }
        return;
    }
    int lane = tid & 63;
    int wv = tid >> 6;
    int wm = wv >> 1, wn = wv & 1;
    int l15 = lane & 15, quad = lane >> 4;
    int rb = ((int)blockIdx.x / gx) * 128;
    int cb = ((int)blockIdx.x % gx) * 128;

    v4f acc[4][4];
#pragma unroll
    for (int mi = 0; mi < 4; ++mi)
#pragma unroll
        for (int ni = 0; ni < 4; ++ni) acc[mi][ni] = (v4f){0.f, 0.f, 0.f, 0.f};

    int sr = tid >> 1;
    int sc = (tid & 1) * 16;

    for (int kc = 0; kc < K; kc += BK) {
        int gr = rb + sr;
        u16x8 a0 = {0,0,0,0,0,0,0,0}, a1 = {0,0,0,0,0,0,0,0};
        if (gr < Nrows) {
            const float* pa = A32 + (size_t)gr * K + kc + sc;
            float4 f0 = *(const float4*)pa;
            float4 f1 = *(const float4*)(pa + 4);
            float4 f2 = *(const float4*)(pa + 8);
            float4 f3 = *(const float4*)(pa + 12);
            a0 = (u16x8){f2bf(f0.x), f2bf(f0.y), f2bf(f0.z), f2bf(f0.w),
                         f2bf(f1.x), f2bf(f1.y), f2bf(f1.z), f2bf(f1.w)};
            a1 = (u16x8){f2bf(f2.x), f2bf(f2.y), f2bf(f2.z), f2bf(f2.w),
                         f2bf(f3.x), f2bf(f3.y), f2bf(f3.z), f2bf(f3.w)};
        }
        size_t bb = (size_t)(cb + sr) * K + kc + sc;
        u16x8 b0 = *(const u16x8*)(Bh_g + bb);
        u16x8 b1 = *(const u16x8*)(Bh_g + bb + 8);
        u16x8 b2 = *(const u16x8*)(Bl_g + bb);
        u16x8 b3 = *(const u16x8*)(Bl_g + bb + 8);
        *(u16x8*)&Ah[sr * LDA + sc] = a0;
        *(u16x8*)&Ah[sr * LDA + sc + 8] = a1;
        *(u16x8*)&Bh[sr * LDA + sc] = b0;
        *(u16x8*)&Bh[sr * LDA + sc + 8] = b1;
        *(u16x8*)&Bl[sr * LDA + sc] = b2;
        *(u16x8*)&Bl[sr * LDA + sc + 8] = b3;
        __syncthreads();
        short8 ah[4], bh[4], bl[4];
#pragma unroll
        for (int mi = 0; mi < 4; ++mi)
            ah[mi] = *(const short8*)&Ah[(wm * 64 + mi * 16 + l15) * LDA + quad * 8];
#pragma unroll
        for (int ni = 0; ni < 4; ++ni) {
            int r = (wn * 64 + ni * 16 + l15) * LDA + quad * 8;
            bh[ni] = *(const short8*)&Bh[r];
            bl[ni] = *(const short8*)&Bl[r];
        }
#pragma unroll
        for (int mi = 0; mi < 4; ++mi)
#pragma unroll
            for (int ni = 0; ni < 4; ++ni) {
                acc[mi][ni] = __builtin_amdgcn_mfma_f32_16x16x32_bf16(ah[mi], bh[ni], acc[mi][ni], 0, 0, 0);
                acc[mi][ni] = __builtin_amdgcn_mfma_f32_16x16x32_bf16(ah[mi], bl[ni], acc[mi][ni], 0, 0, 0);
            }
        __syncthreads();
    }
#pragma unroll
    for (int mi = 0; mi < 4; ++mi)
#pragma unroll
        for (int ni = 0; ni < 4; ++ni)
#pragma unroll
            for (int reg = 0; reg < 4; ++reg) {
                int row = rb + wm * 64 + mi * 16 + quad * 4 + reg;
                if (row < Nrows)
                    Cb[(size_t)row * M + cb + wn * 64 + ni * 16 + l15] = f2bf(acc[mi][ni][reg]);
            }
    float sd[4][4] = {}, dd[4][4] = {};
#pragma unroll
    for (int ni = 0; ni < 4; ++ni) {
        int col = cb + wn * 64 + ni * 16 + l15;
        float a = av[col], b = bv[col];
#pragma unroll
        for (int mi = 0; mi < 4; ++mi)
#pragma unroll
            for (int reg = 0; reg < 4; ++reg) {
                sd[mi][reg] += acc[mi][ni][reg] * a;
                dd[mi][reg] += acc[mi][ni][reg] * b;
            }
    }
#pragma unroll
    for (int off = 1; off < 16; off <<= 1)
#pragma unroll
        for (int mi = 0; mi < 4; ++mi)
#pragma unroll
            for (int reg = 0; reg < 4; ++reg) {
                sd[mi][reg] += __shfl_xor(sd[mi][reg], off);
                dd[mi][reg] += __shfl_xor(dd[mi][reg], off);
            }
    if (l15 == 0)
#pragma unroll
        for (int mi = 0; mi < 4; ++mi) {
            int row0 = rb + wm * 64 + mi * 16 + quad * 4;
#pragma unroll
            for (int reg = 0; reg < 4; ++reg)
                if (row0 + reg < Nrows) {
                    atomicAdd(as_out + row0 + reg, sd[mi][reg]);
                    atomicAdd(ad_out + row0 + reg, dd[mi][reg]);
                }
        }
}

// ---- gemm2: same structure, A already bf16 ---------------------------------
__global__ __launch_bounds__(256) void gemm_mfma_kernel(
        const u16* __restrict__ A_g,
        const u16* __restrict__ Bh_g, const u16* __restrict__ Bl_g,
        u16* __restrict__ Cb, int Nrows, int K, int M,
        const float* __restrict__ av, const float* __restrict__ bv,
        float* __restrict__ as_out, float* __restrict__ ad_out) {
    __shared__ u16 Ah[128 * LDA], Bh[128 * LDA], Bl[128 * LDA];
    int tid = threadIdx.x;
    int lane = tid & 63;
    int wv = tid >> 6;
    int wm = wv >> 1, wn = wv & 1;
    int l15 = lane & 15, quad = lane >> 4;
    int rb = blockIdx.y * 128;
    int cb = blockIdx.x * 128;

    v4f acc[4][4];
#pragma unroll
    for (int mi = 0; mi < 4; ++mi)
#pragma unroll
        for (int ni = 0; ni < 4; ++ni) acc[mi][ni] = (v4f){0.f, 0.f, 0.f, 0.f};

    int sr = tid >> 1;
    int sc = (tid & 1) * 16;

    for (int kc = 0; kc < K; kc += BK) {
        int gr = rb + sr;
        u16x8 a0 = {0,0,0,0,0,0,0,0}, a1 = {0,0,0,0,0,0,0,0};
        if (gr < Nrows) {
            size_t ba = (size_t)gr * K + kc + sc;
            a0 = *(const u16x8*)(A_g + ba);
            a1 = *(const u16x8*)(A_g + ba + 8);
        }
        size_t bb = (size_t)(cb + sr) * K + kc + sc;
        u16x8 b0 = *(const u16x8*)(Bh_g + bb);
        u16x8 b1 = *(const u16x8*)(Bh_g + bb + 8);
        u16x8 b2 = *(const u16x8*)(Bl_g + bb);
        u16x8 b3 = *(const u16x8*)(Bl_g + bb + 8);
        *(u16x8*)&Ah[sr * LDA + sc] = a0;
        *(u16x8*)&Ah[sr * LDA + sc + 8] = a1;
        *(u16x8*)&Bh[sr * LDA + sc] = b0;
        *(u16x8*)&Bh[sr * LDA + sc + 8] = b1;
        *(u16x8*)&Bl[sr * LDA + sc] = b2;
        *(u16x8*)&Bl[sr * LDA + sc + 8] = b3;
        __syncthreads();
        short8 ah[4], bh[4], bl[4];
#pragma unroll
        for (int mi = 0; mi < 4; ++mi)
            ah[mi] = *(const short8*)&Ah[(wm * 64 + mi * 16 + l15) * LDA + quad * 8];
#pragma unroll
        for (int ni = 0; ni < 4; ++ni) {
            int r = (wn * 64 + ni * 16 + l15) * LDA + quad * 8;
            bh[ni] = *(const short8*)&Bh[r];
            bl[ni] = *(const short8*)&Bl[r];
        }
#pragma unroll
        for (int mi = 0; mi < 4; ++mi)
#pragma unroll
            for (int ni = 0; ni < 4; ++ni) {
                acc[mi][ni] = __builtin_amdgcn_mfma_f32_16x16x32_bf16(ah[mi], bh[ni], acc[mi][ni], 0, 0, 0);
                acc[mi][ni] = __builtin_amdgcn_mfma_f32_16x16x32_bf16(ah[mi], bl[ni], acc[mi][ni], 0, 0, 0);
            }
        __syncthreads();
    }
#pragma unroll
    for (int mi = 0; mi < 4; ++mi)
#pragma unroll
        for (int ni = 0; ni < 4; ++ni)
#pragma unroll
            for (int reg = 0; reg < 4; ++reg) {
                int row = rb + wm * 64 + mi * 16 + quad * 4 + reg;
                if (row < Nrows)
                    Cb[(size_t)row * M + cb + wn * 64 + ni * 16 + l15] = f2bf(acc[mi][ni][reg]);
            }
    float sd[4][4] = {}, dd[4][4] = {};
#pragma unroll
    for (int ni = 0; ni < 4; ++ni) {
        int col = cb + wn * 64 + ni * 16 + l15;
        float a = av[col], b = bv[col];
#pragma unroll
        for (int mi = 0; mi < 4; ++mi)
#pragma unroll
            for (int reg = 0; reg < 4; ++reg) {
                sd[mi][reg] += acc[mi][ni][reg] * a;
                dd[mi][reg] += acc[mi][ni][reg] * b;
            }
    }
#pragma unroll
    for (int off = 1; off < 16; off <<= 1)
#pragma unroll
        for (int mi = 0; mi < 4; ++mi)
#pragma unroll
            for (int reg = 0; reg < 4; ++reg) {
                sd[mi][reg] += __shfl_xor(sd[mi][reg], off);
                dd[mi][reg] += __shfl_xor(dd[mi][reg], off);
            }
    if (l15 == 0)
#pragma unroll
        for (int mi = 0; mi < 4; ++mi) {
            int row0 = rb + wm * 64 + mi * 16 + quad * 4;
#pragma unroll
            for (int reg = 0; reg < 4; ++reg)
                if (row0 + reg < Nrows) {
                    atomicAdd(as_out + row0 + reg, sd[mi][reg]);
                    atomicAdd(ad_out + row0 + reg, dd[mi][reg]);
                }
        }
}

// ---- single-pass FLASH softmax-aggregation, L1 (C=256), wave per node ------
__global__ __launch_bounds__(256) void agg1_kernel(const int* __restrict__ row_start,
                                                   const float4* __restrict__ epack,
                                                   const float* __restrict__ asv,
                                                   const float* __restrict__ adv,
                                                   const float* __restrict__ ae_loop,
                                                   const u16* __restrict__ Hb,
                                                   u16* __restrict__ ohi,
                                                   const float* __restrict__ bias, int N) {
    __shared__ float2 xch[4][64];
    int lane = threadIdx.x & 63;
    int wvi = threadIdx.x >> 6;
    int node = blockIdx.x * 4 + wvi;
    if (node >= N) return;
    int st = row_start[node], en = row_start[node + 1];
    float ad = adv[node];
    float aloop = lrelu(asv[node] + ad + ae_loop[0]);
    float m = aloop, sum = 1.f;
    float acc0, acc1, acc2, acc3;
    {
        int2 hv = *(const int2*)(Hb + (size_t)node * 256 + lane * 4);
        acc0 = bf_lo(hv.x); acc1 = bf_hi(hv.x);
        acc2 = bf_lo(hv.y); acc3 = bf_hi(hv.y);
    }
    for (int base = st; base < en; base += 64) {
        int i = base + lane;
        float al = -3.0e38f; int sreg = 0;
        if (i < en) {
            float4 ep = epack[i];
            sreg = __float_as_int(ep.x);
            al = lrelu(asv[sreg] + ad + ep.y);
        }
        float cm = al;
#pragma unroll
        for (int o = 1; o < 64; o <<= 1) cm = fmaxf(cm, __shfl_xor(cm, o));
        if (cm > m) {
            float sc = __expf(m - cm);
            acc0 *= sc; acc1 *= sc; acc2 *= sc; acc3 *= sc;
            sum *= sc; m = cm;
        }
        float w = (i < en) ? __expf(al - m) : 0.f;
        float wsum = w;
#pragma unroll
        for (int o = 1; o < 64; o <<= 1) wsum += __shfl_xor(wsum, o);
        sum += wsum;
        xch[wvi][lane] = make_float2(w, __int_as_float(sreg));
        int cnt = min(64, en - base);
        int j = 0;
        for (; j + 4 <= cnt; j += 4) {
            float2 e0 = xch[wvi][j], e1 = xch[wvi][j + 1];
            float2 e2 = xch[wvi][j + 2], e3 = xch[wvi][j + 3];
            int2 h0 = *(const int2*)(Hb + (size_t)__float_as_int(e0.y) * 256 + lane * 4);
            int2 h1 = *(const int2*)(Hb + (size_t)__float_as_int(e1.y) * 256 + lane * 4);
            int2 h2 = *(const int2*)(Hb + (size_t)__float_as_int(e2.y) * 256 + lane * 4);
            int2 h3 = *(const int2*)(Hb + (size_t)__float_as_int(e3.y) * 256 + lane * 4);
            acc0 += e0.x * bf_lo(h0.x) + e1.x * bf_lo(h1.x) + e2.x * bf_lo(h2.x) + e3.x * bf_lo(h3.x);
            acc1 += e0.x * bf_hi(h0.x) + e1.x * bf_hi(h1.x) + e2.x * bf_hi(h2.x) + e3.x * bf_hi(h3.x);
            acc2 += e0.x * bf_lo(h0.y) + e1.x * bf_lo(h1.y) + e2.x * bf_lo(h2.y) + e3.x * bf_lo(h3.y);
            acc3 += e0.x * bf_hi(h0.y) + e1.x * bf_hi(h1.y) + e2.x * bf_hi(h2.y) + e3.x * bf_hi(h3.y);
        }
        for (; j < cnt; ++j) {
            float2 e0 = xch[wvi][j];
            int2 h0 = *(const int2*)(Hb + (size_t)__float_as_int(e0.y) * 256 + lane * 4);
            acc0 += e0.x * bf_lo(h0.x); acc1 += e0.x * bf_hi(h0.x);
            acc2 += e0.x * bf_lo(h0.y); acc3 += e0.x * bf_hi(h0.y);
        }
    }
    float inv = 1.f / sum;
    const float4 bvv = *(const float4*)(bias + lane * 4);
    float t0 = acc0 * inv + bvv.x, t1 = acc1 * inv + bvv.y;
    float t2 = acc2 * inv + bvv.z, t3 = acc3 * inv + bvv.w;
    t0 = t0 > 0.f ? t0 : 0.f; t1 = t1 > 0.f ? t1 : 0.f;
    t2 = t2 > 0.f ? t2 : 0.f; t3 = t3 > 0.f ? t3 : 0.f;
    u16x4 h;
    h.x = f2bf(t0); h.y = f2bf(t1); h.z = f2bf(t2); h.w = f2bf(t3);
    *(u16x4*)(ohi + (size_t)node * 256 + lane * 4) = h;
}

// ---- single-pass FLASH softmax-aggregation, L2 (C=128) ---------------------
__global__ __launch_bounds__(256) void agg2_kernel(const int* __restrict__ row_start,
                                                   const float4* __restrict__ epack,
                                                   const float* __restrict__ asv,
                                                   const float* __restrict__ adv,
                                                   const float* __restrict__ ae_loop,
                                                   const u16* __restrict__ Hb,
                                                   float* __restrict__ out,
                                                   const float* __restrict__ bias, int N) {
    __shared__ float2 xch[4][64];
    int lane = threadIdx.x & 63;
    int wvi = threadIdx.x >> 6;
    int node = blockIdx.x * 4 + wvi;
    if (node >= N) return;
    int st = row_start[node], en = row_start[node + 1];
    float ad = adv[node];
    float aloop = lrelu(asv[node] + ad + ae_loop[1]);
    float m = aloop, sum = 1.f;
    float acc0, acc1;
    {
        int hv = *(const int*)(Hb + (size_t)node * 128 + lane * 2);
        acc0 = bf_lo(hv); acc1 = bf_hi(hv);
    }
    for (int base = st; base < en; base += 64) {
        int i = base + lane;
        float al = -3.0e38f; int sreg = 0;
        if (i < en) {
            float4 ep = epack[i];
            sreg = __float_as_int(ep.x);
            al = lrelu(asv[sreg] + ad + ep.z);
        }
        float cm = al;
#pragma unroll
        for (int o = 1; o < 64; o <<= 1) cm = fmaxf(cm, __shfl_xor(cm, o));
        if (cm > m) {
            float sc = __expf(m - cm);
            acc0 *= sc; acc1 *= sc;
            sum *= sc; m = cm;
        }
        float w = (i < en) ? __expf(al - m) : 0.f;
        float wsum = w;
#pragma unroll
        for (int o = 1; o < 64; o <<= 1) wsum += __shfl_xor(wsum, o);
        sum += wsum;
        xch[wvi][lane] = make_float2(w, __int_as_float(sreg));
        int cnt = min(64, en - base);
        int j = 0;
        for (; j + 4 <= cnt; j += 4) {
            float2 e0 = xch[wvi][j], e1 = xch[wvi][j + 1];
            float2 e2 = xch[wvi][j + 2], e3 = xch[wvi][j + 3];
            int h0 = *(const int*)(Hb + (size_t)__float_as_int(e0.y) * 128 + lane * 2);
            int h1 = *(const int*)(Hb + (size_t)__float_as_int(e1.y) * 128 + lane * 2);
            int h2 = *(const int*)(Hb + (size_t)__float_as_int(e2.y) * 128 + lane * 2);
            int h3 = *(const int*)(Hb + (size_t)__float_as_int(e3.y) * 128 + lane * 2);
            acc0 += e0.x * bf_lo(h0) + e1.x * bf_lo(h1) + e2.x * bf_lo(h2) + e3.x * bf_lo(h3);
            acc1 += e0.x * bf_hi(h0) + e1.x * bf_hi(h1) + e2.x * bf_hi(h2) + e3.x * bf_hi(h3);
        }
        for (; j < cnt; ++j) {
            float2 e0 = xch[wvi][j];
            int h0 = *(const int*)(Hb + (size_t)__float_as_int(e0.y) * 128 + lane * 2);
            acc0 += e0.x * bf_lo(h0); acc1 += e0.x * bf_hi(h0);
        }
    }
    float inv = 1.f / sum;
    size_t o = (size_t)node * 128 + lane * 2;
    out[o]     = acc0 * inv + bias[lane * 2];
    out[o + 1] = acc1 * inv + bias[lane * 2 + 1];
}

extern "C" void kernel_launch(void* const* d_in, const int* in_sizes, int n_in,
                              void* d_out, int out_size, void* d_ws, size_t ws_size,
                              hipStream_t stream) {
    const int Cin = 128, Ch = 256, Co = 128;
    const int N = in_sizes[0] / Cin;        // 50000
    const int E = in_sizes[1] / 2;          // 800000

    const float* x   = (const float*)d_in[0];
    const int*   src = (const int*)d_in[1];
    const int*   dst = src + E;
    const float* ea  = (const float*)d_in[2];
    const float* W1  = (const float*)d_in[3];
    const float* We1 = (const float*)d_in[4];
    const float* as1 = (const float*)d_in[5];
    const float* ad1 = (const float*)d_in[6];
    const float* ae1 = (const float*)d_in[7];
    const float* b1  = (const float*)d_in[8];
    const float* W2  = (const float*)d_in[9];
    const float* We2 = (const float*)d_in[10];
    const float* as2 = (const float*)d_in[11];
    const float* ad2 = (const float*)d_in[12];
    const float* ae2 = (const float*)d_in[13];
    const float* b2  = (const float*)d_in[14];
    float* out = (float*)d_out;

    // workspace layout (4-byte units)
    float* ws = (float*)d_ws;
    size_t off = 0;
    u16* h1b = (u16*)(ws + off); off += (size_t)N * Ch / 2;   // bf16 h (reused as h2b)
    u16* g1b = (u16*)(ws + off); off += (size_t)N * Ch / 2;   // agg1 output (gemm2 A)
    float4* epack = (float4*)(ws + off); off += (size_t)E * 4;  // packed CSR edges
    float2* aEe   = (float2*)(ws + off); off += (size_t)E * 2;  // edge-order a_e
    int* row_start = (int*)(ws + off); off += (size_t)N + 1;
    int* cursor    = (int*)(ws + off); off += (size_t)N;
    int* partials  = (int*)(ws + off); off += 256;
    int* pprefix   = (int*)(ws + off); off += 256;
    u16* w1thi = (u16*)(ws + off); off += (size_t)Cin * Ch / 2;
    u16* w1tlo = (u16*)(ws + off); off += (size_t)Cin * Ch / 2;
    u16* w2thi = (u16*)(ws + off); off += (size_t)Ch * Co / 2;
    u16* w2tlo = (u16*)(ws + off); off += (size_t)Ch * Co / 2;
    // contiguous zero-region: deg | asv1 adv1 asv2 adv2 | misc | sync
    int*   deg  = (int*)(ws + off); off += (size_t)N + 1;
    float* asv1 = ws + off; off += (size_t)N;
    float* adv1 = ws + off; off += (size_t)N;
    float* asv2 = ws + off; off += (size_t)N;
    float* adv2 = ws + off; off += (size_t)N;
    float* misc = ws + off; off += 32;
    float* mean_acc = misc;
    float* we_vec1  = misc + 8;
    float* we_vec2  = misc + 16;
    float* ae_loop  = misc + 24;
    int* gcount = (int*)(ws + off); off += 1;
    int* gflag  = (int*)(ws + off); off += 1;

    const int n1 = N + 1;
    const int nscan = (n1 + 255) / 256;   // 196 blocks <= 256 CUs (co-resident)

    // one memset zeroes deg + 4 dot-buffers + misc + sync flags
    hipMemsetAsync(deg, 0, ((size_t)5 * N + 35) * sizeof(float), stream);

    // ---- FAT A: ea_hist (1024 blocks) || W splits (256 blocks) -------------
    pre_fat_kernel<<<EHB + 256, 256, 0, stream>>>(
        ea, dst, We1, ae1, We2, ae2, mean_acc, deg, aEe, E,
        W1, w1thi, w1tlo, W2, w2thi, w2tlo, we_vec1, we_vec2);

    // ---- fused scan (+cursor, +ae_loop) ------------------------------------
    scan_fused_kernel<<<nscan, 256, 0, stream>>>(
        deg, row_start, cursor, partials, pprefix, gcount, gflag, N, n1,
        mean_acc, 1.0f / (float)E, we_vec1, we_vec2, ae_loop);

    // ---- FAT B: gemm1 (fp32 A) || CSR fill ---------------------------------
    {
        int gx = Ch / 128;                       // 2
        int Gg = gx * ((N + 127) / 128);         // 782
        int Fb = (E + 255) / 256;                // 3125
        gemm1_fill_fat_kernel<<<Gg + Fb, 256, 0, stream>>>(
            x, w1thi, w1tlo, h1b, N, Cin, Ch, as1, ad1, asv1, adv1, Gg, gx,
            src, dst, aEe, cursor, epack, E);
    }
    agg1_kernel<<<(N + 3) / 4, 256, 0, stream>>>(row_start, epack, asv1, adv1, ae_loop,
                                                 h1b, g1b, b1, N);

    // ---- layer 2 ----------------------------------------------------------
    u16* h2b = h1b; // reuse (agg1 consumed h1b)
    {
        dim3 grid(Co / 128, (N + 127) / 128);
        gemm_mfma_kernel<<<grid, 256, 0, stream>>>(g1b, w2thi, w2tlo, h2b, N, Ch, Co,
                                                   as2, ad2, asv2, adv2);
    }
    agg2_kernel<<<(N + 3) / 4, 256, 0, stream>>>(row_start, epack, asv2, adv2, ae_loop,
                                                 h2b, out, b2, N);
}